// Round 1
// baseline (18445.848 us; speedup 1.0000x reference)
//
#include <hip/hip_runtime.h>

#define HH 512
#define BB 16
#define TT 256
#define VV 32
#define TPB 256
#define NBLK 256
#define PITCH 516   // LDS row pitch (floats): 16B-aligned rows, bank stride 4

struct KArgs {
  const float* enc; const float* c0in;
  const float* Wq; const float* bq; const float* vatt; const float* vb;
  const float* Wih0; const float* bih0; const float* Whh0; const float* bhh0;
  const float* Wih1; const float* bih1; const float* Whh1; const float* bhh1;
  const float* Wout; const float* bout;
  const float* Kproj; float* H0buf; float* H1buf; float* qWg; float* Ug; float* Zg;
  int* bar; float* out;
};

struct Smem {
  float W0e[4][2][PITCH];   // Wih0[g*512+j][0:512]    (enc_t part)
  float W0c[4][2][PITCH];   // Wih0[g*512+j][512:1024] (ctx part)
  float W0h[4][2][PITCH];   // Whh0
  float W1x[4][2][PITCH];   // Wih1
  float W1h[4][2][PITCH];   // Whh1
  float Wqr[2][PITCH];
  float Wor[2][PITCH];
  float vv[HH];
  float qrow[HH];
  float stg[BB][PITCH];     // staging for h1/h0/enc_t/ctx/h0n
  float red[4][64];         // per-wave dot partials
  float pre0[BB][4][2];     // accumulated gate partials (enc+h0+bias)
  float pre1[BB][4][2];     // (h1+bias)
  float cst[2][2][BB];      // c state [layer][jj][b]
  float scw[16];            // attention exp-weights for this block's t-chunk
  float bs0[4][2];
  float bs1[4][2];
  float bqv[2], boutv[2];
  float zinv[BB];
};

__device__ __forceinline__ float fsig(float x){ return 1.0f/(1.0f + __expf(-x)); }
__device__ __forceinline__ float ftanh(float x){
  float ee = __expf(2.0f*x);
  return 1.0f - 2.0f/(ee + 1.0f);
}

// hierarchical device-wide barrier: 8 group counters -> root -> epoch flag
__device__ __forceinline__ void gbar(int* __restrict__ bar, int e){
  __syncthreads();
  if (threadIdx.x == 0){
    const int g = (int)(blockIdx.x & 7);
    int old = __hip_atomic_fetch_add(&bar[g], 1, __ATOMIC_ACQ_REL, __HIP_MEMORY_SCOPE_AGENT);
    if (old == e*32 - 1){
      int o2 = __hip_atomic_fetch_add(&bar[8], 1, __ATOMIC_ACQ_REL, __HIP_MEMORY_SCOPE_AGENT);
      if (o2 == e*8 - 1){
        __hip_atomic_store(&bar[9], e, __ATOMIC_RELEASE, __HIP_MEMORY_SCOPE_AGENT);
      }
    }
    int spins = 0;
    while (__hip_atomic_load(&bar[9], __ATOMIC_RELAXED, __HIP_MEMORY_SCOPE_AGENT) < e){
      __builtin_amdgcn_s_sleep(1);
      if (++spins > (1 << 24)) break;   // safety valve: wrong answer beats a hang
    }
    (void)__hip_atomic_load(&bar[9], __ATOMIC_ACQUIRE, __HIP_MEMORY_SCOPE_AGENT); // acquire fence
  }
  __syncthreads();
}

__device__ __forceinline__ void stage_g(const float* __restrict__ src,
                                        float (* __restrict__ stg)[PITCH], int tid){
  #pragma unroll
  for (int it = 0; it < 8; ++it){
    const int idx = (it*TPB + tid)*4;
    const int b = idx >> 9, h = idx & 511;
    *(float4*)&stg[b][h] = *(const float4*)&src[idx];
  }
}

// wave w handles (jj = w>>1, h-half = w&1); lane = (g<<4)|b ; writes red[w][lane]
__device__ __forceinline__ void dot_part(const float* __restrict__ W,
                                         const float (* __restrict__ stg)[PITCH],
                                         float (* __restrict__ red)[64],
                                         int wave, int lane){
  const int jj = wave >> 1, off = (wave & 1) << 8;
  const int b = lane & 15, g = lane >> 4;
  const float* wrow = W + (size_t)(g*2 + jj)*PITCH + off;
  const float* xrow = &stg[b][off];
  float acc = 0.f;
  #pragma unroll 8
  for (int h = 0; h < 256; h += 4){
    const float4 w4 = *(const float4*)&wrow[h];
    const float4 x4 = *(const float4*)&xrow[h];
    acc = fmaf(w4.x,x4.x, fmaf(w4.y,x4.y, fmaf(w4.z,x4.z, fmaf(w4.w,x4.w, acc))));
  }
  red[wave][lane] = acc;
}

__global__ void init_kernel(const float* __restrict__ h0in, float* __restrict__ H0buf,
                            float* __restrict__ H1buf, int* __restrict__ bar){
  const int i = blockIdx.x*blockDim.x + threadIdx.x;
  if (i < BB*HH){
    H0buf[i] = h0in[i];            // layer 0
    H1buf[i] = h0in[BB*HH + i];    // layer 1
  }
  if (blockIdx.x == 0 && threadIdx.x < 16) bar[threadIdx.x] = 0;
}

// Kproj = enc @ Wk^T + bk : 256 blocks x 16 (b,t)-rows, x register-cached
__global__ __launch_bounds__(256, 1) void kproj_kernel(const float* __restrict__ enc,
                                                       const float* __restrict__ Wk,
                                                       const float* __restrict__ bk,
                                                       float* __restrict__ Kproj){
  __shared__ float er[BB][PITCH];
  const int bid = blockIdx.x, tid = threadIdx.x;
  const int wave = tid >> 6, lane = tid & 63;
  const int r = lane & 15, q = lane >> 4;
  const int row0 = bid*16;
  #pragma unroll
  for (int it = 0; it < 8; ++it){
    const int idx = (it*256 + tid)*4;
    const int rr = idx >> 9, h = idx & 511;
    *(float4*)&er[rr][h] = *(const float4*)&enc[(size_t)(row0+rr)*HH + h];
  }
  __syncthreads();
  float4 xr[32];
  #pragma unroll
  for (int i = 0; i < 32; ++i) xr[i] = *(const float4*)&er[r][q*128 + i*4];
  for (int k = 0; k < 128; ++k){
    const int hk = wave*128 + k;
    const float* wrow = Wk + (size_t)hk*HH + q*128;
    float acc = 0.f;
    #pragma unroll
    for (int i = 0; i < 32; ++i){
      const float4 w4 = *(const float4*)&wrow[i*4];
      acc = fmaf(w4.x,xr[i].x, fmaf(w4.y,xr[i].y, fmaf(w4.z,xr[i].z, fmaf(w4.w,xr[i].w, acc))));
    }
    acc += __shfl_xor(acc, 16);
    acc += __shfl_xor(acc, 32);
    if (lane < 16) Kproj[(size_t)(row0 + r)*HH + hk] = acc + bk[hk];
  }
}

__global__ __launch_bounds__(TPB, 1) void decoder_persist(KArgs a){
  __shared__ Smem S;
  const int bid = blockIdx.x, tid = threadIdx.x;
  const int wave = tid >> 6, lane = tid & 63;
  const int lb = lane & 15, lg = lane >> 4;
  const int j0 = bid*2;

  // ---- one-time: weights to LDS ----
  for (int g = 0; g < 4; ++g){
    for (int jj = 0; jj < 2; ++jj){
      const int row = g*HH + j0 + jj;
      for (int h = tid; h < HH; h += TPB){
        S.W0e[g][jj][h] = a.Wih0[(size_t)row*(2*HH) + h];
        S.W0c[g][jj][h] = a.Wih0[(size_t)row*(2*HH) + HH + h];
        S.W0h[g][jj][h] = a.Whh0[(size_t)row*HH + h];
        S.W1x[g][jj][h] = a.Wih1[(size_t)row*HH + h];
        S.W1h[g][jj][h] = a.Whh1[(size_t)row*HH + h];
      }
    }
  }
  for (int jj = 0; jj < 2; ++jj){
    const int d = bid*2 + jj, vo = d & 31;
    for (int h = tid; h < HH; h += TPB){
      S.Wqr[jj][h] = a.Wq[(size_t)(j0+jj)*HH + h];
      S.Wor[jj][h] = a.Wout[(size_t)vo*HH + h];
    }
  }
  for (int h = tid; h < HH; h += TPB) S.vv[h] = a.vatt[h];
  if (tid < 16){
    S.cst[0][0][tid] = a.c0in[0*BB*HH + tid*HH + j0];
    S.cst[0][1][tid] = a.c0in[0*BB*HH + tid*HH + j0 + 1];
    S.cst[1][0][tid] = a.c0in[1*BB*HH + tid*HH + j0];
    S.cst[1][1][tid] = a.c0in[1*BB*HH + tid*HH + j0 + 1];
  }
  if (tid < 8){
    const int g = tid & 3, jj = tid >> 2;
    const int row = g*HH + j0 + jj;
    S.bs0[g][jj] = a.bih0[row] + a.bhh0[row];
    S.bs1[g][jj] = a.bih1[row] + a.bhh1[row];
  }
  if (tid < 2){
    S.bqv[tid] = a.bq[j0 + tid];
    S.boutv[tid] = a.bout[(bid*2 + tid) & 31];
  }
  const float vb0 = a.vb[0];
  __syncthreads();

  int e = 0;
  for (int t = 0; t < TT; ++t){
    const int par = t & 1, parn = par ^ 1;

    // ================= Phase A =================
    if (tid < 32) a.Ug[bid*32 + tid] = 0.0f;
    if (bid == 0 && tid < 16) a.Zg[tid] = 0.0f;

    stage_g(a.H1buf + par*(BB*HH), S.stg, tid);   // h1_prev
    __syncthreads();

    if (wave < 2){
      if (t > 0){   // logits for step t-1 from staged h1
        const int d = bid*2 + wave, bo = d >> 5, vo = d & 31;
        float acc = 0.f;
        #pragma unroll
        for (int k = 0; k < 8; ++k){
          const int h = lane + 64*k;
          acc = fmaf(S.Wor[wave][h], S.stg[bo][h], acc);
        }
        #pragma unroll
        for (int off = 32; off; off >>= 1) acc += __shfl_xor(acc, off);
        if (lane == 0) a.out[(size_t)(bo*TT + (t-1))*VV + vo] = acc + S.boutv[wave];
      }
    } else {      // qW = h1 @ Wq^T + bq  (2 output rows per block)
      const int jj = wave - 2;
      const int off0 = lg * 128;
      float acc = 0.f;
      #pragma unroll 8
      for (int h = 0; h < 128; h += 4){
        const float4 w4 = *(const float4*)&S.Wqr[jj][off0 + h];
        const float4 x4 = *(const float4*)&S.stg[lb][off0 + h];
        acc = fmaf(w4.x,x4.x, fmaf(w4.y,x4.y, fmaf(w4.z,x4.z, fmaf(w4.w,x4.w, acc))));
      }
      acc += __shfl_xor(acc, 16);
      acc += __shfl_xor(acc, 32);
      if (lane < 16) a.qWg[lane*HH + j0 + jj] = acc + S.bqv[jj];
    }
    dot_part(&S.W1h[0][0][0], S.stg, S.red, wave, lane);  // h1 @ Whh1^T
    __syncthreads();
    if (tid < 128){
      const int jj = tid >> 6, l = tid & 63, g = l >> 4, b = l & 15;
      S.pre1[b][g][jj] = S.red[2*jj][l] + S.red[2*jj+1][l] + S.bs1[g][jj];
    }
    __syncthreads();

    stage_g(a.H0buf + par*(BB*HH), S.stg, tid);   // h0_prev
    __syncthreads();
    dot_part(&S.W0h[0][0][0], S.stg, S.red, wave, lane);  // h0 @ Whh0^T
    __syncthreads();
    if (tid < 128){
      const int jj = tid >> 6, l = tid & 63, g = l >> 4, b = l & 15;
      S.pre0[b][g][jj] = S.red[2*jj][l] + S.red[2*jj+1][l] + S.bs0[g][jj];
    }
    __syncthreads();

    #pragma unroll
    for (int it = 0; it < 8; ++it){               // enc_t stage
      const int idx = (it*TPB + tid)*4;
      const int b = idx >> 9, h = idx & 511;
      *(float4*)&S.stg[b][h] = *(const float4*)&a.enc[(size_t)(b*TT + t)*HH + h];
    }
    __syncthreads();
    dot_part(&S.W0e[0][0][0], S.stg, S.red, wave, lane);  // enc_t part of Wih0
    __syncthreads();
    if (tid < 128){
      const int jj = tid >> 6, l = tid & 63, g = l >> 4, b = l & 15;
      S.pre0[b][g][jj] += S.red[2*jj][l] + S.red[2*jj+1][l];
    }
    e++; gbar(a.bar, e);   // barrier 1: qW + zeroed U/Z visible

    // ================= Phase B: attention =================
    {
      const int ba = bid >> 4, ch = bid & 15, tb = ch*16;
      for (int h = tid; h < HH; h += TPB) S.qrow[h] = a.qWg[ba*HH + h];
      __syncthreads();
      #pragma unroll
      for (int i = 0; i < 4; ++i){
        const int lt = wave*4 + i;
        const float* kp = a.Kproj + (size_t)(ba*TT + tb + lt)*HH;
        float acc = 0.f;
        #pragma unroll
        for (int k = 0; k < 8; ++k){
          const int h = lane + 64*k;
          acc = fmaf(S.vv[h], ftanh(S.qrow[h] + kp[h]), acc);
        }
        #pragma unroll
        for (int off = 32; off; off >>= 1) acc += __shfl_xor(acc, off);
        if (lane == 0) S.scw[lt] = __expf(acc + vb0);   // no max-sub: |score| <= ~18
      }
      __syncthreads();
      float u0 = 0.f, u1 = 0.f;
      for (int lt = 0; lt < 16; ++lt){
        const float w = S.scw[lt];
        const float* er = a.enc + (size_t)(ba*TT + tb + lt)*HH;
        u0 = fmaf(w, er[tid],       u0);
        u1 = fmaf(w, er[tid + 256], u1);
      }
      unsafeAtomicAdd(&a.Ug[ba*HH + tid],       u0);
      unsafeAtomicAdd(&a.Ug[ba*HH + tid + 256], u1);
      if (tid == 0){
        float zs = 0.f;
        #pragma unroll
        for (int lt = 0; lt < 16; ++lt) zs += S.scw[lt];
        unsafeAtomicAdd(&a.Zg[ba], zs);
      }
    }
    e++; gbar(a.bar, e);   // barrier 2: U,Z complete

    // ================= Phase C: LSTM0 =================
    {
      if (tid < 16) S.zinv[tid] = 1.0f / a.Zg[tid];
      __syncthreads();
      #pragma unroll
      for (int it = 0; it < 8; ++it){            // ctx = U/Z -> stg
        const int idx = (it*TPB + tid)*4;
        const int b = idx >> 9, h = idx & 511;
        float4 u4 = *(const float4*)&a.Ug[idx];
        const float zi = S.zinv[b];
        u4.x *= zi; u4.y *= zi; u4.z *= zi; u4.w *= zi;
        *(float4*)&S.stg[b][h] = u4;
      }
      __syncthreads();
      dot_part(&S.W0c[0][0][0], S.stg, S.red, wave, lane);  // ctx part of Wih0
      __syncthreads();
      if (tid < 32){
        const int b = tid & 15, jj = tid >> 4;
        float gv[4];
        #pragma unroll
        for (int g = 0; g < 4; ++g)
          gv[g] = S.pre0[b][g][jj] + S.red[2*jj][g*16+b] + S.red[2*jj+1][g*16+b];
        const float cold = S.cst[0][jj][b];
        const float ii = fsig(gv[0]), ff = fsig(gv[1]);
        const float gg = ftanh(gv[2]), oo = fsig(gv[3]);
        const float cn = ff*cold + ii*gg;
        S.cst[0][jj][b] = cn;
        a.H0buf[parn*(BB*HH) + b*HH + j0 + jj] = oo * ftanh(cn);
      }
    }
    e++; gbar(a.bar, e);   // barrier 3: h0n complete

    // ================= Phase D: LSTM1 =================
    {
      stage_g(a.H0buf + parn*(BB*HH), S.stg, tid);   // h0n
      __syncthreads();
      dot_part(&S.W1x[0][0][0], S.stg, S.red, wave, lane);  // h0n @ Wih1^T
      __syncthreads();
      if (tid < 32){
        const int b = tid & 15, jj = tid >> 4;
        float gv[4];
        #pragma unroll
        for (int g = 0; g < 4; ++g)
          gv[g] = S.pre1[b][g][jj] + S.red[2*jj][g*16+b] + S.red[2*jj+1][g*16+b];
        const float cold = S.cst[1][jj][b];
        const float ii = fsig(gv[0]), ff = fsig(gv[1]);
        const float gg = ftanh(gv[2]), oo = fsig(gv[3]);
        const float cn = ff*cold + ii*gg;
        S.cst[1][jj][b] = cn;
        a.H1buf[parn*(BB*HH) + b*HH + j0 + jj] = oo * ftanh(cn);
      }
    }
    e++; gbar(a.bar, e);   // barrier 4: h1n complete -> next step
  }

  // tail: logits for t=255 (h1 final is in H1buf[0] since (255+1)&1==0)
  stage_g(a.H1buf + 0, S.stg, tid);
  __syncthreads();
  if (wave < 2){
    const int d = bid*2 + wave, bo = d >> 5, vo = d & 31;
    float acc = 0.f;
    #pragma unroll
    for (int k = 0; k < 8; ++k){
      const int h = lane + 64*k;
      acc = fmaf(S.Wor[wave][h], S.stg[bo][h], acc);
    }
    #pragma unroll
    for (int off = 32; off; off >>= 1) acc += __shfl_xor(acc, off);
    if (lane == 0) a.out[(size_t)(bo*TT + 255)*VV + vo] = acc + S.boutv[wave];
  }
}

extern "C" void kernel_launch(void* const* d_in, const int* in_sizes, int n_in,
                              void* d_out, int out_size, void* d_ws, size_t ws_size,
                              hipStream_t stream){
  const float* enc  = (const float*)d_in[0];
  const float* h0in = (const float*)d_in[1];
  const float* c0in = (const float*)d_in[2];
  // d_in[3] audio_lengths: unused by the reference
  const float* Wq   = (const float*)d_in[4];
  const float* bq   = (const float*)d_in[5];
  const float* Wk   = (const float*)d_in[6];
  const float* bk   = (const float*)d_in[7];
  const float* vatt = (const float*)d_in[8];
  const float* vb   = (const float*)d_in[9];
  const float* Wih0 = (const float*)d_in[10];
  const float* bih0 = (const float*)d_in[11];
  const float* Whh0 = (const float*)d_in[12];
  const float* bhh0 = (const float*)d_in[13];
  const float* Wih1 = (const float*)d_in[14];
  const float* bih1 = (const float*)d_in[15];
  const float* Whh1 = (const float*)d_in[16];
  const float* bhh1 = (const float*)d_in[17];
  const float* Wout = (const float*)d_in[18];
  const float* bout = (const float*)d_in[19];

  float* ws    = (float*)d_ws;
  float* Kproj = ws;                               // B*T*H = 2097152
  float* H0buf = Kproj + (size_t)BB*TT*HH;         // 2*B*H
  float* H1buf = H0buf + 2*BB*HH;                  // 2*B*H
  float* qWg   = H1buf + 2*BB*HH;                  // B*H
  float* Ug    = qWg + BB*HH;                      // B*H
  float* Zg    = Ug + BB*HH;                       // B
  int*   bar   = (int*)(Zg + 16);                  // 16 ints

  hipLaunchKernelGGL(init_kernel, dim3(32), dim3(256), 0, stream, h0in, H0buf, H1buf, bar);
  hipLaunchKernelGGL(kproj_kernel, dim3(256), dim3(256), 0, stream, enc, Wk, bk, Kproj);

  KArgs ka;
  ka.enc = enc; ka.c0in = c0in; ka.Wq = Wq; ka.bq = bq; ka.vatt = vatt; ka.vb = vb;
  ka.Wih0 = Wih0; ka.bih0 = bih0; ka.Whh0 = Whh0; ka.bhh0 = bhh0;
  ka.Wih1 = Wih1; ka.bih1 = bih1; ka.Whh1 = Whh1; ka.bhh1 = bhh1;
  ka.Wout = Wout; ka.bout = bout;
  ka.Kproj = Kproj; ka.H0buf = H0buf; ka.H1buf = H1buf;
  ka.qWg = qWg; ka.Ug = Ug; ka.Zg = Zg; ka.bar = bar; ka.out = (float*)d_out;

  void* params[] = { (void*)&ka };
  hipLaunchCooperativeKernel((const void*)decoder_persist, dim3(NBLK), dim3(TPB),
                             params, 0, stream);
}

// Round 2
// 16536.781 us; speedup vs baseline: 1.1154x; 1.1154x over previous
//
#include <hip/hip_runtime.h>

#define HH 512
#define BB 16
#define TT 256
#define VV 32
#define TPB 256
#define NBLK 256
#define PITCH 516   // LDS row pitch (floats)

// barrier layout: padded slots of 32 ints (128B) each
#define BAR_GRP(g)  ((g)*32)        // 8 group counters
#define BAR_ROOT    (8*32)          // root counter
#define BAR_FLAG(g) ((9+(g))*32)    // 8 epoch-flag replicas
#define BAR_INTS    (17*32)

struct KArgs {
  const float* enc; const float* c0in;
  const float* Wq; const float* bq; const float* vatt; const float* vb;
  const float* Wih0; const float* bih0; const float* Whh0; const float* bhh0;
  const float* Wih1; const float* bih1; const float* Whh1; const float* bhh1;
  const float* Wout; const float* bout;
  const float* Kproj; float* H0buf; float* H1buf; float* qWg; float* Ug; float* Zg;
  int* bar; float* out;
};

struct Smem {
  float W0e[4][2][PITCH];   // Wih0[g*512+j][0:512]    (enc_t part)
  float W0c[4][2][PITCH];   // Wih0[g*512+j][512:1024] (ctx part)
  float W0h[4][2][PITCH];   // Whh0
  float W1x[4][2][PITCH];   // Wih1
  float W1h[4][2][PITCH];   // Whh1
  float Wqr[2][PITCH];
  float Wor[2][PITCH];
  float vv[HH];
  float qrow[HH];
  float stg[BB][PITCH];     // staging for h1/h0/enc_t/ctx/h0n
  float red[4][64];         // per-wave dot partials
  float pre0[BB][4][2];     // accumulated gate partials (enc+h0+bias)
  float pre1[BB][4][2];     // (h1+bias)
  float cst[2][2][BB];      // c state [layer][jj][b]
  float scw[16];            // attention exp-weights for this block's t-chunk
  float bs0[4][2];
  float bs1[4][2];
  float bqv[2], boutv[2];
};

__device__ __forceinline__ float fsig(float x){ return 1.0f/(1.0f + __expf(-x)); }
__device__ __forceinline__ float ftanh(float x){
  float ee = __expf(2.0f*x);
  return 1.0f - 2.0f/(ee + 1.0f);
}

// hierarchical device-wide barrier, contention-split:
// 8 padded per-XCD-group counters -> padded root -> 8 padded flag replicas
__device__ __forceinline__ void gbar(int* __restrict__ bar, int e, int bid){
  __syncthreads();
  if (threadIdx.x == 0){
    const int g = bid & 7;
    int old = __hip_atomic_fetch_add(&bar[BAR_GRP(g)], 1, __ATOMIC_ACQ_REL, __HIP_MEMORY_SCOPE_AGENT);
    if (old == e*32 - 1){
      int o2 = __hip_atomic_fetch_add(&bar[BAR_ROOT], 1, __ATOMIC_ACQ_REL, __HIP_MEMORY_SCOPE_AGENT);
      if (o2 == e*8 - 1){
        #pragma unroll
        for (int x = 0; x < 8; ++x)
          __hip_atomic_store(&bar[BAR_FLAG(x)], e, __ATOMIC_RELEASE, __HIP_MEMORY_SCOPE_AGENT);
      }
    }
    int spins = 0;
    while (__hip_atomic_load(&bar[BAR_FLAG(g)], __ATOMIC_RELAXED, __HIP_MEMORY_SCOPE_AGENT) < e){
      __builtin_amdgcn_s_sleep(1);
      if (++spins > (1 << 22)) break;   // safety valve: wrong answer beats a hang
    }
    (void)__hip_atomic_load(&bar[BAR_FLAG(g)], __ATOMIC_ACQUIRE, __HIP_MEMORY_SCOPE_AGENT);
  }
  __syncthreads();
}

// wave w handles (jj = w>>1, h-half = w&1); lane = (g<<4)|b ; writes red[w][lane]
__device__ __forceinline__ void dot_part(const float* __restrict__ W,
                                         const float (* __restrict__ stg)[PITCH],
                                         float (* __restrict__ red)[64],
                                         int wave, int lane){
  const int jj = wave >> 1, off = (wave & 1) << 8;
  const int b = lane & 15, g = lane >> 4;
  const float* wrow = W + (size_t)(g*2 + jj)*PITCH + off;
  const float* xrow = &stg[b][off];
  float acc = 0.f;
  #pragma unroll 8
  for (int h = 0; h < 256; h += 4){
    const float4 w4 = *(const float4*)&wrow[h];
    const float4 x4 = *(const float4*)&xrow[h];
    acc = fmaf(w4.x,x4.x, fmaf(w4.y,x4.y, fmaf(w4.z,x4.z, fmaf(w4.w,x4.w, acc))));
  }
  red[wave][lane] = acc;
}

__global__ void init_kernel(const float* __restrict__ h0in, float* __restrict__ H0buf,
                            float* __restrict__ H1buf, int* __restrict__ bar){
  const int i = blockIdx.x*blockDim.x + threadIdx.x;
  if (i < BB*HH){
    H0buf[i] = h0in[i];            // layer 0
    H1buf[i] = h0in[BB*HH + i];    // layer 1
  }
  if (i < BAR_INTS) bar[i] = 0;
}

// Kproj = enc @ Wk^T + bk : 256 blocks x 16 (b,t)-rows, x register-cached
__global__ __launch_bounds__(256, 1) void kproj_kernel(const float* __restrict__ enc,
                                                       const float* __restrict__ Wk,
                                                       const float* __restrict__ bk,
                                                       float* __restrict__ Kproj){
  __shared__ float er[BB][PITCH];
  const int bid = blockIdx.x, tid = threadIdx.x;
  const int wave = tid >> 6, lane = tid & 63;
  const int r = lane & 15, q = lane >> 4;
  const int row0 = bid*16;
  #pragma unroll
  for (int it = 0; it < 8; ++it){
    const int idx = (it*256 + tid)*4;
    const int rr = idx >> 9, h = idx & 511;
    *(float4*)&er[rr][h] = *(const float4*)&enc[(size_t)(row0+rr)*HH + h];
  }
  __syncthreads();
  float4 xr[32];
  #pragma unroll
  for (int i = 0; i < 32; ++i) xr[i] = *(const float4*)&er[r][q*128 + i*4];
  for (int k = 0; k < 128; ++k){
    const int hk = wave*128 + k;
    const float* wrow = Wk + (size_t)hk*HH + q*128;
    float acc = 0.f;
    #pragma unroll
    for (int i = 0; i < 32; ++i){
      const float4 w4 = *(const float4*)&wrow[i*4];
      acc = fmaf(w4.x,xr[i].x, fmaf(w4.y,xr[i].y, fmaf(w4.z,xr[i].z, fmaf(w4.w,xr[i].w, acc))));
    }
    acc += __shfl_xor(acc, 16);
    acc += __shfl_xor(acc, 32);
    if (lane < 16) Kproj[(size_t)(row0 + r)*HH + hk] = acc + bk[hk];
  }
}

__global__ __launch_bounds__(TPB, 1) void decoder_persist(KArgs a){
  __shared__ Smem S;
  const int bid = blockIdx.x, tid = threadIdx.x;
  const int wave = tid >> 6, lane = tid & 63;
  const int lb = lane & 15, lg = lane >> 4;
  const int j0 = bid*2;
  const int ba = bid >> 4, tb = (bid & 15) * 16;   // attention assignment

  // ---- one-time: weights to LDS ----
  for (int g = 0; g < 4; ++g){
    for (int jj = 0; jj < 2; ++jj){
      const int row = g*HH + j0 + jj;
      for (int h = tid; h < HH; h += TPB){
        S.W0e[g][jj][h] = a.Wih0[(size_t)row*(2*HH) + h];
        S.W0c[g][jj][h] = a.Wih0[(size_t)row*(2*HH) + HH + h];
        S.W0h[g][jj][h] = a.Whh0[(size_t)row*HH + h];
        S.W1x[g][jj][h] = a.Wih1[(size_t)row*HH + h];
        S.W1h[g][jj][h] = a.Whh1[(size_t)row*HH + h];
      }
    }
  }
  for (int jj = 0; jj < 2; ++jj){
    const int d = bid*2 + jj, vo = d & 31;
    for (int h = tid; h < HH; h += TPB){
      S.Wqr[jj][h] = a.Wq[(size_t)(j0+jj)*HH + h];
      S.Wor[jj][h] = a.Wout[(size_t)vo*HH + h];
    }
  }
  for (int h = tid; h < HH; h += TPB) S.vv[h] = a.vatt[h];
  if (tid < 16){
    S.cst[0][0][tid] = a.c0in[0*BB*HH + tid*HH + j0];
    S.cst[0][1][tid] = a.c0in[0*BB*HH + tid*HH + j0 + 1];
    S.cst[1][0][tid] = a.c0in[1*BB*HH + tid*HH + j0];
    S.cst[1][1][tid] = a.c0in[1*BB*HH + tid*HH + j0 + 1];
  }
  if (tid < 8){
    const int g = tid & 3, jj = tid >> 2;
    const int row = g*HH + j0 + jj;
    S.bs0[g][jj] = a.bih0[row] + a.bhh0[row];
    S.bs1[g][jj] = a.bih1[row] + a.bhh1[row];
  }
  if (tid < 2){
    S.bqv[tid] = a.bq[j0 + tid];
    S.boutv[tid] = a.bout[(bid*2 + tid) & 31];
  }
  const float vb0 = a.vb[0];
  __syncthreads();

  int e = 0;
  for (int t = 0; t < TT; ++t){
    const int par = t & 1, parn = par ^ 1;

    // ================= Phase A =================
    if (tid < 32) a.Ug[bid*32 + tid] = 0.0f;
    if (bid == 0 && tid < 16) a.Zg[tid] = 0.0f;

    // issue h1 + h0 loads up front (reg-staged)
    float4 r_h1[8], r_h0[8];
    {
      const float* h1p = a.H1buf + par*(BB*HH);
      const float* h0p = a.H0buf + par*(BB*HH);
      #pragma unroll
      for (int it = 0; it < 8; ++it){
        const int idx = (it*TPB + tid)*4;
        r_h1[it] = *(const float4*)&h1p[idx];
        r_h0[it] = *(const float4*)&h0p[idx];
      }
    }
    #pragma unroll
    for (int it = 0; it < 8; ++it){
      const int idx = (it*TPB + tid)*4;
      *(float4*)&S.stg[idx >> 9][idx & 511] = r_h1[it];
    }
    // issue enc_t loads now (consumed two dots later)
    float4 r_en[8];
    #pragma unroll
    for (int it = 0; it < 8; ++it){
      const int idx = (it*TPB + tid)*4;
      r_en[it] = *(const float4*)&a.enc[(size_t)((idx >> 9)*TT + t)*HH + (idx & 511)];
    }
    __syncthreads();   // h1 staged

    if (wave < 2){
      if (t > 0){   // logits for step t-1 from staged h1
        const int d = bid*2 + wave, bo = d >> 5, vo = d & 31;
        float acc = 0.f;
        #pragma unroll
        for (int k = 0; k < 8; ++k){
          const int h = lane + 64*k;
          acc = fmaf(S.Wor[wave][h], S.stg[bo][h], acc);
        }
        #pragma unroll
        for (int off = 32; off; off >>= 1) acc += __shfl_xor(acc, off);
        if (lane == 0) a.out[(size_t)(bo*TT + (t-1))*VV + vo] = acc + S.boutv[wave];
      }
    } else {      // qW = h1 @ Wq^T + bq  (2 output rows per block)
      const int jj = wave - 2;
      const int off0 = lg * 128;
      float acc = 0.f;
      #pragma unroll 8
      for (int h = 0; h < 128; h += 4){
        const float4 w4 = *(const float4*)&S.Wqr[jj][off0 + h];
        const float4 x4 = *(const float4*)&S.stg[lb][off0 + h];
        acc = fmaf(w4.x,x4.x, fmaf(w4.y,x4.y, fmaf(w4.z,x4.z, fmaf(w4.w,x4.w, acc))));
      }
      acc += __shfl_xor(acc, 16);
      acc += __shfl_xor(acc, 32);
      if (lane < 16) a.qWg[lane*HH + j0 + jj] = acc + S.bqv[jj];
    }
    dot_part(&S.W1h[0][0][0], S.stg, S.red, wave, lane);  // h1 @ Whh1^T
    __syncthreads();
    if (tid < 128){
      const int jj = tid >> 6, l = tid & 63, g = l >> 4, b = l & 15;
      S.pre1[b][g][jj] = S.red[2*jj][l] + S.red[2*jj+1][l] + S.bs1[g][jj];
    }
    #pragma unroll
    for (int it = 0; it < 8; ++it){
      const int idx = (it*TPB + tid)*4;
      *(float4*)&S.stg[idx >> 9][idx & 511] = r_h0[it];
    }
    __syncthreads();   // h0 staged, pre1 done
    dot_part(&S.W0h[0][0][0], S.stg, S.red, wave, lane);  // h0 @ Whh0^T
    __syncthreads();
    if (tid < 128){
      const int jj = tid >> 6, l = tid & 63, g = l >> 4, b = l & 15;
      S.pre0[b][g][jj] = S.red[2*jj][l] + S.red[2*jj+1][l] + S.bs0[g][jj];
    }
    #pragma unroll
    for (int it = 0; it < 8; ++it){
      const int idx = (it*TPB + tid)*4;
      *(float4*)&S.stg[idx >> 9][idx & 511] = r_en[it];
    }
    __syncthreads();   // enc staged, pre0(h) done
    dot_part(&S.W0e[0][0][0], S.stg, S.red, wave, lane);  // enc_t part of Wih0
    // (enc-part combine into pre0 deferred past barrier 2 — red untouched till then)

    // prefetch attention operands (barrier-independent; latency hides under spin)
    float r_kp[4][8];
    #pragma unroll
    for (int i = 0; i < 4; ++i){
      const float* kp = a.Kproj + (size_t)(ba*TT + tb + wave*4 + i)*HH;
      #pragma unroll
      for (int k = 0; k < 8; ++k) r_kp[i][k] = kp[lane + 64*k];
    }
    float r_e0[16], r_e1[16];
    #pragma unroll
    for (int lt = 0; lt < 16; ++lt){
      const float* er = a.enc + (size_t)(ba*TT + tb + lt)*HH;
      r_e0[lt] = er[tid];
      r_e1[lt] = er[tid + 256];
    }

    e++; gbar(a.bar, e, bid);   // barrier 1: qW + zeroed U/Z visible

    // ================= Phase B: attention =================
    {
      for (int h = tid; h < HH; h += TPB) S.qrow[h] = a.qWg[ba*HH + h];
      __syncthreads();
      #pragma unroll
      for (int i = 0; i < 4; ++i){
        float acc = 0.f;
        #pragma unroll
        for (int k = 0; k < 8; ++k){
          const int h = lane + 64*k;
          acc = fmaf(S.vv[h], ftanh(S.qrow[h] + r_kp[i][k]), acc);
        }
        #pragma unroll
        for (int off = 32; off; off >>= 1) acc += __shfl_xor(acc, off);
        if (lane == 0) S.scw[wave*4 + i] = __expf(acc + vb0);  // |score| <= ~18, exp safe
      }
      __syncthreads();
      float u0 = 0.f, u1 = 0.f;
      #pragma unroll
      for (int lt = 0; lt < 16; ++lt){
        const float w = S.scw[lt];
        u0 = fmaf(w, r_e0[lt], u0);
        u1 = fmaf(w, r_e1[lt], u1);
      }
      unsafeAtomicAdd(&a.Ug[ba*HH + tid],       u0);
      unsafeAtomicAdd(&a.Ug[ba*HH + tid + 256], u1);
      if (tid == 0){
        float zs = 0.f;
        #pragma unroll
        for (int lt = 0; lt < 16; ++lt) zs += S.scw[lt];
        unsafeAtomicAdd(&a.Zg[ba], zs);
      }
    }
    e++; gbar(a.bar, e, bid);   // barrier 2: U,Z complete

    // ================= Phase C: LSTM0 =================
    {
      if (tid < 128){   // enc-part combine (red intact from W0e dot)
        const int jj = tid >> 6, l = tid & 63, g = l >> 4, b = l & 15;
        S.pre0[b][g][jj] += S.red[2*jj][l] + S.red[2*jj+1][l];
      }
      #pragma unroll
      for (int it = 0; it < 8; ++it){            // ctx = U/Z -> stg
        const int idx = (it*TPB + tid)*4;
        const int b = idx >> 9, h = idx & 511;
        float4 u4 = *(const float4*)&a.Ug[idx];
        const float zi = 1.0f / a.Zg[b];
        u4.x *= zi; u4.y *= zi; u4.z *= zi; u4.w *= zi;
        *(float4*)&S.stg[b][h] = u4;
      }
      __syncthreads();
      dot_part(&S.W0c[0][0][0], S.stg, S.red, wave, lane);  // ctx part of Wih0
      __syncthreads();
      if (tid < 32){
        const int b = tid & 15, jj = tid >> 4;
        float gv[4];
        #pragma unroll
        for (int g = 0; g < 4; ++g)
          gv[g] = S.pre0[b][g][jj] + S.red[2*jj][g*16+b] + S.red[2*jj+1][g*16+b];
        const float cold = S.cst[0][jj][b];
        const float ii = fsig(gv[0]), ff = fsig(gv[1]);
        const float gg = ftanh(gv[2]), oo = fsig(gv[3]);
        const float cn = ff*cold + ii*gg;
        S.cst[0][jj][b] = cn;
        a.H0buf[parn*(BB*HH) + b*HH + j0 + jj] = oo * ftanh(cn);
      }
    }
    e++; gbar(a.bar, e, bid);   // barrier 3: h0n complete

    // ================= Phase D: LSTM1 =================
    {
      const float* h0p = a.H0buf + parn*(BB*HH);
      #pragma unroll
      for (int it = 0; it < 8; ++it){
        const int idx = (it*TPB + tid)*4;
        *(float4*)&S.stg[idx >> 9][idx & 511] = *(const float4*)&h0p[idx];
      }
      __syncthreads();
      dot_part(&S.W1x[0][0][0], S.stg, S.red, wave, lane);  // h0n @ Wih1^T
      __syncthreads();
      if (tid < 32){
        const int b = tid & 15, jj = tid >> 4;
        float gv[4];
        #pragma unroll
        for (int g = 0; g < 4; ++g)
          gv[g] = S.pre1[b][g][jj] + S.red[2*jj][g*16+b] + S.red[2*jj+1][g*16+b];
        const float cold = S.cst[1][jj][b];
        const float ii = fsig(gv[0]), ff = fsig(gv[1]);
        const float gg = ftanh(gv[2]), oo = fsig(gv[3]);
        const float cn = ff*cold + ii*gg;
        S.cst[1][jj][b] = cn;
        a.H1buf[parn*(BB*HH) + b*HH + j0 + jj] = oo * ftanh(cn);
      }
    }
    e++; gbar(a.bar, e, bid);   // barrier 4: h1n complete -> next step
  }

  // tail: logits for t=255 (final h1 is in H1buf[0] since (255+1)&1==0)
  {
    const float* h1p = a.H1buf + 0;
    #pragma unroll
    for (int it = 0; it < 8; ++it){
      const int idx = (it*TPB + tid)*4;
      *(float4*)&S.stg[idx >> 9][idx & 511] = *(const float4*)&h1p[idx];
    }
    __syncthreads();
    if (wave < 2){
      const int d = bid*2 + wave, bo = d >> 5, vo = d & 31;
      float acc = 0.f;
      #pragma unroll
      for (int k = 0; k < 8; ++k){
        const int h = lane + 64*k;
        acc = fmaf(S.Wor[wave][h], S.stg[bo][h], acc);
      }
      #pragma unroll
      for (int off = 32; off; off >>= 1) acc += __shfl_xor(acc, off);
      if (lane == 0) a.out[(size_t)(bo*TT + 255)*VV + vo] = acc + S.boutv[wave];
    }
  }
}

extern "C" void kernel_launch(void* const* d_in, const int* in_sizes, int n_in,
                              void* d_out, int out_size, void* d_ws, size_t ws_size,
                              hipStream_t stream){
  const float* enc  = (const float*)d_in[0];
  const float* h0in = (const float*)d_in[1];
  const float* c0in = (const float*)d_in[2];
  // d_in[3] audio_lengths: unused by the reference
  const float* Wq   = (const float*)d_in[4];
  const float* bq   = (const float*)d_in[5];
  const float* Wk   = (const float*)d_in[6];
  const float* bk   = (const float*)d_in[7];
  const float* vatt = (const float*)d_in[8];
  const float* vb   = (const float*)d_in[9];
  const float* Wih0 = (const float*)d_in[10];
  const float* bih0 = (const float*)d_in[11];
  const float* Whh0 = (const float*)d_in[12];
  const float* bhh0 = (const float*)d_in[13];
  const float* Wih1 = (const float*)d_in[14];
  const float* bih1 = (const float*)d_in[15];
  const float* Whh1 = (const float*)d_in[16];
  const float* bhh1 = (const float*)d_in[17];
  const float* Wout = (const float*)d_in[18];
  const float* bout = (const float*)d_in[19];

  float* ws    = (float*)d_ws;
  float* Kproj = ws;                               // B*T*H = 2097152
  float* H0buf = Kproj + (size_t)BB*TT*HH;         // 2*B*H
  float* H1buf = H0buf + 2*BB*HH;                  // 2*B*H
  float* qWg   = H1buf + 2*BB*HH;                  // B*H
  float* Ug    = qWg + BB*HH;                      // B*H
  float* Zg    = Ug + BB*HH;                       // B
  int*   bar   = (int*)(Zg + 16);                  // BAR_INTS ints, padded slots

  hipLaunchKernelGGL(init_kernel, dim3(32), dim3(256), 0, stream, h0in, H0buf, H1buf, bar);
  hipLaunchKernelGGL(kproj_kernel, dim3(256), dim3(256), 0, stream, enc, Wk, bk, Kproj);

  KArgs ka;
  ka.enc = enc; ka.c0in = c0in; ka.Wq = Wq; ka.bq = bq; ka.vatt = vatt; ka.vb = vb;
  ka.Wih0 = Wih0; ka.bih0 = bih0; ka.Whh0 = Whh0; ka.bhh0 = bhh0;
  ka.Wih1 = Wih1; ka.bih1 = bih1; ka.Whh1 = Whh1; ka.bhh1 = bhh1;
  ka.Wout = Wout; ka.bout = bout;
  ka.Kproj = Kproj; ka.H0buf = H0buf; ka.H1buf = H1buf;
  ka.qWg = qWg; ka.Ug = Ug; ka.Zg = Zg; ka.bar = bar; ka.out = (float*)d_out;

  void* params[] = { (void*)&ka };
  hipLaunchCooperativeKernel((const void*)decoder_persist, dim3(NBLK), dim3(TPB),
                             params, 0, stream);
}

// Round 5
// 11008.044 us; speedup vs baseline: 1.6757x; 1.5022x over previous
//
#include <hip/hip_runtime.h>

#define HH 512
#define BB 16
#define TT 256
#define VV 32
#define TPB 256
#define NBLK 256
#define PITCH 516   // LDS row pitch (floats)

// barrier layout: padded slots of 32 ints (128B) each
#define BAR_GRP(g)  ((g)*32)        // 8 group counters
#define BAR_ROOT    (8*32)          // root counter
#define BAR_FLAG(g) ((9+(g))*32)    // 8 epoch-flag replicas
#define BAR_INTS    (17*32)

struct KArgs {
  const float* enc; const float* c0in;
  const float* Wq; const float* bq; const float* vatt; const float* vb;
  const float* Wih0; const float* bih0; const float* Whh0; const float* bhh0;
  const float* Wih1; const float* bih1; const float* Whh1; const float* bhh1;
  const float* Wout; const float* bout;
  const float* Kproj; float* H0buf; float* H1buf; float* qWg; float* Ug; float* Zg;
  int* bar; float* out;
};

struct Smem {
  float W0e[4][2][PITCH];   // Wih0[g*512+j][0:512]    (enc_t part)
  float W0c[4][2][PITCH];   // Wih0[g*512+j][512:1024] (ctx part)
  float W0h[4][2][PITCH];   // Whh0
  float W1x[4][2][PITCH];   // Wih1
  float W1h[4][2][PITCH];   // Whh1
  float Wqr[2][PITCH];
  float Wor[2][PITCH];
  float vv[HH];
  float qrow[HH];
  float stg[BB][PITCH];     // staging for h1/h0/enc_t/ctx/h0n
  float red[4][64];         // per-wave dot partials
  float pre0[BB][4][2];     // accumulated gate partials (enc+h0+bias)
  float pre1[BB][4][2];     // (h1+bias)
  float cst[2][2][BB];      // c state [layer][jj][b]
  float scw[16];            // attention exp-weights for this block's t-chunk
  float bs0[4][2];
  float bs1[4][2];
  float bqv[2], boutv[2];
};

__device__ __forceinline__ float fsig(float x){ return 1.0f/(1.0f + __expf(-x)); }
__device__ __forceinline__ float ftanh(float x){
  float ee = __expf(2.0f*x);
  return 1.0f - 2.0f/(ee + 1.0f);
}

__device__ __forceinline__ void stcc(float* p, float v){
  __hip_atomic_store(p, v, __ATOMIC_RELAXED, __HIP_MEMORY_SCOPE_AGENT);
}

// hierarchical device-wide barrier (r2-proven structure, cheaper fences):
// arrival RMW = RELEASE (wbL2, no inv); flag store RELAXED; post-spin ACQUIRE (inv)
__device__ __forceinline__ void gbar(int* __restrict__ bar, int e, int bid){
  __syncthreads();
  if (threadIdx.x == 0){
    const int g = bid & 7;
    int old = __hip_atomic_fetch_add(&bar[BAR_GRP(g)], 1, __ATOMIC_RELEASE, __HIP_MEMORY_SCOPE_AGENT);
    if (old == e*32 - 1){
      int o2 = __hip_atomic_fetch_add(&bar[BAR_ROOT], 1, __ATOMIC_ACQ_REL, __HIP_MEMORY_SCOPE_AGENT);
      if (o2 == e*8 - 1){
        #pragma unroll
        for (int x = 0; x < 8; ++x)
          __hip_atomic_store(&bar[BAR_FLAG(x)], e, __ATOMIC_RELAXED, __HIP_MEMORY_SCOPE_AGENT);
      }
    }
    int spins = 0;
    while (__hip_atomic_load(&bar[BAR_FLAG(g)], __ATOMIC_RELAXED, __HIP_MEMORY_SCOPE_AGENT) < e){
      __builtin_amdgcn_s_sleep(1);
      if (++spins > (1 << 22)) break;   // safety valve: wrong answer beats a hang
    }
    (void)__hip_atomic_load(&bar[BAR_FLAG(g)], __ATOMIC_ACQUIRE, __HIP_MEMORY_SCOPE_AGENT);
  }
  __syncthreads();
}

// wave w handles (jj = w>>1, h-half = w&1); lane = (g<<4)|b ; writes red[w][lane]
__device__ __forceinline__ void dot_part(const float* __restrict__ W,
                                         const float (* __restrict__ stg)[PITCH],
                                         float (* __restrict__ red)[64],
                                         int wave, int lane){
  const int jj = wave >> 1, off = (wave & 1) << 8;
  const int b = lane & 15, g = lane >> 4;
  const float* wrow = W + (size_t)(g*2 + jj)*PITCH + off;
  const float* xrow = &stg[b][off];
  float acc = 0.f;
  #pragma unroll 8
  for (int h = 0; h < 256; h += 4){
    const float4 w4 = *(const float4*)&wrow[h];
    const float4 x4 = *(const float4*)&xrow[h];
    acc = fmaf(w4.x,x4.x, fmaf(w4.y,x4.y, fmaf(w4.z,x4.z, fmaf(w4.w,x4.w, acc))));
  }
  red[wave][lane] = acc;
}

__global__ void init_kernel(const float* __restrict__ h0in, float* __restrict__ H0buf,
                            float* __restrict__ H1buf, float* __restrict__ Ug,
                            float* __restrict__ Zg, int* __restrict__ bar){
  const int i = blockIdx.x*blockDim.x + threadIdx.x;
  if (i < BB*HH){
    H0buf[i] = h0in[i];            // layer 0
    H1buf[i] = h0in[BB*HH + i];    // layer 1
  }
  if (i < 2*BB*HH) Ug[i] = 0.0f;
  if (i < 32) Zg[i] = 0.0f;
  if (i < BAR_INTS) bar[i] = 0;
}

// Kproj = enc @ Wk^T + bk : 256 blocks x 16 (b,t)-rows, x register-cached
__global__ __launch_bounds__(256, 1) void kproj_kernel(const float* __restrict__ enc,
                                                       const float* __restrict__ Wk,
                                                       const float* __restrict__ bk,
                                                       float* __restrict__ Kproj){
  __shared__ float er[BB][PITCH];
  const int bid = blockIdx.x, tid = threadIdx.x;
  const int wave = tid >> 6, lane = tid & 63;
  const int r = lane & 15, q = lane >> 4;
  const int row0 = bid*16;
  #pragma unroll
  for (int it = 0; it < 8; ++it){
    const int idx = (it*256 + tid)*4;
    const int rr = idx >> 9, h = idx & 511;
    *(float4*)&er[rr][h] = *(const float4*)&enc[(size_t)(row0+rr)*HH + h];
  }
  __syncthreads();
  float4 xr[32];
  #pragma unroll
  for (int i = 0; i < 32; ++i) xr[i] = *(const float4*)&er[r][q*128 + i*4];
  for (int k = 0; k < 128; ++k){
    const int hk = wave*128 + k;
    const float* wrow = Wk + (size_t)hk*HH + q*128;
    float acc = 0.f;
    #pragma unroll
    for (int i = 0; i < 32; ++i){
      const float4 w4 = *(const float4*)&wrow[i*4];
      acc = fmaf(w4.x,xr[i].x, fmaf(w4.y,xr[i].y, fmaf(w4.z,xr[i].z, fmaf(w4.w,xr[i].w, acc))));
    }
    acc += __shfl_xor(acc, 16);
    acc += __shfl_xor(acc, 32);
    if (lane < 16) Kproj[(size_t)(row0 + r)*HH + hk] = acc + bk[hk];
  }
}

__global__ __launch_bounds__(TPB, 1) void decoder_persist(KArgs a){
  __shared__ Smem S;
  const int bid = blockIdx.x, tid = threadIdx.x;
  const int wave = tid >> 6, lane = tid & 63;
  const int lb = lane & 15, lg = lane >> 4;
  const int j0 = bid*2;
  const int ba = bid >> 4, tb = (bid & 15) * 16;   // attention assignment

  // ---- one-time: weights to LDS ----
  for (int g = 0; g < 4; ++g){
    for (int jj = 0; jj < 2; ++jj){
      const int row = g*HH + j0 + jj;
      for (int h = tid; h < HH; h += TPB){
        S.W0e[g][jj][h] = a.Wih0[(size_t)row*(2*HH) + h];
        S.W0c[g][jj][h] = a.Wih0[(size_t)row*(2*HH) + HH + h];
        S.W0h[g][jj][h] = a.Whh0[(size_t)row*HH + h];
        S.W1x[g][jj][h] = a.Wih1[(size_t)row*HH + h];
        S.W1h[g][jj][h] = a.Whh1[(size_t)row*HH + h];
      }
    }
  }
  for (int jj = 0; jj < 2; ++jj){
    const int d = bid*2 + jj, vo = d & 31;
    for (int h = tid; h < HH; h += TPB){
      S.Wqr[jj][h] = a.Wq[(size_t)(j0+jj)*HH + h];
      S.Wor[jj][h] = a.Wout[(size_t)vo*HH + h];
    }
  }
  for (int h = tid; h < HH; h += TPB) S.vv[h] = a.vatt[h];
  if (tid < 16){
    S.cst[0][0][tid] = a.c0in[0*BB*HH + tid*HH + j0];
    S.cst[0][1][tid] = a.c0in[0*BB*HH + tid*HH + j0 + 1];
    S.cst[1][0][tid] = a.c0in[1*BB*HH + tid*HH + j0];
    S.cst[1][1][tid] = a.c0in[1*BB*HH + tid*HH + j0 + 1];
  }
  if (tid < 8){
    const int g = tid & 3, jj = tid >> 2;
    const int row = g*HH + j0 + jj;
    S.bs0[g][jj] = a.bih0[row] + a.bhh0[row];
    S.bs1[g][jj] = a.bih1[row] + a.bhh1[row];
  }
  if (tid < 2){
    S.bqv[tid] = a.bq[j0 + tid];
    S.boutv[tid] = a.bout[(bid*2 + tid) & 31];
  }
  const float vb0 = a.vb[0];
  __syncthreads();

  int e = 0;
  for (int t = 0; t < TT; ++t){
    const int par = t & 1, parn = par ^ 1;

    // ================= Phase A =================
    // (Ug/Zg zeroing for the NEXT step now lives in phase D; t=0 done by init)

    // issue h1 + h0 loads up front (reg-staged)
    float4 r_h1[8], r_h0[8];
    {
      const float* h1p = a.H1buf + par*(BB*HH);
      const float* h0p = a.H0buf + par*(BB*HH);
      #pragma unroll
      for (int it = 0; it < 8; ++it){
        const int idx = (it*TPB + tid)*4;
        r_h1[it] = *(const float4*)&h1p[idx];
        r_h0[it] = *(const float4*)&h0p[idx];
      }
    }
    #pragma unroll
    for (int it = 0; it < 8; ++it){
      const int idx = (it*TPB + tid)*4;
      *(float4*)&S.stg[idx >> 9][idx & 511] = r_h1[it];
    }
    // issue enc_t loads now (consumed two dots later)
    float4 r_en[8];
    #pragma unroll
    for (int it = 0; it < 8; ++it){
      const int idx = (it*TPB + tid)*4;
      r_en[it] = *(const float4*)&a.enc[(size_t)((idx >> 9)*TT + t)*HH + (idx & 511)];
    }
    __syncthreads();   // h1 staged

    if (wave < 2){
      if (t > 0){   // logits for step t-1 from staged h1
        const int d = bid*2 + wave, bo = d >> 5, vo = d & 31;
        float acc = 0.f;
        #pragma unroll
        for (int k = 0; k < 8; ++k){
          const int h = lane + 64*k;
          acc = fmaf(S.Wor[wave][h], S.stg[bo][h], acc);
        }
        #pragma unroll
        for (int off = 32; off; off >>= 1) acc += __shfl_xor(acc, off);
        if (lane == 0) a.out[(size_t)(bo*TT + (t-1))*VV + vo] = acc + S.boutv[wave];
      }
    } else {      // qW = h1 @ Wq^T + bq  (2 output rows per block)
      const int jj = wave - 2;
      const int off0 = lg * 128;
      float acc = 0.f;
      #pragma unroll 8
      for (int h = 0; h < 128; h += 4){
        const float4 w4 = *(const float4*)&S.Wqr[jj][off0 + h];
        const float4 x4 = *(const float4*)&S.stg[lb][off0 + h];
        acc = fmaf(w4.x,x4.x, fmaf(w4.y,x4.y, fmaf(w4.z,x4.z, fmaf(w4.w,x4.w, acc))));
      }
      acc += __shfl_xor(acc, 16);
      acc += __shfl_xor(acc, 32);
      if (lane < 16) stcc(&a.qWg[lane*HH + j0 + jj], acc + S.bqv[jj]);
    }
    dot_part(&S.W1h[0][0][0], S.stg, S.red, wave, lane);  // h1 @ Whh1^T
    __syncthreads();
    if (tid < 128){
      const int jj = tid >> 6, l = tid & 63, g = l >> 4, b = l & 15;
      S.pre1[b][g][jj] = S.red[2*jj][l] + S.red[2*jj+1][l] + S.bs1[g][jj];
    }
    #pragma unroll
    for (int it = 0; it < 8; ++it){
      const int idx = (it*TPB + tid)*4;
      *(float4*)&S.stg[idx >> 9][idx & 511] = r_h0[it];
    }
    __syncthreads();   // h0 staged, pre1 done
    dot_part(&S.W0h[0][0][0], S.stg, S.red, wave, lane);  // h0 @ Whh0^T
    __syncthreads();
    if (tid < 128){
      const int jj = tid >> 6, l = tid & 63, g = l >> 4, b = l & 15;
      S.pre0[b][g][jj] = S.red[2*jj][l] + S.red[2*jj+1][l] + S.bs0[g][jj];
    }
    #pragma unroll
    for (int it = 0; it < 8; ++it){
      const int idx = (it*TPB + tid)*4;
      *(float4*)&S.stg[idx >> 9][idx & 511] = r_en[it];
    }
    __syncthreads();   // enc staged, pre0(h) done
    dot_part(&S.W0e[0][0][0], S.stg, S.red, wave, lane);  // enc_t part of Wih0
    // (enc-part combine into pre0 deferred past barrier 2 — red untouched till then)

    // prefetch attention operands (barrier-independent; latency hides under spin)
    float r_kp[4][8];
    #pragma unroll
    for (int i = 0; i < 4; ++i){
      const float* kp = a.Kproj + (size_t)(ba*TT + tb + wave*4 + i)*HH;
      #pragma unroll
      for (int k = 0; k < 8; ++k) r_kp[i][k] = kp[lane + 64*k];
    }
    float r_e0[16], r_e1[16];
    #pragma unroll
    for (int lt = 0; lt < 16; ++lt){
      const float* er = a.enc + (size_t)(ba*TT + tb + lt)*HH;
      r_e0[lt] = er[tid];
      r_e1[lt] = er[tid + 256];
    }

    e++; gbar(a.bar, e, bid);   // barrier 1: qW visible

    // ================= Phase B: attention =================
    {
      float* Up = a.Ug + par*(BB*HH);
      float* Zp = a.Zg + par*16;
      for (int h = tid; h < HH; h += TPB) S.qrow[h] = a.qWg[ba*HH + h];
      __syncthreads();
      #pragma unroll
      for (int i = 0; i < 4; ++i){
        float acc = 0.f;
        #pragma unroll
        for (int k = 0; k < 8; ++k){
          const int h = lane + 64*k;
          acc = fmaf(S.vv[h], ftanh(S.qrow[h] + r_kp[i][k]), acc);
        }
        #pragma unroll
        for (int off = 32; off; off >>= 1) acc += __shfl_xor(acc, off);
        if (lane == 0) S.scw[wave*4 + i] = __expf(acc + vb0);  // |score| <= ~18, exp safe
      }
      __syncthreads();
      float u0 = 0.f, u1 = 0.f;
      #pragma unroll
      for (int lt = 0; lt < 16; ++lt){
        const float w = S.scw[lt];
        u0 = fmaf(w, r_e0[lt], u0);
        u1 = fmaf(w, r_e1[lt], u1);
      }
      unsafeAtomicAdd(&Up[ba*HH + tid],       u0);
      unsafeAtomicAdd(&Up[ba*HH + tid + 256], u1);
      if (tid == 0){
        float zs = 0.f;
        #pragma unroll
        for (int lt = 0; lt < 16; ++lt) zs += S.scw[lt];
        unsafeAtomicAdd(&Zp[ba], zs);
      }
    }
    e++; gbar(a.bar, e, bid);   // barrier 2: U,Z complete

    // ================= Phase C: LSTM0 =================
    {
      // issue ctx loads FIRST so latency hides under the combine below
      const float* Up = a.Ug + par*(BB*HH);
      const float* Zp = a.Zg + par*16;
      float4 r_u[8]; float r_z[8];
      #pragma unroll
      for (int it = 0; it < 8; ++it){
        const int idx = (it*TPB + tid)*4;
        r_u[it] = *(const float4*)&Up[idx];
        r_z[it] = Zp[idx >> 9];
      }
      if (tid < 128){   // enc-part combine (red intact from W0e dot)
        const int jj = tid >> 6, l = tid & 63, g = l >> 4, b = l & 15;
        S.pre0[b][g][jj] += S.red[2*jj][l] + S.red[2*jj+1][l];
      }
      #pragma unroll
      for (int it = 0; it < 8; ++it){            // ctx = U/Z -> stg
        const int idx = (it*TPB + tid)*4;
        const float zi = 1.0f / r_z[it];
        float4 u4 = r_u[it];
        u4.x *= zi; u4.y *= zi; u4.z *= zi; u4.w *= zi;
        *(float4*)&S.stg[idx >> 9][idx & 511] = u4;
      }
      __syncthreads();
      dot_part(&S.W0c[0][0][0], S.stg, S.red, wave, lane);  // ctx part of Wih0
      __syncthreads();
      if (tid < 32){
        const int b = tid & 15, jj = tid >> 4;
        float gv[4];
        #pragma unroll
        for (int g = 0; g < 4; ++g)
          gv[g] = S.pre0[b][g][jj] + S.red[2*jj][g*16+b] + S.red[2*jj+1][g*16+b];
        const float cold = S.cst[0][jj][b];
        const float ii = fsig(gv[0]), ff = fsig(gv[1]);
        const float gg = ftanh(gv[2]), oo = fsig(gv[3]);
        const float cn = ff*cold + ii*gg;
        S.cst[0][jj][b] = cn;
        stcc(&a.H0buf[parn*(BB*HH) + b*HH + j0 + jj], oo * ftanh(cn));
      }
    }
    e++; gbar(a.bar, e, bid);   // barrier 3: h0n complete

    // ================= Phase D: LSTM1 =================
    {
      // zero next step's U/Z buffers (visibility rides barrier 4)
      if (tid < 32) stcc(&a.Ug[parn*(BB*HH) + bid*32 + tid], 0.0f);
      if (bid == 0 && tid < 16) stcc(&a.Zg[parn*16 + tid], 0.0f);

      const float* h0p = a.H0buf + parn*(BB*HH);
      #pragma unroll
      for (int it = 0; it < 8; ++it){
        const int idx = (it*TPB + tid)*4;
        *(float4*)&S.stg[idx >> 9][idx & 511] = *(const float4*)&h0p[idx];
      }
      __syncthreads();
      dot_part(&S.W1x[0][0][0], S.stg, S.red, wave, lane);  // h0n @ Wih1^T
      __syncthreads();
      if (tid < 32){
        const int b = tid & 15, jj = tid >> 4;
        float gv[4];
        #pragma unroll
        for (int g = 0; g < 4; ++g)
          gv[g] = S.pre1[b][g][jj] + S.red[2*jj][g*16+b] + S.red[2*jj+1][g*16+b];
        const float cold = S.cst[1][jj][b];
        const float ii = fsig(gv[0]), ff = fsig(gv[1]);
        const float gg = ftanh(gv[2]), oo = fsig(gv[3]);
        const float cn = ff*cold + ii*gg;
        S.cst[1][jj][b] = cn;
        stcc(&a.H1buf[parn*(BB*HH) + b*HH + j0 + jj], oo * ftanh(cn));
      }
    }
    e++; gbar(a.bar, e, bid);   // barrier 4: h1n complete -> next step
  }

  // tail: logits for t=255 (final h1 is in H1buf[0] since (255+1)&1==0)
  {
    const float* h1p = a.H1buf + 0;
    #pragma unroll
    for (int it = 0; it < 8; ++it){
      const int idx = (it*TPB + tid)*4;
      *(float4*)&S.stg[idx >> 9][idx & 511] = *(const float4*)&h1p[idx];
    }
    __syncthreads();
    if (wave < 2){
      const int d = bid*2 + wave, bo = d >> 5, vo = d & 31;
      float acc = 0.f;
      #pragma unroll
      for (int k = 0; k < 8; ++k){
        const int h = lane + 64*k;
        acc = fmaf(S.Wor[wave][h], S.stg[bo][h], acc);
      }
      #pragma unroll
      for (int off = 32; off; off >>= 1) acc += __shfl_xor(acc, off);
      if (lane == 0) a.out[(size_t)(bo*TT + 255)*VV + vo] = acc + S.boutv[wave];
    }
  }
}

extern "C" void kernel_launch(void* const* d_in, const int* in_sizes, int n_in,
                              void* d_out, int out_size, void* d_ws, size_t ws_size,
                              hipStream_t stream){
  const float* enc  = (const float*)d_in[0];
  const float* h0in = (const float*)d_in[1];
  const float* c0in = (const float*)d_in[2];
  // d_in[3] audio_lengths: unused by the reference
  const float* Wq   = (const float*)d_in[4];
  const float* bq   = (const float*)d_in[5];
  const float* Wk   = (const float*)d_in[6];
  const float* bk   = (const float*)d_in[7];
  const float* vatt = (const float*)d_in[8];
  const float* vb   = (const float*)d_in[9];
  const float* Wih0 = (const float*)d_in[10];
  const float* bih0 = (const float*)d_in[11];
  const float* Whh0 = (const float*)d_in[12];
  const float* bhh0 = (const float*)d_in[13];
  const float* Wih1 = (const float*)d_in[14];
  const float* bih1 = (const float*)d_in[15];
  const float* Whh1 = (const float*)d_in[16];
  const float* bhh1 = (const float*)d_in[17];
  const float* Wout = (const float*)d_in[18];
  const float* bout = (const float*)d_in[19];

  float* ws    = (float*)d_ws;
  float* Kproj = ws;                               // B*T*H = 2097152
  float* H0buf = Kproj + (size_t)BB*TT*HH;         // 2*B*H
  float* H1buf = H0buf + 2*BB*HH;                  // 2*B*H
  float* qWg   = H1buf + 2*BB*HH;                  // B*H
  float* Ug    = qWg + BB*HH;                      // 2*B*H (parity double-buffer)
  float* Zg    = Ug + 2*BB*HH;                     // 2*16
  int*   bar   = (int*)(Zg + 32);                  // BAR_INTS ints, padded slots

  hipLaunchKernelGGL(init_kernel, dim3(64), dim3(256), 0, stream,
                     h0in, H0buf, H1buf, Ug, Zg, bar);
  hipLaunchKernelGGL(kproj_kernel, dim3(256), dim3(256), 0, stream, enc, Wk, bk, Kproj);

  KArgs ka;
  ka.enc = enc; ka.c0in = c0in; ka.Wq = Wq; ka.bq = bq; ka.vatt = vatt; ka.vb = vb;
  ka.Wih0 = Wih0; ka.bih0 = bih0; ka.Whh0 = Whh0; ka.bhh0 = bhh0;
  ka.Wih1 = Wih1; ka.bih1 = bih1; ka.Whh1 = Whh1; ka.bhh1 = bhh1;
  ka.Wout = Wout; ka.bout = bout;
  ka.Kproj = Kproj; ka.H0buf = H0buf; ka.H1buf = H1buf;
  ka.qWg = qWg; ka.Ug = Ug; ka.Zg = Zg; ka.bar = bar; ka.out = (float*)d_out;

  void* params[] = { (void*)&ka };
  hipLaunchCooperativeKernel((const void*)decoder_persist, dim3(NBLK), dim3(TPB),
                             params, 0, stream);
}

// Round 6
// 9349.716 us; speedup vs baseline: 1.9729x; 1.1774x over previous
//
#include <hip/hip_runtime.h>

#define HH 512
#define BB 16
#define TT 256
#define VV 32
#define TPB 256
#define NBLK 256
#define PITCH 516   // LDS row pitch (floats)

#define BAR_INTS 256   // one epoch slot per block

struct KArgs {
  const float* enc; const float* c0in;
  const float* Wq; const float* bq; const float* vatt; const float* vb;
  const float* Wih0; const float* bih0; const float* Whh0; const float* bhh0;
  const float* Wih1; const float* bih1; const float* Whh1; const float* bhh1;
  const float* Wout; const float* bout;
  const float* Kproj; float* H0buf; float* H1buf; float* qWg; float* Ug; float* Zg;
  int* bar; float* out;
};

struct Smem {
  float W0e[4][2][PITCH];   // Wih0[g*512+j][0:512]    (enc_t part)
  float W0c[4][2][PITCH];   // Wih0[g*512+j][512:1024] (ctx part)
  float W0h[4][2][PITCH];   // Whh0
  float W1x[4][2][PITCH];   // Wih1
  float W1h[4][2][PITCH];   // Whh1
  float Wqr[2][PITCH];
  float Wor[2][PITCH];
  float vv[HH];
  float qrow[HH];
  float stg[BB][PITCH];     // staging for h1/h0/enc_t/ctx/h0n
  float red[4][64];         // per-wave dot partials
  float pre0[BB][4][2];     // accumulated gate partials (enc+h0+bias)
  float pre1[BB][4][2];     // (h1+bias)
  float cst[2][2][BB];      // c state [layer][jj][b]
  float scw[16];            // attention exp-weights for this block's t-chunk
  float bs0[4][2];
  float bs1[4][2];
  float bqv[2], boutv[2];
};

__device__ __forceinline__ float fsig(float x){ return 1.0f/(1.0f + __expf(-x)); }
__device__ __forceinline__ float ftanh(float x){
  float ee = __expf(2.0f*x);
  return 1.0f - 2.0f/(ee + 1.0f);
}

// relaxed agent-scope (cross-XCD coherent, write-through, no wb/inv) accessors
__device__ __forceinline__ void stcc(float* p, float v){
  __hip_atomic_store(p, v, __ATOMIC_RELAXED, __HIP_MEMORY_SCOPE_AGENT);
}
__device__ __forceinline__ float ldcc(const float* p){
  return __hip_atomic_load(p, __ATOMIC_RELAXED, __HIP_MEMORY_SCOPE_AGENT);
}
__device__ __forceinline__ float2 ld2cc(const float* p){
  unsigned long long v = __hip_atomic_load((const unsigned long long*)p,
                                           __ATOMIC_RELAXED, __HIP_MEMORY_SCOPE_AGENT);
  union { unsigned long long u; float2 f; } c; c.u = v;
  return c.f;
}

// fence-free device barrier:
//   syncthreads (compiler drains vmcnt -> all this block's coherent stores complete)
//   tid0 posts epoch to its slot; wave 0 sweeps all 256 slots in parallel (ballot)
__device__ __forceinline__ void gbar(int* __restrict__ bar, int e){
  __syncthreads();
  if (threadIdx.x == 0)
    __hip_atomic_store(&bar[blockIdx.x], e, __ATOMIC_RELAXED, __HIP_MEMORY_SCOPE_AGENT);
  if (threadIdx.x < 64){
    const unsigned long long* p = (const unsigned long long*)bar;   // 128 ulls
    const int i0 = threadIdx.x * 2;
    int spins = 0;
    for (;;){
      unsigned long long v0 = __hip_atomic_load(&p[i0],     __ATOMIC_RELAXED, __HIP_MEMORY_SCOPE_AGENT);
      unsigned long long v1 = __hip_atomic_load(&p[i0 + 1], __ATOMIC_RELAXED, __HIP_MEMORY_SCOPE_AGENT);
      const int a0 = (int)v0, a1 = (int)(v0 >> 32), a2 = (int)v1, a3 = (int)(v1 >> 32);
      const int ok = (a0 >= e) & (a1 >= e) & (a2 >= e) & (a3 >= e);
      if (__all(ok)) break;
      if (++spins > (1 << 20)) break;   // safety valve: wrong answer beats a hang
    }
  }
  __syncthreads();
}

// stage 16x512 coherent buffer -> LDS (16 x 8B atomic loads, batched, then LDS writes)
__device__ __forceinline__ void stage_cc(const float* __restrict__ src,
                                         float (* __restrict__ stg)[PITCH], int tid){
  float2 v[16];
  #pragma unroll
  for (int it = 0; it < 8; ++it){
    const int idx = (it*TPB + tid)*4;
    v[2*it]   = ld2cc(&src[idx]);
    v[2*it+1] = ld2cc(&src[idx + 2]);
  }
  #pragma unroll
  for (int it = 0; it < 8; ++it){
    const int idx = (it*TPB + tid)*4;
    float4 w; w.x = v[2*it].x; w.y = v[2*it].y; w.z = v[2*it+1].x; w.w = v[2*it+1].y;
    *(float4*)&stg[idx >> 9][idx & 511] = w;
  }
}

// wave w handles (jj = w>>1, h-half = w&1); lane = (g<<4)|b ; writes red[w][lane]
__device__ __forceinline__ void dot_part(const float* __restrict__ W,
                                         const float (* __restrict__ stg)[PITCH],
                                         float (* __restrict__ red)[64],
                                         int wave, int lane){
  const int jj = wave >> 1, off = (wave & 1) << 8;
  const int b = lane & 15, g = lane >> 4;
  const float* wrow = W + (size_t)(g*2 + jj)*PITCH + off;
  const float* xrow = &stg[b][off];
  float acc = 0.f;
  #pragma unroll 8
  for (int h = 0; h < 256; h += 4){
    const float4 w4 = *(const float4*)&wrow[h];
    const float4 x4 = *(const float4*)&xrow[h];
    acc = fmaf(w4.x,x4.x, fmaf(w4.y,x4.y, fmaf(w4.z,x4.z, fmaf(w4.w,x4.w, acc))));
  }
  red[wave][lane] = acc;
}

__global__ void init_kernel(const float* __restrict__ h0in, float* __restrict__ H0buf,
                            float* __restrict__ H1buf, float* __restrict__ Ug,
                            float* __restrict__ Zg, int* __restrict__ bar){
  const int i = blockIdx.x*blockDim.x + threadIdx.x;
  if (i < BB*HH){
    H0buf[i] = h0in[i];            // layer 0
    H1buf[i] = h0in[BB*HH + i];    // layer 1
  }
  if (i < 2*BB*HH) Ug[i] = 0.0f;
  if (i < 32) Zg[i] = 0.0f;
  if (i < BAR_INTS) bar[i] = 0;
}

// Kproj = enc @ Wk^T + bk : 256 blocks x 16 (b,t)-rows, x register-cached
__global__ __launch_bounds__(256, 1) void kproj_kernel(const float* __restrict__ enc,
                                                       const float* __restrict__ Wk,
                                                       const float* __restrict__ bk,
                                                       float* __restrict__ Kproj){
  __shared__ float er[BB][PITCH];
  const int bid = blockIdx.x, tid = threadIdx.x;
  const int wave = tid >> 6, lane = tid & 63;
  const int r = lane & 15, q = lane >> 4;
  const int row0 = bid*16;
  #pragma unroll
  for (int it = 0; it < 8; ++it){
    const int idx = (it*256 + tid)*4;
    const int rr = idx >> 9, h = idx & 511;
    *(float4*)&er[rr][h] = *(const float4*)&enc[(size_t)(row0+rr)*HH + h];
  }
  __syncthreads();
  float4 xr[32];
  #pragma unroll
  for (int i = 0; i < 32; ++i) xr[i] = *(const float4*)&er[r][q*128 + i*4];
  for (int k = 0; k < 128; ++k){
    const int hk = wave*128 + k;
    const float* wrow = Wk + (size_t)hk*HH + q*128;
    float acc = 0.f;
    #pragma unroll
    for (int i = 0; i < 32; ++i){
      const float4 w4 = *(const float4*)&wrow[i*4];
      acc = fmaf(w4.x,xr[i].x, fmaf(w4.y,xr[i].y, fmaf(w4.z,xr[i].z, fmaf(w4.w,xr[i].w, acc))));
    }
    acc += __shfl_xor(acc, 16);
    acc += __shfl_xor(acc, 32);
    if (lane < 16) Kproj[(size_t)(row0 + r)*HH + hk] = acc + bk[hk];
  }
}

__global__ __launch_bounds__(TPB, 1) void decoder_persist(KArgs a){
  __shared__ Smem S;
  const int bid = blockIdx.x, tid = threadIdx.x;
  const int wave = tid >> 6, lane = tid & 63;
  const int lb = lane & 15, lg = lane >> 4;
  const int j0 = bid*2;
  const int ba = bid >> 4, tb = (bid & 15) * 16;   // attention assignment

  // ---- one-time: weights to LDS ----
  for (int g = 0; g < 4; ++g){
    for (int jj = 0; jj < 2; ++jj){
      const int row = g*HH + j0 + jj;
      for (int h = tid; h < HH; h += TPB){
        S.W0e[g][jj][h] = a.Wih0[(size_t)row*(2*HH) + h];
        S.W0c[g][jj][h] = a.Wih0[(size_t)row*(2*HH) + HH + h];
        S.W0h[g][jj][h] = a.Whh0[(size_t)row*HH + h];
        S.W1x[g][jj][h] = a.Wih1[(size_t)row*HH + h];
        S.W1h[g][jj][h] = a.Whh1[(size_t)row*HH + h];
      }
    }
  }
  for (int jj = 0; jj < 2; ++jj){
    const int d = bid*2 + jj, vo = d & 31;
    for (int h = tid; h < HH; h += TPB){
      S.Wqr[jj][h] = a.Wq[(size_t)(j0+jj)*HH + h];
      S.Wor[jj][h] = a.Wout[(size_t)vo*HH + h];
    }
  }
  for (int h = tid; h < HH; h += TPB) S.vv[h] = a.vatt[h];
  if (tid < 16){
    S.cst[0][0][tid] = a.c0in[0*BB*HH + tid*HH + j0];
    S.cst[0][1][tid] = a.c0in[0*BB*HH + tid*HH + j0 + 1];
    S.cst[1][0][tid] = a.c0in[1*BB*HH + tid*HH + j0];
    S.cst[1][1][tid] = a.c0in[1*BB*HH + tid*HH + j0 + 1];
  }
  if (tid < 8){
    const int g = tid & 3, jj = tid >> 2;
    const int row = g*HH + j0 + jj;
    S.bs0[g][jj] = a.bih0[row] + a.bhh0[row];
    S.bs1[g][jj] = a.bih1[row] + a.bhh1[row];
  }
  if (tid < 2){
    S.bqv[tid] = a.bq[j0 + tid];
    S.boutv[tid] = a.bout[(bid*2 + tid) & 31];
  }
  const float vb0 = a.vb[0];
  __syncthreads();

  int e = 0;
  for (int t = 0; t < TT; ++t){
    const int par = t & 1, parn = par ^ 1;

    // ================= Phase A =================
    // issue coherent h1 + h0 loads up front (batched 8B atomic loads)
    float2 r_h1[16], r_h0[16];
    {
      const float* h1p = a.H1buf + par*(BB*HH);
      const float* h0p = a.H0buf + par*(BB*HH);
      #pragma unroll
      for (int it = 0; it < 8; ++it){
        const int idx = (it*TPB + tid)*4;
        r_h1[2*it]   = ld2cc(&h1p[idx]);
        r_h1[2*it+1] = ld2cc(&h1p[idx + 2]);
      }
      #pragma unroll
      for (int it = 0; it < 8; ++it){
        const int idx = (it*TPB + tid)*4;
        r_h0[2*it]   = ld2cc(&h0p[idx]);
        r_h0[2*it+1] = ld2cc(&h0p[idx + 2]);
      }
    }
    // enc_t loads (read-only, plain cached)
    float4 r_en[8];
    #pragma unroll
    for (int it = 0; it < 8; ++it){
      const int idx = (it*TPB + tid)*4;
      r_en[it] = *(const float4*)&a.enc[(size_t)((idx >> 9)*TT + t)*HH + (idx & 511)];
    }
    #pragma unroll
    for (int it = 0; it < 8; ++it){
      const int idx = (it*TPB + tid)*4;
      float4 w; w.x=r_h1[2*it].x; w.y=r_h1[2*it].y; w.z=r_h1[2*it+1].x; w.w=r_h1[2*it+1].y;
      *(float4*)&S.stg[idx >> 9][idx & 511] = w;
    }
    __syncthreads();   // h1 staged

    if (wave < 2){
      if (t > 0){   // logits for step t-1 from staged h1
        const int d = bid*2 + wave, bo = d >> 5, vo = d & 31;
        float acc = 0.f;
        #pragma unroll
        for (int k = 0; k < 8; ++k){
          const int h = lane + 64*k;
          acc = fmaf(S.Wor[wave][h], S.stg[bo][h], acc);
        }
        #pragma unroll
        for (int off = 32; off; off >>= 1) acc += __shfl_xor(acc, off);
        if (lane == 0) a.out[(size_t)(bo*TT + (t-1))*VV + vo] = acc + S.boutv[wave];
      }
    } else {      // qW = h1 @ Wq^T + bq  (2 output rows per block)
      const int jj = wave - 2;
      const int off0 = lg * 128;
      float acc = 0.f;
      #pragma unroll 8
      for (int h = 0; h < 128; h += 4){
        const float4 w4 = *(const float4*)&S.Wqr[jj][off0 + h];
        const float4 x4 = *(const float4*)&S.stg[lb][off0 + h];
        acc = fmaf(w4.x,x4.x, fmaf(w4.y,x4.y, fmaf(w4.z,x4.z, fmaf(w4.w,x4.w, acc))));
      }
      acc += __shfl_xor(acc, 16);
      acc += __shfl_xor(acc, 32);
      if (lane < 16) stcc(&a.qWg[lane*HH + j0 + jj], acc + S.bqv[jj]);
    }
    dot_part(&S.W1h[0][0][0], S.stg, S.red, wave, lane);  // h1 @ Whh1^T
    __syncthreads();
    if (tid < 128){
      const int jj = tid >> 6, l = tid & 63, g = l >> 4, b = l & 15;
      S.pre1[b][g][jj] = S.red[2*jj][l] + S.red[2*jj+1][l] + S.bs1[g][jj];
    }
    #pragma unroll
    for (int it = 0; it < 8; ++it){
      const int idx = (it*TPB + tid)*4;
      float4 w; w.x=r_h0[2*it].x; w.y=r_h0[2*it].y; w.z=r_h0[2*it+1].x; w.w=r_h0[2*it+1].y;
      *(float4*)&S.stg[idx >> 9][idx & 511] = w;
    }
    __syncthreads();   // h0 staged, pre1 done
    dot_part(&S.W0h[0][0][0], S.stg, S.red, wave, lane);  // h0 @ Whh0^T
    __syncthreads();
    if (tid < 128){
      const int jj = tid >> 6, l = tid & 63, g = l >> 4, b = l & 15;
      S.pre0[b][g][jj] = S.red[2*jj][l] + S.red[2*jj+1][l] + S.bs0[g][jj];
    }
    #pragma unroll
    for (int it = 0; it < 8; ++it){
      const int idx = (it*TPB + tid)*4;
      *(float4*)&S.stg[idx >> 9][idx & 511] = r_en[it];
    }
    __syncthreads();   // enc staged, pre0(h) done
    dot_part(&S.W0e[0][0][0], S.stg, S.red, wave, lane);  // enc_t part of Wih0
    // (enc-part combine into pre0 deferred past barrier 2 — red untouched till then)

    // prefetch attention operands (read-only; latency hides under barrier)
    float r_kp[4][8];
    #pragma unroll
    for (int i = 0; i < 4; ++i){
      const float* kp = a.Kproj + (size_t)(ba*TT + tb + wave*4 + i)*HH;
      #pragma unroll
      for (int k = 0; k < 8; ++k) r_kp[i][k] = kp[lane + 64*k];
    }
    float r_e0[16], r_e1[16];
    #pragma unroll
    for (int lt = 0; lt < 16; ++lt){
      const float* er = a.enc + (size_t)(ba*TT + tb + lt)*HH;
      r_e0[lt] = er[tid];
      r_e1[lt] = er[tid + 256];
    }

    e++; gbar(a.bar, e);   // barrier 1: qW visible

    // ================= Phase B: attention =================
    {
      float* Up = a.Ug + par*(BB*HH);
      float* Zp = a.Zg + par*16;
      const float q0 = ldcc(&a.qWg[ba*HH + tid]);
      const float q1 = ldcc(&a.qWg[ba*HH + tid + 256]);
      S.qrow[tid] = q0; S.qrow[tid + 256] = q1;
      __syncthreads();
      #pragma unroll
      for (int i = 0; i < 4; ++i){
        float acc = 0.f;
        #pragma unroll
        for (int k = 0; k < 8; ++k){
          const int h = lane + 64*k;
          acc = fmaf(S.vv[h], ftanh(S.qrow[h] + r_kp[i][k]), acc);
        }
        #pragma unroll
        for (int off = 32; off; off >>= 1) acc += __shfl_xor(acc, off);
        if (lane == 0) S.scw[wave*4 + i] = __expf(acc + vb0);  // |score| <= ~18, exp safe
      }
      __syncthreads();
      float u0 = 0.f, u1 = 0.f;
      #pragma unroll
      for (int lt = 0; lt < 16; ++lt){
        const float w = S.scw[lt];
        u0 = fmaf(w, r_e0[lt], u0);
        u1 = fmaf(w, r_e1[lt], u1);
      }
      unsafeAtomicAdd(&Up[ba*HH + tid],       u0);
      unsafeAtomicAdd(&Up[ba*HH + tid + 256], u1);
      if (tid == 0){
        float zs = 0.f;
        #pragma unroll
        for (int lt = 0; lt < 16; ++lt) zs += S.scw[lt];
        unsafeAtomicAdd(&Zp[ba], zs);
      }
    }
    e++; gbar(a.bar, e);   // barrier 2: U,Z complete

    // ================= Phase C: LSTM0 =================
    {
      // issue ctx loads FIRST so latency hides under the combine below
      const float* Up = a.Ug + par*(BB*HH);
      const float* Zp = a.Zg + par*16;
      float2 r_u[16]; float r_z[8];
      #pragma unroll
      for (int it = 0; it < 8; ++it){
        const int idx = (it*TPB + tid)*4;
        r_u[2*it]   = ld2cc(&Up[idx]);
        r_u[2*it+1] = ld2cc(&Up[idx + 2]);
        r_z[it]     = ldcc(&Zp[idx >> 9]);
      }
      if (tid < 128){   // enc-part combine (red intact from W0e dot)
        const int jj = tid >> 6, l = tid & 63, g = l >> 4, b = l & 15;
        S.pre0[b][g][jj] += S.red[2*jj][l] + S.red[2*jj+1][l];
      }
      #pragma unroll
      for (int it = 0; it < 8; ++it){            // ctx = U/Z -> stg
        const int idx = (it*TPB + tid)*4;
        const float zi = 1.0f / r_z[it];
        float4 u4;
        u4.x = r_u[2*it].x   * zi; u4.y = r_u[2*it].y   * zi;
        u4.z = r_u[2*it+1].x * zi; u4.w = r_u[2*it+1].y * zi;
        *(float4*)&S.stg[idx >> 9][idx & 511] = u4;
      }
      __syncthreads();
      dot_part(&S.W0c[0][0][0], S.stg, S.red, wave, lane);  // ctx part of Wih0
      __syncthreads();
      if (tid < 32){
        const int b = tid & 15, jj = tid >> 4;
        float gv[4];
        #pragma unroll
        for (int g = 0; g < 4; ++g)
          gv[g] = S.pre0[b][g][jj] + S.red[2*jj][g*16+b] + S.red[2*jj+1][g*16+b];
        const float cold = S.cst[0][jj][b];
        const float ii = fsig(gv[0]), ff = fsig(gv[1]);
        const float gg = ftanh(gv[2]), oo = fsig(gv[3]);
        const float cn = ff*cold + ii*gg;
        S.cst[0][jj][b] = cn;
        stcc(&a.H0buf[parn*(BB*HH) + b*HH + j0 + jj], oo * ftanh(cn));
      }
    }
    e++; gbar(a.bar, e);   // barrier 3: h0n complete

    // ================= Phase D: LSTM1 =================
    {
      // zero next step's U/Z buffers (visibility rides barrier 4)
      if (tid < 32) stcc(&a.Ug[parn*(BB*HH) + bid*32 + tid], 0.0f);
      if (bid == 0 && tid < 16) stcc(&a.Zg[parn*16 + tid], 0.0f);

      stage_cc(a.H0buf + parn*(BB*HH), S.stg, tid);
      __syncthreads();
      dot_part(&S.W1x[0][0][0], S.stg, S.red, wave, lane);  // h0n @ Wih1^T
      __syncthreads();
      if (tid < 32){
        const int b = tid & 15, jj = tid >> 4;
        float gv[4];
        #pragma unroll
        for (int g = 0; g < 4; ++g)
          gv[g] = S.pre1[b][g][jj] + S.red[2*jj][g*16+b] + S.red[2*jj+1][g*16+b];
        const float cold = S.cst[1][jj][b];
        const float ii = fsig(gv[0]), ff = fsig(gv[1]);
        const float gg = ftanh(gv[2]), oo = fsig(gv[3]);
        const float cn = ff*cold + ii*gg;
        S.cst[1][jj][b] = cn;
        stcc(&a.H1buf[parn*(BB*HH) + b*HH + j0 + jj], oo * ftanh(cn));
      }
    }
    e++; gbar(a.bar, e);   // barrier 4: h1n complete -> next step
  }

  // tail: logits for t=255 (final h1 is in H1buf[0] since (255+1)&1==0)
  {
    stage_cc(a.H1buf, S.stg, tid);
    __syncthreads();
    if (wave < 2){
      const int d = bid*2 + wave, bo = d >> 5, vo = d & 31;
      float acc = 0.f;
      #pragma unroll
      for (int k = 0; k < 8; ++k){
        const int h = lane + 64*k;
        acc = fmaf(S.Wor[wave][h], S.stg[bo][h], acc);
      }
      #pragma unroll
      for (int off = 32; off; off >>= 1) acc += __shfl_xor(acc, off);
      if (lane == 0) a.out[(size_t)(bo*TT + 255)*VV + vo] = acc + S.boutv[wave];
    }
  }
}

extern "C" void kernel_launch(void* const* d_in, const int* in_sizes, int n_in,
                              void* d_out, int out_size, void* d_ws, size_t ws_size,
                              hipStream_t stream){
  const float* enc  = (const float*)d_in[0];
  const float* h0in = (const float*)d_in[1];
  const float* c0in = (const float*)d_in[2];
  // d_in[3] audio_lengths: unused by the reference
  const float* Wq   = (const float*)d_in[4];
  const float* bq   = (const float*)d_in[5];
  const float* Wk   = (const float*)d_in[6];
  const float* bk   = (const float*)d_in[7];
  const float* vatt = (const float*)d_in[8];
  const float* vb   = (const float*)d_in[9];
  const float* Wih0 = (const float*)d_in[10];
  const float* bih0 = (const float*)d_in[11];
  const float* Whh0 = (const float*)d_in[12];
  const float* bhh0 = (const float*)d_in[13];
  const float* Wih1 = (const float*)d_in[14];
  const float* bih1 = (const float*)d_in[15];
  const float* Whh1 = (const float*)d_in[16];
  const float* bhh1 = (const float*)d_in[17];
  const float* Wout = (const float*)d_in[18];
  const float* bout = (const float*)d_in[19];

  float* ws    = (float*)d_ws;
  float* Kproj = ws;                               // B*T*H = 2097152
  float* H0buf = Kproj + (size_t)BB*TT*HH;         // 2*B*H
  float* H1buf = H0buf + 2*BB*HH;                  // 2*B*H
  float* qWg   = H1buf + 2*BB*HH;                  // B*H
  float* Ug    = qWg + BB*HH;                      // 2*B*H (parity double-buffer)
  float* Zg    = Ug + 2*BB*HH;                     // 2*16
  int*   bar   = (int*)(Zg + 32);                  // BAR_INTS ints

  hipLaunchKernelGGL(init_kernel, dim3(64), dim3(256), 0, stream,
                     h0in, H0buf, H1buf, Ug, Zg, bar);
  hipLaunchKernelGGL(kproj_kernel, dim3(256), dim3(256), 0, stream, enc, Wk, bk, Kproj);

  KArgs ka;
  ka.enc = enc; ka.c0in = c0in; ka.Wq = Wq; ka.bq = bq; ka.vatt = vatt; ka.vb = vb;
  ka.Wih0 = Wih0; ka.bih0 = bih0; ka.Whh0 = Whh0; ka.bhh0 = bhh0;
  ka.Wih1 = Wih1; ka.bih1 = bih1; ka.Whh1 = Whh1; ka.bhh1 = bhh1;
  ka.Wout = Wout; ka.bout = bout;
  ka.Kproj = Kproj; ka.H0buf = H0buf; ka.H1buf = H1buf;
  ka.qWg = qWg; ka.Ug = Ug; ka.Zg = Zg; ka.bar = bar; ka.out = (float*)d_out;

  void* params[] = { (void*)&ka };
  hipLaunchCooperativeKernel((const void*)decoder_persist, dim3(NBLK), dim3(TPB),
                             params, 0, stream);
}

// Round 7
// 6847.377 us; speedup vs baseline: 2.6939x; 1.3654x over previous
//
#include <hip/hip_runtime.h>

#define HH 512
#define BB 16
#define TT 256
#define VV 32
#define TPB 256
#define NBLK 256
#define PITCH 516   // LDS row pitch (floats)

// barrier: 256 packed arrival slots + 8 padded flag replicas (128B apart)
#define BFLAG(g)  (256 + (g)*32)
#define BAR_INTS  (256 + 256)

struct KArgs {
  const float* enc; const float* c0in;
  const float* Wq; const float* bq; const float* vatt; const float* vb;
  const float* Wih0; const float* bih0; const float* Whh0; const float* bhh0;
  const float* Wih1; const float* bih1; const float* Whh1; const float* bhh1;
  const float* Wout; const float* bout;
  const float* Kproj; float* H0buf; float* H1buf; float* qWg; float* Ug; float* Zg;
  int* bar; float* out;
};

struct Smem {
  float W0e[4][2][PITCH];   // Wih0[g*512+j][0:512]    (enc_t part)
  float W0c[4][2][PITCH];   // Wih0[g*512+j][512:1024] (ctx part)
  float W0h[4][2][PITCH];   // Whh0
  float W1x[4][2][PITCH];   // Wih1
  float W1h[4][2][PITCH];   // Whh1
  float Wqr[2][PITCH];
  float Wor[2][PITCH];
  float vv[HH];
  float qrow[HH];
  float stg[BB][PITCH];     // staging for h1/h0/enc_t/ctx/h0n
  float red[4][64];         // per-wave dot partials
  float pre0[BB][4][2];     // accumulated gate partials (enc+h0+bias)
  float pre1[BB][4][2];     // (h1+bias)
  float cst[2][2][BB];      // c state [layer][jj][b]
  float scw[16];            // attention exp-weights for this block's t-chunk
  float bs0[4][2];
  float bs1[4][2];
  float bqv[2], boutv[2];
};

__device__ __forceinline__ float fsig(float x){ return 1.0f/(1.0f + __expf(-x)); }
__device__ __forceinline__ float ftanh(float x){
  float ee = __expf(2.0f*x);
  return 1.0f - 2.0f/(ee + 1.0f);
}

// relaxed agent-scope (cross-XCD coherent, write-through, no wb/inv) accessors
__device__ __forceinline__ void stcc(float* p, float v){
  __hip_atomic_store(p, v, __ATOMIC_RELAXED, __HIP_MEMORY_SCOPE_AGENT);
}
__device__ __forceinline__ float ldcc(const float* p){
  return __hip_atomic_load(p, __ATOMIC_RELAXED, __HIP_MEMORY_SCOPE_AGENT);
}
__device__ __forceinline__ float2 ld2cc(const float* p){
  unsigned long long v = __hip_atomic_load((const unsigned long long*)p,
                                           __ATOMIC_RELAXED, __HIP_MEMORY_SCOPE_AGENT);
  union { unsigned long long u; float2 f; } c; c.u = v;
  return c.f;
}

// ---- split device barrier, leader-sweep + flag topology ----
// arrive: block syncs (per-wave vmcnt drain -> coherent stores landed), tid0 posts slot
__device__ __forceinline__ void gbar_arrive(int* __restrict__ bar, int e, int bid){
  __syncthreads();
  if (threadIdx.x == 0)
    __hip_atomic_store(&bar[bid], e, __ATOMIC_RELAXED, __HIP_MEMORY_SCOPE_AGENT);
}
// wait: block 0 wave 0 sweeps all 256 slots, posts 8 flag replicas;
//       other blocks: tid0 polls its XCD-group flag (sleep-paced)
__device__ __forceinline__ void gbar_wait(int* __restrict__ bar, int e, int bid){
  if (bid == 0){
    if (threadIdx.x < 64){
      const unsigned long long* p = (const unsigned long long*)bar;   // 128 ulls
      const int i0 = threadIdx.x * 2;
      int spins = 0;
      for (;;){
        unsigned long long v0 = __hip_atomic_load(&p[i0],     __ATOMIC_RELAXED, __HIP_MEMORY_SCOPE_AGENT);
        unsigned long long v1 = __hip_atomic_load(&p[i0 + 1], __ATOMIC_RELAXED, __HIP_MEMORY_SCOPE_AGENT);
        const int a0 = (int)v0, a1 = (int)(v0 >> 32), a2 = (int)v1, a3 = (int)(v1 >> 32);
        const int ok = (a0 >= e) & (a1 >= e) & (a2 >= e) & (a3 >= e);
        if (__all(ok)) break;
        __builtin_amdgcn_s_sleep(1);
        if (++spins > (1 << 20)) break;   // safety valve: wrong answer beats a hang
      }
      if (threadIdx.x < 8)
        __hip_atomic_store(&bar[BFLAG(threadIdx.x)], e, __ATOMIC_RELAXED, __HIP_MEMORY_SCOPE_AGENT);
    }
  } else {
    if (threadIdx.x == 0){
      int spins = 0;
      while (__hip_atomic_load(&bar[BFLAG(bid & 7)], __ATOMIC_RELAXED, __HIP_MEMORY_SCOPE_AGENT) < e){
        __builtin_amdgcn_s_sleep(1);
        if (++spins > (1 << 22)) break;
      }
    }
  }
  __syncthreads();
}
__device__ __forceinline__ void gbar(int* __restrict__ bar, int e, int bid){
  gbar_arrive(bar, e, bid);
  gbar_wait(bar, e, bid);
}

// stage 16x512 coherent buffer -> LDS (batched 8B atomic loads, then LDS writes)
__device__ __forceinline__ void stage_cc(const float* __restrict__ src,
                                         float (* __restrict__ stg)[PITCH], int tid){
  float2 v[16];
  #pragma unroll
  for (int it = 0; it < 8; ++it){
    const int idx = (it*TPB + tid)*4;
    v[2*it]   = ld2cc(&src[idx]);
    v[2*it+1] = ld2cc(&src[idx + 2]);
  }
  #pragma unroll
  for (int it = 0; it < 8; ++it){
    const int idx = (it*TPB + tid)*4;
    float4 w; w.x = v[2*it].x; w.y = v[2*it].y; w.z = v[2*it+1].x; w.w = v[2*it+1].y;
    *(float4*)&stg[idx >> 9][idx & 511] = w;
  }
}

// wave w handles (jj = w>>1, h-half = w&1); lane = (g<<4)|b ; writes red[w][lane]
__device__ __forceinline__ void dot_part(const float* __restrict__ W,
                                         const float (* __restrict__ stg)[PITCH],
                                         float (* __restrict__ red)[64],
                                         int wave, int lane){
  const int jj = wave >> 1, off = (wave & 1) << 8;
  const int b = lane & 15, g = lane >> 4;
  const float* wrow = W + (size_t)(g*2 + jj)*PITCH + off;
  const float* xrow = &stg[b][off];
  float acc = 0.f;
  #pragma unroll 8
  for (int h = 0; h < 256; h += 4){
    const float4 w4 = *(const float4*)&wrow[h];
    const float4 x4 = *(const float4*)&xrow[h];
    acc = fmaf(w4.x,x4.x, fmaf(w4.y,x4.y, fmaf(w4.z,x4.z, fmaf(w4.w,x4.w, acc))));
  }
  red[wave][lane] = acc;
}

__global__ void init_kernel(const float* __restrict__ h0in, float* __restrict__ H0buf,
                            float* __restrict__ H1buf, float* __restrict__ Ug,
                            float* __restrict__ Zg, int* __restrict__ bar){
  const int i = blockIdx.x*blockDim.x + threadIdx.x;
  if (i < BB*HH){
    H0buf[i] = h0in[i];            // layer 0
    H1buf[i] = h0in[BB*HH + i];    // layer 1
  }
  if (i < 2*BB*HH) Ug[i] = 0.0f;
  if (i < 32) Zg[i] = 0.0f;
  if (i < BAR_INTS) bar[i] = 0;
}

// Kproj = enc @ Wk^T + bk : 256 blocks x 16 (b,t)-rows, x register-cached
__global__ __launch_bounds__(256, 1) void kproj_kernel(const float* __restrict__ enc,
                                                       const float* __restrict__ Wk,
                                                       const float* __restrict__ bk,
                                                       float* __restrict__ Kproj){
  __shared__ float er[BB][PITCH];
  const int bid = blockIdx.x, tid = threadIdx.x;
  const int wave = tid >> 6, lane = tid & 63;
  const int r = lane & 15, q = lane >> 4;
  const int row0 = bid*16;
  #pragma unroll
  for (int it = 0; it < 8; ++it){
    const int idx = (it*256 + tid)*4;
    const int rr = idx >> 9, h = idx & 511;
    *(float4*)&er[rr][h] = *(const float4*)&enc[(size_t)(row0+rr)*HH + h];
  }
  __syncthreads();
  float4 xr[32];
  #pragma unroll
  for (int i = 0; i < 32; ++i) xr[i] = *(const float4*)&er[r][q*128 + i*4];
  for (int k = 0; k < 128; ++k){
    const int hk = wave*128 + k;
    const float* wrow = Wk + (size_t)hk*HH + q*128;
    float acc = 0.f;
    #pragma unroll
    for (int i = 0; i < 32; ++i){
      const float4 w4 = *(const float4*)&wrow[i*4];
      acc = fmaf(w4.x,xr[i].x, fmaf(w4.y,xr[i].y, fmaf(w4.z,xr[i].z, fmaf(w4.w,xr[i].w, acc))));
    }
    acc += __shfl_xor(acc, 16);
    acc += __shfl_xor(acc, 32);
    if (lane < 16) Kproj[(size_t)(row0 + r)*HH + hk] = acc + bk[hk];
  }
}

__global__ __launch_bounds__(TPB, 1) void decoder_persist(KArgs a){
  __shared__ Smem S;
  const int bid = blockIdx.x, tid = threadIdx.x;
  const int wave = tid >> 6, lane = tid & 63;
  const int lb = lane & 15, lg = lane >> 4;
  const int j0 = bid*2;
  const int ba = bid >> 4, tb = (bid & 15) * 16;   // attention assignment

  // ---- one-time: weights to LDS ----
  for (int g = 0; g < 4; ++g){
    for (int jj = 0; jj < 2; ++jj){
      const int row = g*HH + j0 + jj;
      for (int h = tid; h < HH; h += TPB){
        S.W0e[g][jj][h] = a.Wih0[(size_t)row*(2*HH) + h];
        S.W0c[g][jj][h] = a.Wih0[(size_t)row*(2*HH) + HH + h];
        S.W0h[g][jj][h] = a.Whh0[(size_t)row*HH + h];
        S.W1x[g][jj][h] = a.Wih1[(size_t)row*HH + h];
        S.W1h[g][jj][h] = a.Whh1[(size_t)row*HH + h];
      }
    }
  }
  for (int jj = 0; jj < 2; ++jj){
    const int d = bid*2 + jj, vo = d & 31;
    for (int h = tid; h < HH; h += TPB){
      S.Wqr[jj][h] = a.Wq[(size_t)(j0+jj)*HH + h];
      S.Wor[jj][h] = a.Wout[(size_t)vo*HH + h];
    }
  }
  for (int h = tid; h < HH; h += TPB) S.vv[h] = a.vatt[h];
  if (tid < 16){
    S.cst[0][0][tid] = a.c0in[0*BB*HH + tid*HH + j0];
    S.cst[0][1][tid] = a.c0in[0*BB*HH + tid*HH + j0 + 1];
    S.cst[1][0][tid] = a.c0in[1*BB*HH + tid*HH + j0];
    S.cst[1][1][tid] = a.c0in[1*BB*HH + tid*HH + j0 + 1];
  }
  if (tid < 8){
    const int g = tid & 3, jj = tid >> 2;
    const int row = g*HH + j0 + jj;
    S.bs0[g][jj] = a.bih0[row] + a.bhh0[row];
    S.bs1[g][jj] = a.bih1[row] + a.bhh1[row];
  }
  if (tid < 2){
    S.bqv[tid] = a.bq[j0 + tid];
    S.boutv[tid] = a.bout[(bid*2 + tid) & 31];
  }
  const float vb0 = a.vb[0];

  // ---- step-invariant attention operands -> registers (values never change) ----
  float r_kp[4][8];
  #pragma unroll
  for (int i = 0; i < 4; ++i){
    const float* kp = a.Kproj + (size_t)(ba*TT + tb + wave*4 + i)*HH;
    #pragma unroll
    for (int k = 0; k < 8; ++k) r_kp[i][k] = kp[lane + 64*k];
  }
  float r_e0[16], r_e1[16];
  #pragma unroll
  for (int lt = 0; lt < 16; ++lt){
    const float* er = a.enc + (size_t)(ba*TT + tb + lt)*HH;
    r_e0[lt] = er[tid];
    r_e1[lt] = er[tid + 256];
  }
  // enc_t prefetch for t=0
  float4 r_en[8];
  #pragma unroll
  for (int it = 0; it < 8; ++it){
    const int idx = (it*TPB + tid)*4;
    r_en[it] = *(const float4*)&a.enc[(size_t)((idx >> 9)*TT + 0)*HH + (idx & 511)];
  }
  __syncthreads();

  int e = 0;
  for (int t = 0; t < TT; ++t){
    const int par = t & 1, parn = par ^ 1;

    // ================= Phase A =================
    float2 r_h1[16], r_h0[16];
    {
      const float* h1p = a.H1buf + par*(BB*HH);
      const float* h0p = a.H0buf + par*(BB*HH);
      #pragma unroll
      for (int it = 0; it < 8; ++it){
        const int idx = (it*TPB + tid)*4;
        r_h1[2*it]   = ld2cc(&h1p[idx]);
        r_h1[2*it+1] = ld2cc(&h1p[idx + 2]);
      }
      #pragma unroll
      for (int it = 0; it < 8; ++it){
        const int idx = (it*TPB + tid)*4;
        r_h0[2*it]   = ld2cc(&h0p[idx]);
        r_h0[2*it+1] = ld2cc(&h0p[idx + 2]);
      }
    }
    #pragma unroll
    for (int it = 0; it < 8; ++it){
      const int idx = (it*TPB + tid)*4;
      float4 w; w.x=r_h1[2*it].x; w.y=r_h1[2*it].y; w.z=r_h1[2*it+1].x; w.w=r_h1[2*it+1].y;
      *(float4*)&S.stg[idx >> 9][idx & 511] = w;
    }
    __syncthreads();   // h1 staged (drains h0 loads too)

    if (wave < 2){
      if (t > 0){   // logits for step t-1 from staged h1
        const int d = bid*2 + wave, bo = d >> 5, vo = d & 31;
        float acc = 0.f;
        #pragma unroll
        for (int k = 0; k < 8; ++k){
          const int h = lane + 64*k;
          acc = fmaf(S.Wor[wave][h], S.stg[bo][h], acc);
        }
        #pragma unroll
        for (int off = 32; off; off >>= 1) acc += __shfl_xor(acc, off);
        if (lane == 0) a.out[(size_t)(bo*TT + (t-1))*VV + vo] = acc + S.boutv[wave];
      }
    } else {      // qW = h1 @ Wq^T + bq  (2 output rows per block)
      const int jj = wave - 2;
      const int off0 = lg * 128;
      float acc = 0.f;
      #pragma unroll 8
      for (int h = 0; h < 128; h += 4){
        const float4 w4 = *(const float4*)&S.Wqr[jj][off0 + h];
        const float4 x4 = *(const float4*)&S.stg[lb][off0 + h];
        acc = fmaf(w4.x,x4.x, fmaf(w4.y,x4.y, fmaf(w4.z,x4.z, fmaf(w4.w,x4.w, acc))));
      }
      acc += __shfl_xor(acc, 16);
      acc += __shfl_xor(acc, 32);
      if (lane < 16) stcc(&a.qWg[lane*HH + j0 + jj], acc + S.bqv[jj]);
    }

    e++; gbar_arrive(a.bar, e, bid);   // barrier 1 ARRIVE (qW stores drained)

    // ---- work inside the barrier-1 window (intra-block only) ----
    dot_part(&S.W1h[0][0][0], S.stg, S.red, wave, lane);  // h1 @ Whh1^T
    __syncthreads();
    if (tid < 128){
      const int jj = tid >> 6, l = tid & 63, g = l >> 4, b = l & 15;
      S.pre1[b][g][jj] = S.red[2*jj][l] + S.red[2*jj+1][l] + S.bs1[g][jj];
    }
    #pragma unroll
    for (int it = 0; it < 8; ++it){
      const int idx = (it*TPB + tid)*4;
      float4 w; w.x=r_h0[2*it].x; w.y=r_h0[2*it].y; w.z=r_h0[2*it+1].x; w.w=r_h0[2*it+1].y;
      *(float4*)&S.stg[idx >> 9][idx & 511] = w;
    }
    __syncthreads();   // h0 staged, pre1 done
    dot_part(&S.W0h[0][0][0], S.stg, S.red, wave, lane);  // h0 @ Whh0^T
    __syncthreads();
    if (tid < 128){
      const int jj = tid >> 6, l = tid & 63, g = l >> 4, b = l & 15;
      S.pre0[b][g][jj] = S.red[2*jj][l] + S.red[2*jj+1][l] + S.bs0[g][jj];
    }
    #pragma unroll
    for (int it = 0; it < 8; ++it){
      const int idx = (it*TPB + tid)*4;
      *(float4*)&S.stg[idx >> 9][idx & 511] = r_en[it];
    }
    __syncthreads();   // enc staged, pre0(h) done
    dot_part(&S.W0e[0][0][0], S.stg, S.red, wave, lane);  // enc_t part of Wih0
    // (red preserved through phase B; combined after barrier-2 arrive)

    gbar_wait(a.bar, e, bid);   // barrier 1 WAIT (usually already satisfied)

    // ================= Phase B: attention =================
    {
      float* Up = a.Ug + par*(BB*HH);
      float* Zp = a.Zg + par*16;
      const float q0 = ldcc(&a.qWg[ba*HH + tid]);
      const float q1 = ldcc(&a.qWg[ba*HH + tid + 256]);
      S.qrow[tid] = q0; S.qrow[tid + 256] = q1;
      __syncthreads();
      #pragma unroll
      for (int i = 0; i < 4; ++i){
        float acc = 0.f;
        #pragma unroll
        for (int k = 0; k < 8; ++k){
          const int h = lane + 64*k;
          acc = fmaf(S.vv[h], ftanh(S.qrow[h] + r_kp[i][k]), acc);
        }
        #pragma unroll
        for (int off = 32; off; off >>= 1) acc += __shfl_xor(acc, off);
        if (lane == 0) S.scw[wave*4 + i] = __expf(acc + vb0);  // |score| <= ~18, exp safe
      }
      __syncthreads();
      float u0 = 0.f, u1 = 0.f;
      #pragma unroll
      for (int lt = 0; lt < 16; ++lt){
        const float w = S.scw[lt];
        u0 = fmaf(w, r_e0[lt], u0);
        u1 = fmaf(w, r_e1[lt], u1);
      }
      unsafeAtomicAdd(&Up[ba*HH + tid],       u0);
      unsafeAtomicAdd(&Up[ba*HH + tid + 256], u1);
      if (tid == 0){
        float zs = 0.f;
        #pragma unroll
        for (int lt = 0; lt < 16; ++lt) zs += S.scw[lt];
        unsafeAtomicAdd(&Zp[ba], zs);
      }
    }
    e++; gbar_arrive(a.bar, e, bid);   // barrier 2 ARRIVE (U/Z atomics drained)
    if (tid < 128){   // enc-part combine inside barrier-2 window (red from W0e dot)
      const int jj = tid >> 6, l = tid & 63, g = l >> 4, b = l & 15;
      S.pre0[b][g][jj] += S.red[2*jj][l] + S.red[2*jj+1][l];
    }
    gbar_wait(a.bar, e, bid);          // barrier 2 WAIT: U,Z complete

    // ================= Phase C: LSTM0 =================
    {
      const float* Up = a.Ug + par*(BB*HH);
      const float* Zp = a.Zg + par*16;
      float2 r_u[16]; float r_z[8];
      #pragma unroll
      for (int it = 0; it < 8; ++it){
        const int idx = (it*TPB + tid)*4;
        r_u[2*it]   = ld2cc(&Up[idx]);
        r_u[2*it+1] = ld2cc(&Up[idx + 2]);
        r_z[it]     = ldcc(&Zp[idx >> 9]);
      }
      #pragma unroll
      for (int it = 0; it < 8; ++it){            // ctx = U/Z -> stg
        const int idx = (it*TPB + tid)*4;
        const float zi = 1.0f / r_z[it];
        float4 u4;
        u4.x = r_u[2*it].x   * zi; u4.y = r_u[2*it].y   * zi;
        u4.z = r_u[2*it+1].x * zi; u4.w = r_u[2*it+1].y * zi;
        *(float4*)&S.stg[idx >> 9][idx & 511] = u4;
      }
      __syncthreads();
      dot_part(&S.W0c[0][0][0], S.stg, S.red, wave, lane);  // ctx part of Wih0
      __syncthreads();
      if (tid < 32){
        const int b = tid & 15, jj = tid >> 4;
        float gv[4];
        #pragma unroll
        for (int g = 0; g < 4; ++g)
          gv[g] = S.pre0[b][g][jj] + S.red[2*jj][g*16+b] + S.red[2*jj+1][g*16+b];
        const float cold = S.cst[0][jj][b];
        const float ii = fsig(gv[0]), ff = fsig(gv[1]);
        const float gg = ftanh(gv[2]), oo = fsig(gv[3]);
        const float cn = ff*cold + ii*gg;
        S.cst[0][jj][b] = cn;
        stcc(&a.H0buf[parn*(BB*HH) + b*HH + j0 + jj], oo * ftanh(cn));
      }
    }
    e++; gbar(a.bar, e, bid);   // barrier 3: h0n complete

    // ================= Phase D: LSTM1 =================
    {
      // zero next step's U/Z buffers (visibility rides barrier 4)
      if (tid < 32) stcc(&a.Ug[parn*(BB*HH) + bid*32 + tid], 0.0f);
      if (bid == 0 && tid < 16) stcc(&a.Zg[parn*16 + tid], 0.0f);

      stage_cc(a.H0buf + parn*(BB*HH), S.stg, tid);
      __syncthreads();
      dot_part(&S.W1x[0][0][0], S.stg, S.red, wave, lane);  // h0n @ Wih1^T
      __syncthreads();
      if (tid < 32){
        const int b = tid & 15, jj = tid >> 4;
        float gv[4];
        #pragma unroll
        for (int g = 0; g < 4; ++g)
          gv[g] = S.pre1[b][g][jj] + S.red[2*jj][g*16+b] + S.red[2*jj+1][g*16+b];
        const float cold = S.cst[1][jj][b];
        const float ii = fsig(gv[0]), ff = fsig(gv[1]);
        const float gg = ftanh(gv[2]), oo = fsig(gv[3]);
        const float cn = ff*cold + ii*gg;
        S.cst[1][jj][b] = cn;
        stcc(&a.H1buf[parn*(BB*HH) + b*HH + j0 + jj], oo * ftanh(cn));
      }
    }
    e++; gbar_arrive(a.bar, e, bid);   // barrier 4 ARRIVE (h1n stores drained)
    {
      // prefetch next step's enc_t inside the barrier-4 window (read-only)
      const int tn = (t + 1 < TT) ? (t + 1) : t;
      #pragma unroll
      for (int it = 0; it < 8; ++it){
        const int idx = (it*TPB + tid)*4;
        r_en[it] = *(const float4*)&a.enc[(size_t)((idx >> 9)*TT + tn)*HH + (idx & 511)];
      }
    }
    gbar_wait(a.bar, e, bid);          // barrier 4 WAIT -> next step
  }

  // tail: logits for t=255 (final h1 is in H1buf[0] since (255+1)&1==0)
  {
    stage_cc(a.H1buf, S.stg, tid);
    __syncthreads();
    if (wave < 2){
      const int d = bid*2 + wave, bo = d >> 5, vo = d & 31;
      float acc = 0.f;
      #pragma unroll
      for (int k = 0; k < 8; ++k){
        const int h = lane + 64*k;
        acc = fmaf(S.Wor[wave][h], S.stg[bo][h], acc);
      }
      #pragma unroll
      for (int off = 32; off; off >>= 1) acc += __shfl_xor(acc, off);
      if (lane == 0) a.out[(size_t)(bo*TT + 255)*VV + vo] = acc + S.boutv[wave];
    }
  }
}

extern "C" void kernel_launch(void* const* d_in, const int* in_sizes, int n_in,
                              void* d_out, int out_size, void* d_ws, size_t ws_size,
                              hipStream_t stream){
  const float* enc  = (const float*)d_in[0];
  const float* h0in = (const float*)d_in[1];
  const float* c0in = (const float*)d_in[2];
  // d_in[3] audio_lengths: unused by the reference
  const float* Wq   = (const float*)d_in[4];
  const float* bq   = (const float*)d_in[5];
  const float* Wk   = (const float*)d_in[6];
  const float* bk   = (const float*)d_in[7];
  const float* vatt = (const float*)d_in[8];
  const float* vb   = (const float*)d_in[9];
  const float* Wih0 = (const float*)d_in[10];
  const float* bih0 = (const float*)d_in[11];
  const float* Whh0 = (const float*)d_in[12];
  const float* bhh0 = (const float*)d_in[13];
  const float* Wih1 = (const float*)d_in[14];
  const float* bih1 = (const float*)d_in[15];
  const float* Whh1 = (const float*)d_in[16];
  const float* bhh1 = (const float*)d_in[17];
  const float* Wout = (const float*)d_in[18];
  const float* bout = (const float*)d_in[19];

  float* ws    = (float*)d_ws;
  float* Kproj = ws;                               // B*T*H = 2097152
  float* H0buf = Kproj + (size_t)BB*TT*HH;         // 2*B*H
  float* H1buf = H0buf + 2*BB*HH;                  // 2*B*H
  float* qWg   = H1buf + 2*BB*HH;                  // B*H
  float* Ug    = qWg + BB*HH;                      // 2*B*H (parity double-buffer)
  float* Zg    = Ug + 2*BB*HH;                     // 2*16
  int*   bar   = (int*)(Zg + 32);                  // BAR_INTS ints

  hipLaunchKernelGGL(init_kernel, dim3(64), dim3(256), 0, stream,
                     h0in, H0buf, H1buf, Ug, Zg, bar);
  hipLaunchKernelGGL(kproj_kernel, dim3(256), dim3(256), 0, stream, enc, Wk, bk, Kproj);

  KArgs ka;
  ka.enc = enc; ka.c0in = c0in; ka.Wq = Wq; ka.bq = bq; ka.vatt = vatt; ka.vb = vb;
  ka.Wih0 = Wih0; ka.bih0 = bih0; ka.Whh0 = Whh0; ka.bhh0 = bhh0;
  ka.Wih1 = Wih1; ka.bih1 = bih1; ka.Whh1 = Whh1; ka.bhh1 = bhh1;
  ka.Wout = Wout; ka.bout = bout;
  ka.Kproj = Kproj; ka.H0buf = H0buf; ka.H1buf = H1buf;
  ka.qWg = qWg; ka.Ug = Ug; ka.Zg = Zg; ka.bar = bar; ka.out = (float*)d_out;

  void* params[] = { (void*)&ka };
  hipLaunchCooperativeKernel((const void*)decoder_persist, dim3(NBLK), dim3(TPB),
                             params, 0, stream);
}

// Round 8
// 6648.772 us; speedup vs baseline: 2.7743x; 1.0299x over previous
//
#include <hip/hip_runtime.h>

#define HH 512
#define BB 16
#define TT 256
#define VV 32
#define TPB 256
#define NBLK 256
#define PITCH 516   // LDS row pitch (floats)

#define BAR_INTS 256   // one epoch slot per block

struct KArgs {
  const float* enc; const float* c0in;
  const float* Wq; const float* bq; const float* vatt; const float* vb;
  const float* Wih0; const float* bih0; const float* Whh0; const float* bhh0;
  const float* Wih1; const float* bih1; const float* Whh1; const float* bhh1;
  const float* Wout; const float* bout;
  const float* Kproj; float* H0buf; float* H1buf; float* qWg; float* Ug; float* Zg;
  int* bar; float* out;
};

struct Smem {
  float W0e[4][2][PITCH];   // Wih0[g*512+j][0:512]    (enc_t part)
  float W0c[4][2][PITCH];   // Wih0[g*512+j][512:1024] (ctx part)
  float W0h[4][2][PITCH];   // Whh0
  float W1x[4][2][PITCH];   // Wih1
  float W1h[4][2][PITCH];   // Whh1
  float Wqr[2][PITCH];
  float Wor[2][PITCH];
  float vv[HH];
  float qrow[HH];
  float stg[BB][PITCH];     // staging: h1 -> h0 -> enc -> ctx -> h0n
  float red[4][64];         // per-wave dot partials
  float pre0[BB][4][2];     // gate partials L0 (h0+bias, then +enc)
  float pre1[BB][4][2];     // gate partials L1 (h1+bias)
  float cst[2][2][BB];      // c state [layer][jj][b]
  float scw[16];            // attention exp-weights for this block's t-chunk
  float bs0[4][2];
  float bs1[4][2];
  float bqv[2], boutv[2];
};

__device__ __forceinline__ float fsig(float x){ return 1.0f/(1.0f + __expf(-x)); }
__device__ __forceinline__ float ftanh(float x){
  float ee = __expf(2.0f*x);
  return 1.0f - 2.0f/(ee + 1.0f);
}

// relaxed agent-scope (cross-XCD coherent, write-through, no wb/inv) accessors
__device__ __forceinline__ void stcc(float* p, float v){
  __hip_atomic_store(p, v, __ATOMIC_RELAXED, __HIP_MEMORY_SCOPE_AGENT);
}
__device__ __forceinline__ float ldcc(const float* p){
  return __hip_atomic_load(p, __ATOMIC_RELAXED, __HIP_MEMORY_SCOPE_AGENT);
}
__device__ __forceinline__ float2 ld2cc(const float* p){
  unsigned long long v = __hip_atomic_load((const unsigned long long*)p,
                                           __ATOMIC_RELAXED, __HIP_MEMORY_SCOPE_AGENT);
  union { unsigned long long u; float2 f; } c; c.u = v;
  return c.f;
}

// ---- split device barrier, decentralized detection ----
// arrive: block syncs (per-wave vmcnt drain -> coherent stores landed), tid0 posts slot
__device__ __forceinline__ void gbar_arrive(int* __restrict__ bar, int e, int bid){
  __syncthreads();
  if (threadIdx.x == 0)
    __hip_atomic_store(&bar[bid], e, __ATOMIC_RELAXED, __HIP_MEMORY_SCOPE_AGENT);
}
// wait: EVERY block's wave 0 sweeps all 256 slots itself (sleep-paced) — no leader,
// no flag hop, no straggler coupling.
__device__ __forceinline__ void gbar_wait(int* __restrict__ bar, int e, int bid){
  if (threadIdx.x < 64){
    const unsigned long long* p = (const unsigned long long*)bar;   // 128 ulls
    const int i0 = threadIdx.x * 2;
    int spins = 0;
    for (;;){
      unsigned long long v0 = __hip_atomic_load(&p[i0],     __ATOMIC_RELAXED, __HIP_MEMORY_SCOPE_AGENT);
      unsigned long long v1 = __hip_atomic_load(&p[i0 + 1], __ATOMIC_RELAXED, __HIP_MEMORY_SCOPE_AGENT);
      const int a0 = (int)v0, a1 = (int)(v0 >> 32), a2 = (int)v1, a3 = (int)(v1 >> 32);
      const int ok = (a0 >= e) & (a1 >= e) & (a2 >= e) & (a3 >= e);
      if (__all(ok)) break;
      __builtin_amdgcn_s_sleep(2);
      if (++spins > (1 << 20)) break;   // safety valve: wrong answer beats a hang
    }
  }
  __syncthreads();
}
__device__ __forceinline__ void gbar(int* __restrict__ bar, int e, int bid){
  gbar_arrive(bar, e, bid);
  gbar_wait(bar, e, bid);
}

// stage 16x512 coherent buffer -> LDS (batched 8B atomic loads, then LDS writes)
__device__ __forceinline__ void stage_cc(const float* __restrict__ src,
                                         float (* __restrict__ stg)[PITCH], int tid){
  float2 v[16];
  #pragma unroll
  for (int it = 0; it < 8; ++it){
    const int idx = (it*TPB + tid)*4;
    v[2*it]   = ld2cc(&src[idx]);
    v[2*it+1] = ld2cc(&src[idx + 2]);
  }
  #pragma unroll
  for (int it = 0; it < 8; ++it){
    const int idx = (it*TPB + tid)*4;
    float4 w; w.x = v[2*it].x; w.y = v[2*it].y; w.z = v[2*it+1].x; w.w = v[2*it+1].y;
    *(float4*)&stg[idx >> 9][idx & 511] = w;
  }
}

// wave w handles (jj = w>>1, h-half = w&1); lane = (g<<4)|b ; writes red[w][lane]
__device__ __forceinline__ void dot_part(const float* __restrict__ W,
                                         const float (* __restrict__ stg)[PITCH],
                                         float (* __restrict__ red)[64],
                                         int wave, int lane){
  const int jj = wave >> 1, off = (wave & 1) << 8;
  const int b = lane & 15, g = lane >> 4;
  const float* wrow = W + (size_t)(g*2 + jj)*PITCH + off;
  const float* xrow = &stg[b][off];
  float acc = 0.f;
  #pragma unroll 8
  for (int h = 0; h < 256; h += 4){
    const float4 w4 = *(const float4*)&wrow[h];
    const float4 x4 = *(const float4*)&xrow[h];
    acc = fmaf(w4.x,x4.x, fmaf(w4.y,x4.y, fmaf(w4.z,x4.z, fmaf(w4.w,x4.w, acc))));
  }
  red[wave][lane] = acc;
}

__global__ void init_kernel(const float* __restrict__ h0in, float* __restrict__ H0buf,
                            float* __restrict__ H1buf, float* __restrict__ Ug,
                            float* __restrict__ Zg, int* __restrict__ bar){
  const int i = blockIdx.x*blockDim.x + threadIdx.x;
  if (i < BB*HH){
    H0buf[i] = h0in[i];            // layer 0
    H1buf[i] = h0in[BB*HH + i];    // layer 1
  }
  if (i < 2*BB*HH) Ug[i] = 0.0f;
  if (i < 32) Zg[i] = 0.0f;
  if (i < BAR_INTS) bar[i] = 0;
}

// Kproj = enc @ Wk^T + bk : 256 blocks x 16 (b,t)-rows, x register-cached
__global__ __launch_bounds__(256, 1) void kproj_kernel(const float* __restrict__ enc,
                                                       const float* __restrict__ Wk,
                                                       const float* __restrict__ bk,
                                                       float* __restrict__ Kproj){
  __shared__ float er[BB][PITCH];
  const int bid = blockIdx.x, tid = threadIdx.x;
  const int wave = tid >> 6, lane = tid & 63;
  const int r = lane & 15, q = lane >> 4;
  const int row0 = bid*16;
  #pragma unroll
  for (int it = 0; it < 8; ++it){
    const int idx = (it*256 + tid)*4;
    const int rr = idx >> 9, h = idx & 511;
    *(float4*)&er[rr][h] = *(const float4*)&enc[(size_t)(row0+rr)*HH + h];
  }
  __syncthreads();
  float4 xr[32];
  #pragma unroll
  for (int i = 0; i < 32; ++i) xr[i] = *(const float4*)&er[r][q*128 + i*4];
  for (int k = 0; k < 128; ++k){
    const int hk = wave*128 + k;
    const float* wrow = Wk + (size_t)hk*HH + q*128;
    float acc = 0.f;
    #pragma unroll
    for (int i = 0; i < 32; ++i){
      const float4 w4 = *(const float4*)&wrow[i*4];
      acc = fmaf(w4.x,xr[i].x, fmaf(w4.y,xr[i].y, fmaf(w4.z,xr[i].z, fmaf(w4.w,xr[i].w, acc))));
    }
    acc += __shfl_xor(acc, 16);
    acc += __shfl_xor(acc, 32);
    if (lane < 16) Kproj[(size_t)(row0 + r)*HH + hk] = acc + bk[hk];
  }
}

__global__ __launch_bounds__(TPB, 1) void decoder_persist(KArgs a){
  __shared__ Smem S;
  const int bid = blockIdx.x, tid = threadIdx.x;
  const int wave = tid >> 6, lane = tid & 63;
  const int lb = lane & 15, lg = lane >> 4;
  const int j0 = bid*2;
  const int ba = bid >> 4, tb = (bid & 15) * 16;   // attention assignment

  // ---- one-time: weights to LDS ----
  for (int g = 0; g < 4; ++g){
    for (int jj = 0; jj < 2; ++jj){
      const int row = g*HH + j0 + jj;
      for (int h = tid; h < HH; h += TPB){
        S.W0e[g][jj][h] = a.Wih0[(size_t)row*(2*HH) + h];
        S.W0c[g][jj][h] = a.Wih0[(size_t)row*(2*HH) + HH + h];
        S.W0h[g][jj][h] = a.Whh0[(size_t)row*HH + h];
        S.W1x[g][jj][h] = a.Wih1[(size_t)row*HH + h];
        S.W1h[g][jj][h] = a.Whh1[(size_t)row*HH + h];
      }
    }
  }
  for (int jj = 0; jj < 2; ++jj){
    const int d = bid*2 + jj, vo = d & 31;
    for (int h = tid; h < HH; h += TPB){
      S.Wqr[jj][h] = a.Wq[(size_t)(j0+jj)*HH + h];
      S.Wor[jj][h] = a.Wout[(size_t)vo*HH + h];
    }
  }
  for (int h = tid; h < HH; h += TPB) S.vv[h] = a.vatt[h];
  if (tid < 16){
    S.cst[0][0][tid] = a.c0in[0*BB*HH + tid*HH + j0];
    S.cst[0][1][tid] = a.c0in[0*BB*HH + tid*HH + j0 + 1];
    S.cst[1][0][tid] = a.c0in[1*BB*HH + tid*HH + j0];
    S.cst[1][1][tid] = a.c0in[1*BB*HH + tid*HH + j0 + 1];
  }
  if (tid < 8){
    const int g = tid & 3, jj = tid >> 2;
    const int row = g*HH + j0 + jj;
    S.bs0[g][jj] = a.bih0[row] + a.bhh0[row];
    S.bs1[g][jj] = a.bih1[row] + a.bhh1[row];
  }
  if (tid < 2){
    S.bqv[tid] = a.bq[j0 + tid];
    S.boutv[tid] = a.bout[(bid*2 + tid) & 31];
  }
  const float vb0 = a.vb[0];

  // ---- step-invariant attention operands -> registers ----
  float r_kp[4][8];
  #pragma unroll
  for (int i = 0; i < 4; ++i){
    const float* kp = a.Kproj + (size_t)(ba*TT + tb + wave*4 + i)*HH;
    #pragma unroll
    for (int k = 0; k < 8; ++k) r_kp[i][k] = kp[lane + 64*k];
  }
  float r_e0[16], r_e1[16];
  #pragma unroll
  for (int lt = 0; lt < 16; ++lt){
    const float* er = a.enc + (size_t)(ba*TT + tb + lt)*HH;
    r_e0[lt] = er[tid];
    r_e1[lt] = er[tid + 256];
  }
  // enc_t prefetch for t=0
  float4 r_en[8];
  #pragma unroll
  for (int it = 0; it < 8; ++it){
    const int idx = (it*TPB + tid)*4;
    r_en[it] = *(const float4*)&a.enc[(size_t)((idx >> 9)*TT + 0)*HH + (idx & 511)];
  }
  __syncthreads();

  int e = 0;
  for (int t = 0; t < TT; ++t){
    const int par = t & 1, parn = par ^ 1;

    // ================= Phase A: h1 stage, logits(t-1), qW =================
    float2 r_h1[16], r_h0[16];
    {
      const float* h1p = a.H1buf + par*(BB*HH);
      const float* h0p = a.H0buf + par*(BB*HH);
      #pragma unroll
      for (int it = 0; it < 8; ++it){
        const int idx = (it*TPB + tid)*4;
        r_h1[2*it]   = ld2cc(&h1p[idx]);
        r_h1[2*it+1] = ld2cc(&h1p[idx + 2]);
      }
      #pragma unroll
      for (int it = 0; it < 8; ++it){
        const int idx = (it*TPB + tid)*4;
        r_h0[2*it]   = ld2cc(&h0p[idx]);
        r_h0[2*it+1] = ld2cc(&h0p[idx + 2]);
      }
    }
    #pragma unroll
    for (int it = 0; it < 8; ++it){
      const int idx = (it*TPB + tid)*4;
      float4 w; w.x=r_h1[2*it].x; w.y=r_h1[2*it].y; w.z=r_h1[2*it+1].x; w.w=r_h1[2*it+1].y;
      *(float4*)&S.stg[idx >> 9][idx & 511] = w;
    }
    __syncthreads();   // h1 staged (drains h0 loads too)

    if (wave < 2){
      if (t > 0){   // logits for step t-1 from staged h1
        const int d = bid*2 + wave, bo = d >> 5, vo = d & 31;
        float acc = 0.f;
        #pragma unroll
        for (int k = 0; k < 8; ++k){
          const int h = lane + 64*k;
          acc = fmaf(S.Wor[wave][h], S.stg[bo][h], acc);
        }
        #pragma unroll
        for (int off = 32; off; off >>= 1) acc += __shfl_xor(acc, off);
        if (lane == 0) a.out[(size_t)(bo*TT + (t-1))*VV + vo] = acc + S.boutv[wave];
      }
    } else {      // qW = h1 @ Wq^T + bq  (2 output rows per block)
      const int jj = wave - 2;
      const int off0 = lg * 128;
      float acc = 0.f;
      #pragma unroll 8
      for (int h = 0; h < 128; h += 4){
        const float4 w4 = *(const float4*)&S.Wqr[jj][off0 + h];
        const float4 x4 = *(const float4*)&S.stg[lb][off0 + h];
        acc = fmaf(w4.x,x4.x, fmaf(w4.y,x4.y, fmaf(w4.z,x4.z, fmaf(w4.w,x4.w, acc))));
      }
      acc += __shfl_xor(acc, 16);
      acc += __shfl_xor(acc, 32);
      if (lane < 16) stcc(&a.qWg[lane*HH + j0 + jj], acc + S.bqv[jj]);
    }

    e++; gbar_arrive(a.bar, e, bid);   // ---- B1 ARRIVE (qW stores drained) ----

    // B1 window: W1h dot + pre1, h0 stage, W0h dot + pre0  (intra-block only)
    dot_part(&S.W1h[0][0][0], S.stg, S.red, wave, lane);  // h1 @ Whh1^T
    __syncthreads();
    if (tid < 128){
      const int jj = tid >> 6, l = tid & 63, g = l >> 4, b = l & 15;
      S.pre1[b][g][jj] = S.red[2*jj][l] + S.red[2*jj+1][l] + S.bs1[g][jj];
    }
    #pragma unroll
    for (int it = 0; it < 8; ++it){
      const int idx = (it*TPB + tid)*4;
      float4 w; w.x=r_h0[2*it].x; w.y=r_h0[2*it].y; w.z=r_h0[2*it+1].x; w.w=r_h0[2*it+1].y;
      *(float4*)&S.stg[idx >> 9][idx & 511] = w;
    }
    __syncthreads();   // h0 staged, pre1 done
    dot_part(&S.W0h[0][0][0], S.stg, S.red, wave, lane);  // h0 @ Whh0^T
    __syncthreads();
    if (tid < 128){
      const int jj = tid >> 6, l = tid & 63, g = l >> 4, b = l & 15;
      S.pre0[b][g][jj] = S.red[2*jj][l] + S.red[2*jj+1][l] + S.bs0[g][jj];
    }

    gbar_wait(a.bar, e, bid);   // ---- B1 WAIT: qW visible ----

    // ================= Phase B: attention (critical path) =================
    {
      float* Up = a.Ug + par*(BB*HH);
      float* Zp = a.Zg + par*16;
      const float q0 = ldcc(&a.qWg[ba*HH + tid]);
      const float q1 = ldcc(&a.qWg[ba*HH + tid + 256]);
      S.qrow[tid] = q0; S.qrow[tid + 256] = q1;
      __syncthreads();
      #pragma unroll
      for (int i = 0; i < 4; ++i){
        float acc = 0.f;
        #pragma unroll
        for (int k = 0; k < 8; ++k){
          const int h = lane + 64*k;
          acc = fmaf(S.vv[h], ftanh(S.qrow[h] + r_kp[i][k]), acc);
        }
        #pragma unroll
        for (int off = 32; off; off >>= 1) acc += __shfl_xor(acc, off);
        if (lane == 0) S.scw[wave*4 + i] = __expf(acc + vb0);  // |score| <= ~18, exp safe
      }
      __syncthreads();
      float u0 = 0.f, u1 = 0.f;
      #pragma unroll
      for (int lt = 0; lt < 16; ++lt){
        const float w = S.scw[lt];
        u0 = fmaf(w, r_e0[lt], u0);
        u1 = fmaf(w, r_e1[lt], u1);
      }
      unsafeAtomicAdd(&Up[ba*HH + tid],       u0);
      unsafeAtomicAdd(&Up[ba*HH + tid + 256], u1);
      if (tid == 0){
        float zs = 0.f;
        #pragma unroll
        for (int lt = 0; lt < 16; ++lt) zs += S.scw[lt];
        unsafeAtomicAdd(&Zp[ba], zs);
      }
    }
    e++; gbar_arrive(a.bar, e, bid);   // ---- B2 ARRIVE (U/Z atomics drained) ----

    // B2 window: enc stage + W0e dot + combine (intra-block only)
    #pragma unroll
    for (int it = 0; it < 8; ++it){
      const int idx = (it*TPB + tid)*4;
      *(float4*)&S.stg[idx >> 9][idx & 511] = r_en[it];
    }
    __syncthreads();   // enc staged
    dot_part(&S.W0e[0][0][0], S.stg, S.red, wave, lane);  // enc_t part of Wih0
    __syncthreads();
    if (tid < 128){
      const int jj = tid >> 6, l = tid & 63, g = l >> 4, b = l & 15;
      S.pre0[b][g][jj] += S.red[2*jj][l] + S.red[2*jj+1][l];
    }

    gbar_wait(a.bar, e, bid);          // ---- B2 WAIT: U,Z complete ----

    // ================= Phase C: LSTM0 =================
    {
      const float* Up = a.Ug + par*(BB*HH);
      const float* Zp = a.Zg + par*16;
      float2 r_u[16]; float r_z[8];
      #pragma unroll
      for (int it = 0; it < 8; ++it){
        const int idx = (it*TPB + tid)*4;
        r_u[2*it]   = ld2cc(&Up[idx]);
        r_u[2*it+1] = ld2cc(&Up[idx + 2]);
        r_z[it]     = ldcc(&Zp[idx >> 9]);
      }
      #pragma unroll
      for (int it = 0; it < 8; ++it){            // ctx = U/Z -> stg
        const int idx = (it*TPB + tid)*4;
        const float zi = 1.0f / r_z[it];
        float4 u4;
        u4.x = r_u[2*it].x   * zi; u4.y = r_u[2*it].y   * zi;
        u4.z = r_u[2*it+1].x * zi; u4.w = r_u[2*it+1].y * zi;
        *(float4*)&S.stg[idx >> 9][idx & 511] = u4;
      }
      __syncthreads();
      dot_part(&S.W0c[0][0][0], S.stg, S.red, wave, lane);  // ctx part of Wih0
      __syncthreads();
      if (tid < 32){
        const int b = tid & 15, jj = tid >> 4;
        float gv[4];
        #pragma unroll
        for (int g = 0; g < 4; ++g)
          gv[g] = S.pre0[b][g][jj] + S.red[2*jj][g*16+b] + S.red[2*jj+1][g*16+b];
        const float cold = S.cst[0][jj][b];
        const float ii = fsig(gv[0]), ff = fsig(gv[1]);
        const float gg = ftanh(gv[2]), oo = fsig(gv[3]);
        const float cn = ff*cold + ii*gg;
        S.cst[0][jj][b] = cn;
        stcc(&a.H0buf[parn*(BB*HH) + b*HH + j0 + jj], oo * ftanh(cn));
      }
    }
    e++; gbar_arrive(a.bar, e, bid);   // ---- B3 ARRIVE (h0n stores drained) ----
    {
      // B3 window: prefetch next step's enc_t (read-only)
      const int tn = (t + 1 < TT) ? (t + 1) : t;
      #pragma unroll
      for (int it = 0; it < 8; ++it){
        const int idx = (it*TPB + tid)*4;
        r_en[it] = *(const float4*)&a.enc[(size_t)((idx >> 9)*TT + tn)*HH + (idx & 511)];
      }
    }
    gbar_wait(a.bar, e, bid);          // ---- B3 WAIT: h0n complete ----

    // ================= Phase D: LSTM1 =================
    {
      // zero next step's U/Z buffers (visibility rides barrier 4)
      if (tid < 32) stcc(&a.Ug[parn*(BB*HH) + bid*32 + tid], 0.0f);
      if (bid == 0 && tid < 16) stcc(&a.Zg[parn*16 + tid], 0.0f);

      stage_cc(a.H0buf + parn*(BB*HH), S.stg, tid);
      __syncthreads();
      dot_part(&S.W1x[0][0][0], S.stg, S.red, wave, lane);  // h0n @ Wih1^T
      __syncthreads();
      if (tid < 32){
        const int b = tid & 15, jj = tid >> 4;
        float gv[4];
        #pragma unroll
        for (int g = 0; g < 4; ++g)
          gv[g] = S.pre1[b][g][jj] + S.red[2*jj][g*16+b] + S.red[2*jj+1][g*16+b];
        const float cold = S.cst[1][jj][b];
        const float ii = fsig(gv[0]), ff = fsig(gv[1]);
        const float gg = ftanh(gv[2]), oo = fsig(gv[3]);
        const float cn = ff*cold + ii*gg;
        S.cst[1][jj][b] = cn;
        stcc(&a.H1buf[parn*(BB*HH) + b*HH + j0 + jj], oo * ftanh(cn));
      }
    }
    e++; gbar(a.bar, e, bid);   // ---- B4: h1n complete -> next step ----
  }

  // tail: logits for t=255 (final h1 is in H1buf[0] since (255+1)&1==0)
  {
    stage_cc(a.H1buf, S.stg, tid);
    __syncthreads();
    if (wave < 2){
      const int d = bid*2 + wave, bo = d >> 5, vo = d & 31;
      float acc = 0.f;
      #pragma unroll
      for (int k = 0; k < 8; ++k){
        const int h = lane + 64*k;
        acc = fmaf(S.Wor[wave][h], S.stg[bo][h], acc);
      }
      #pragma unroll
      for (int off = 32; off; off >>= 1) acc += __shfl_xor(acc, off);
      if (lane == 0) a.out[(size_t)(bo*TT + 255)*VV + vo] = acc + S.boutv[wave];
    }
  }
}

extern "C" void kernel_launch(void* const* d_in, const int* in_sizes, int n_in,
                              void* d_out, int out_size, void* d_ws, size_t ws_size,
                              hipStream_t stream){
  const float* enc  = (const float*)d_in[0];
  const float* h0in = (const float*)d_in[1];
  const float* c0in = (const float*)d_in[2];
  // d_in[3] audio_lengths: unused by the reference
  const float* Wq   = (const float*)d_in[4];
  const float* bq   = (const float*)d_in[5];
  const float* Wk   = (const float*)d_in[6];
  const float* bk   = (const float*)d_in[7];
  const float* vatt = (const float*)d_in[8];
  const float* vb   = (const float*)d_in[9];
  const float* Wih0 = (const float*)d_in[10];
  const float* bih0 = (const float*)d_in[11];
  const float* Whh0 = (const float*)d_in[12];
  const float* bhh0 = (const float*)d_in[13];
  const float* Wih1 = (const float*)d_in[14];
  const float* bih1 = (const float*)d_in[15];
  const float* Whh1 = (const float*)d_in[16];
  const float* bhh1 = (const float*)d_in[17];
  const float* Wout = (const float*)d_in[18];
  const float* bout = (const float*)d_in[19];

  float* ws    = (float*)d_ws;
  float* Kproj = ws;                               // B*T*H = 2097152
  float* H0buf = Kproj + (size_t)BB*TT*HH;         // 2*B*H
  float* H1buf = H0buf + 2*BB*HH;                  // 2*B*H
  float* qWg   = H1buf + 2*BB*HH;                  // B*H
  float* Ug    = qWg + BB*HH;                      // 2*B*H (parity double-buffer)
  float* Zg    = Ug + 2*BB*HH;                     // 2*16
  int*   bar   = (int*)(Zg + 32);                  // BAR_INTS ints

  hipLaunchKernelGGL(init_kernel, dim3(64), dim3(256), 0, stream,
                     h0in, H0buf, H1buf, Ug, Zg, bar);
  hipLaunchKernelGGL(kproj_kernel, dim3(256), dim3(256), 0, stream, enc, Wk, bk, Kproj);

  KArgs ka;
  ka.enc = enc; ka.c0in = c0in; ka.Wq = Wq; ka.bq = bq; ka.vatt = vatt; ka.vb = vb;
  ka.Wih0 = Wih0; ka.bih0 = bih0; ka.Whh0 = Whh0; ka.bhh0 = bhh0;
  ka.Wih1 = Wih1; ka.bih1 = bih1; ka.Whh1 = Whh1; ka.bhh1 = bhh1;
  ka.Wout = Wout; ka.bout = bout;
  ka.Kproj = Kproj; ka.H0buf = H0buf; ka.H1buf = H1buf;
  ka.qWg = qWg; ka.Ug = Ug; ka.Zg = Zg; ka.bar = bar; ka.out = (float*)d_out;

  void* params[] = { (void*)&ka };
  hipLaunchCooperativeKernel((const void*)decoder_persist, dim3(NBLK), dim3(TPB),
                             params, 0, stream);
}

// Round 10
// 6199.505 us; speedup vs baseline: 2.9754x; 1.0725x over previous
//
#include <hip/hip_runtime.h>

#define HH 512
#define BB 16
#define TT 256
#define VV 32
#define TPB 256
#define NBLK 256
#define PITCH 516   // LDS row pitch (floats)

#define BAR_INTS 256   // one epoch slot per block

struct KArgs {
  const float* enc; const float* c0in;
  const float* Wq; const float* bq; const float* vatt; const float* vb;
  const float* Wih0; const float* bih0; const float* Whh0; const float* bhh0;
  const float* Wih1; const float* bih1; const float* Whh1; const float* bhh1;
  const float* Wout; const float* bout;
  const float* Kproj; float* H0buf; float* H1buf; float* qWg; float* Ug; float* Zg;
  int* bar; float* out;
};

struct Smem {
  float W0e[4][2][PITCH];   // Wih0[g*512+j][0:512]    (enc_t part)
  float W0c[4][2][PITCH];   // Wih0[g*512+j][512:1024] (ctx part)
  float W0h[4][2][PITCH];   // Whh0
  float W1x[4][2][PITCH];   // Wih1
  float W1h[4][2][PITCH];   // Whh1
  float Wqr[2][PITCH];
  float Wor[2][PITCH];
  float vv[HH];
  float qrow[HH];
  float stg[BB][PITCH];     // staging: h1 -> h0 -> enc -> U -> h0n
  float red[4][64];         // per-wave dot partials
  float pre0[BB][4][2];     // gate partials L0 (h0+bias, then +enc)
  float pre1[BB][4][2];     // gate partials L1 (h1+bias)
  float cst[2][2][BB];      // c state [layer][jj][b]
  float scw[16];            // attention exp-weights for this block's t-chunk
  float zinv[BB];
  float bs0[4][2];
  float bs1[4][2];
  float bqv[2], boutv[2];
};

__device__ __forceinline__ float fsig(float x){ return 1.0f/(1.0f + __expf(-x)); }
__device__ __forceinline__ float ftanh(float x){
  float ee = __expf(2.0f*x);
  return 1.0f - 2.0f/(ee + 1.0f);
}

// relaxed agent-scope (cross-XCD coherent, write-through, no wb/inv) accessors
__device__ __forceinline__ void stcc(float* p, float v){
  __hip_atomic_store(p, v, __ATOMIC_RELAXED, __HIP_MEMORY_SCOPE_AGENT);
}
__device__ __forceinline__ float ldcc(const float* p){
  return __hip_atomic_load(p, __ATOMIC_RELAXED, __HIP_MEMORY_SCOPE_AGENT);
}
__device__ __forceinline__ float2 ld2cc(const float* p){
  unsigned long long v = __hip_atomic_load((const unsigned long long*)p,
                                           __ATOMIC_RELAXED, __HIP_MEMORY_SCOPE_AGENT);
  union { unsigned long long u; float2 f; } c; c.u = v;
  return c.f;
}

// contiguous coherent load of a 16x512 buffer: thread tid covers floats
// [(it*256+tid)*2, +1] — each wave instruction spans 512 contiguous bytes
__device__ __forceinline__ void ldbuf_cc(const float* __restrict__ src,
                                         float2* __restrict__ v, int tid){
  #pragma unroll
  for (int it = 0; it < 16; ++it)
    v[it] = ld2cc(&src[(it*TPB + tid)*2]);
}
__device__ __forceinline__ void stg_regs(const float2* __restrict__ v,
                                         float (* __restrict__ stg)[PITCH], int tid){
  #pragma unroll
  for (int it = 0; it < 16; ++it){
    const int i2 = (it*TPB + tid)*2;
    *(float2*)&stg[i2 >> 9][i2 & 511] = v[it];
  }
}

// ---- split device barrier (r8-proven): slot store + decentralized sweep ----
__device__ __forceinline__ void gbar_arrive(int* __restrict__ bar, int e, int bid){
  __syncthreads();   // per-wave vmcnt drain -> all coherent stores/atomics landed
  if (threadIdx.x == 0)
    __hip_atomic_store(&bar[bid], e, __ATOMIC_RELAXED, __HIP_MEMORY_SCOPE_AGENT);
}
__device__ __forceinline__ void gbar_wait(int* __restrict__ bar, int e, int bid){
  if (threadIdx.x < 64){
    const unsigned long long* p = (const unsigned long long*)bar;   // 128 ulls
    const int i0 = threadIdx.x * 2;
    int spins = 0;
    for (;;){
      unsigned long long v0 = __hip_atomic_load(&p[i0],     __ATOMIC_RELAXED, __HIP_MEMORY_SCOPE_AGENT);
      unsigned long long v1 = __hip_atomic_load(&p[i0 + 1], __ATOMIC_RELAXED, __HIP_MEMORY_SCOPE_AGENT);
      const int a0 = (int)v0, a1 = (int)(v0 >> 32), a2 = (int)v1, a3 = (int)(v1 >> 32);
      const int ok = (a0 >= e) & (a1 >= e) & (a2 >= e) & (a3 >= e);
      if (__all(ok)) break;
      __builtin_amdgcn_s_sleep(2);
      if (++spins > (1 << 20)) break;   // safety valve
    }
  }
  __syncthreads();
}
__device__ __forceinline__ void gbar(int* __restrict__ bar, int e, int bid){
  gbar_arrive(bar, e, bid);
  gbar_wait(bar, e, bid);
}

// wave w handles (jj = w>>1, h-half = w&1); lane = (g<<4)|b ; writes red[w][lane]
__device__ __forceinline__ void dot_part(const float* __restrict__ W,
                                         const float (* __restrict__ stg)[PITCH],
                                         float (* __restrict__ red)[64],
                                         int wave, int lane){
  const int jj = wave >> 1, off = (wave & 1) << 8;
  const int b = lane & 15, g = lane >> 4;
  const float* wrow = W + (size_t)(g*2 + jj)*PITCH + off;
  const float* xrow = &stg[b][off];
  float acc = 0.f;
  #pragma unroll 8
  for (int h = 0; h < 256; h += 4){
    const float4 w4 = *(const float4*)&wrow[h];
    const float4 x4 = *(const float4*)&xrow[h];
    acc = fmaf(w4.x,x4.x, fmaf(w4.y,x4.y, fmaf(w4.z,x4.z, fmaf(w4.w,x4.w, acc))));
  }
  red[wave][lane] = acc;
}

__global__ void init_kernel(const float* __restrict__ h0in, float* __restrict__ H0buf,
                            float* __restrict__ H1buf, float* __restrict__ Ug,
                            float* __restrict__ Zg, int* __restrict__ bar){
  const int i = blockIdx.x*blockDim.x + threadIdx.x;
  if (i < BB*HH){
    H0buf[i] = h0in[i];            // layer 0
    H1buf[i] = h0in[BB*HH + i];    // layer 1
  }
  if (i < 2*BB*HH) Ug[i] = 0.0f;
  if (i < 32) Zg[i] = 0.0f;
  if (i < BAR_INTS) bar[i] = 0;
}

// Kproj = enc @ Wk^T + bk : 256 blocks x 16 (b,t)-rows, x register-cached
__global__ __launch_bounds__(256, 1) void kproj_kernel(const float* __restrict__ enc,
                                                       const float* __restrict__ Wk,
                                                       const float* __restrict__ bk,
                                                       float* __restrict__ Kproj){
  __shared__ float er[BB][PITCH];
  const int bid = blockIdx.x, tid = threadIdx.x;
  const int wave = tid >> 6, lane = tid & 63;
  const int r = lane & 15, q = lane >> 4;
  const int row0 = bid*16;
  #pragma unroll
  for (int it = 0; it < 8; ++it){
    const int idx = (it*256 + tid)*4;
    const int rr = idx >> 9, h = idx & 511;
    *(float4*)&er[rr][h] = *(const float4*)&enc[(size_t)(row0+rr)*HH + h];
  }
  __syncthreads();
  float4 xr[32];
  #pragma unroll
  for (int i = 0; i < 32; ++i) xr[i] = *(const float4*)&er[r][q*128 + i*4];
  for (int k = 0; k < 128; ++k){
    const int hk = wave*128 + k;
    const float* wrow = Wk + (size_t)hk*HH + q*128;
    float acc = 0.f;
    #pragma unroll
    for (int i = 0; i < 32; ++i){
      const float4 w4 = *(const float4*)&wrow[i*4];
      acc = fmaf(w4.x,xr[i].x, fmaf(w4.y,xr[i].y, fmaf(w4.z,xr[i].z, fmaf(w4.w,xr[i].w, acc))));
    }
    acc += __shfl_xor(acc, 16);
    acc += __shfl_xor(acc, 32);
    if (lane < 16) Kproj[(size_t)(row0 + r)*HH + hk] = acc + bk[hk];
  }
}

__global__ __launch_bounds__(TPB, 1) void decoder_persist(KArgs a){
  __shared__ Smem S;
  const int bid = blockIdx.x, tid = threadIdx.x;
  const int wave = tid >> 6, lane = tid & 63;
  const int lb = lane & 15, lg = lane >> 4;
  const int j0 = bid*2;
  const int ba = bid >> 4, tb = (bid & 15) * 16;   // attention assignment

  // ---- one-time: weights to LDS ----
  for (int g = 0; g < 4; ++g){
    for (int jj = 0; jj < 2; ++jj){
      const int row = g*HH + j0 + jj;
      for (int h = tid; h < HH; h += TPB){
        S.W0e[g][jj][h] = a.Wih0[(size_t)row*(2*HH) + h];
        S.W0c[g][jj][h] = a.Wih0[(size_t)row*(2*HH) + HH + h];
        S.W0h[g][jj][h] = a.Whh0[(size_t)row*HH + h];
        S.W1x[g][jj][h] = a.Wih1[(size_t)row*HH + h];
        S.W1h[g][jj][h] = a.Whh1[(size_t)row*HH + h];
      }
    }
  }
  for (int jj = 0; jj < 2; ++jj){
    const int d = bid*2 + jj, vo = d & 31;
    for (int h = tid; h < HH; h += TPB){
      S.Wqr[jj][h] = a.Wq[(size_t)(j0+jj)*HH + h];
      S.Wor[jj][h] = a.Wout[(size_t)vo*HH + h];
    }
  }
  for (int h = tid; h < HH; h += TPB) S.vv[h] = a.vatt[h];
  if (tid < 16){
    S.cst[0][0][tid] = a.c0in[0*BB*HH + tid*HH + j0];
    S.cst[0][1][tid] = a.c0in[0*BB*HH + tid*HH + j0 + 1];
    S.cst[1][0][tid] = a.c0in[1*BB*HH + tid*HH + j0];
    S.cst[1][1][tid] = a.c0in[1*BB*HH + tid*HH + j0 + 1];
  }
  if (tid < 8){
    const int g = tid & 3, jj = tid >> 2;
    const int row = g*HH + j0 + jj;
    S.bs0[g][jj] = a.bih0[row] + a.bhh0[row];
    S.bs1[g][jj] = a.bih1[row] + a.bhh1[row];
  }
  if (tid < 2){
    S.bqv[tid] = a.bq[j0 + tid];
    S.boutv[tid] = a.bout[(bid*2 + tid) & 31];
  }
  const float vb0 = a.vb[0];

  // ---- step-invariant attention operands -> registers ----
  float r_kp[4][8];
  #pragma unroll
  for (int i = 0; i < 4; ++i){
    const float* kp = a.Kproj + (size_t)(ba*TT + tb + wave*4 + i)*HH;
    #pragma unroll
    for (int k = 0; k < 8; ++k) r_kp[i][k] = kp[lane + 64*k];
  }
  float r_e0[16], r_e1[16];
  #pragma unroll
  for (int lt = 0; lt < 16; ++lt){
    const float* er = a.enc + (size_t)(ba*TT + tb + lt)*HH;
    r_e0[lt] = er[tid];
    r_e1[lt] = er[tid + 256];
  }
  // enc_t prefetch for t=0
  float4 r_en[8];
  #pragma unroll
  for (int it = 0; it < 8; ++it){
    const int idx = (it*TPB + tid)*4;
    r_en[it] = *(const float4*)&a.enc[(size_t)((idx >> 9)*TT + 0)*HH + (idx & 511)];
  }
  __syncthreads();

  int e = 0;
  for (int t = 0; t < TT; ++t){
    const int par = t & 1, parn = par ^ 1;

    // ================= Phase A: h1 only (contiguous), logits(t-1), qW =======
    float2 r_h1[16];
    ldbuf_cc(a.H1buf + par*(BB*HH), r_h1, tid);
    stg_regs(r_h1, S.stg, tid);
    __syncthreads();   // h1 staged

    if (wave < 2){
      if (t > 0){   // logits for step t-1 from staged h1
        const int d = bid*2 + wave, bo = d >> 5, vo = d & 31;
        float acc = 0.f;
        #pragma unroll
        for (int k = 0; k < 8; ++k){
          const int h = lane + 64*k;
          acc = fmaf(S.Wor[wave][h], S.stg[bo][h], acc);
        }
        #pragma unroll
        for (int off = 32; off; off >>= 1) acc += __shfl_xor(acc, off);
        if (lane == 0) a.out[(size_t)(bo*TT + (t-1))*VV + vo] = acc + S.boutv[wave];
      }
    } else {      // qW = h1 @ Wq^T + bq  (2 output rows per block)
      const int jj = wave - 2;
      const int off0 = lg * 128;
      float acc = 0.f;
      #pragma unroll 8
      for (int h = 0; h < 128; h += 4){
        const float4 w4 = *(const float4*)&S.Wqr[jj][off0 + h];
        const float4 x4 = *(const float4*)&S.stg[lb][off0 + h];
        acc = fmaf(w4.x,x4.x, fmaf(w4.y,x4.y, fmaf(w4.z,x4.z, fmaf(w4.w,x4.w, acc))));
      }
      acc += __shfl_xor(acc, 16);
      acc += __shfl_xor(acc, 32);
      if (lane < 16) stcc(&a.qWg[lane*HH + j0 + jj], acc + S.bqv[jj]);
    }

    e++; gbar_arrive(a.bar, e, bid);   // ---- B1 ARRIVE (only qW + h1-loads drained) ----

    // B1 window: issue h0 loads, W1h dot + pre1, h0 stage, W0h dot + pre0
    float2 r_h0[16];
    ldbuf_cc(a.H0buf + par*(BB*HH), r_h0, tid);   // latency hides under W1h dot
    dot_part(&S.W1h[0][0][0], S.stg, S.red, wave, lane);  // h1 @ Whh1^T
    __syncthreads();
    if (tid < 128){
      const int jj = tid >> 6, l = tid & 63, g = l >> 4, b = l & 15;
      S.pre1[b][g][jj] = S.red[2*jj][l] + S.red[2*jj+1][l] + S.bs1[g][jj];
    }
    stg_regs(r_h0, S.stg, tid);
    __syncthreads();   // h0 staged, pre1 done
    dot_part(&S.W0h[0][0][0], S.stg, S.red, wave, lane);  // h0 @ Whh0^T
    __syncthreads();
    if (tid < 128){
      const int jj = tid >> 6, l = tid & 63, g = l >> 4, b = l & 15;
      S.pre0[b][g][jj] = S.red[2*jj][l] + S.red[2*jj+1][l] + S.bs0[g][jj];
    }

    gbar_wait(a.bar, e, bid);   // ---- B1 WAIT: qW visible ----

    // ================= Phase B: attention (critical path) =================
    {
      float* Up = a.Ug + par*(BB*HH);
      float* Zp = a.Zg + par*16;
      const float2 q2 = ld2cc(&a.qWg[ba*HH + tid*2]);
      *(float2*)&S.qrow[tid*2] = q2;
      __syncthreads();
      #pragma unroll
      for (int i = 0; i < 4; ++i){
        float acc = 0.f;
        #pragma unroll
        for (int k = 0; k < 8; ++k){
          const int h = lane + 64*k;
          acc = fmaf(S.vv[h], ftanh(S.qrow[h] + r_kp[i][k]), acc);
        }
        #pragma unroll
        for (int off = 32; off; off >>= 1) acc += __shfl_xor(acc, off);
        if (lane == 0) S.scw[wave*4 + i] = __expf(acc + vb0);  // |score| <= ~18, exp safe
      }
      __syncthreads();
      float u0 = 0.f, u1 = 0.f;
      #pragma unroll
      for (int lt = 0; lt < 16; ++lt){
        const float w = S.scw[lt];
        u0 = fmaf(w, r_e0[lt], u0);
        u1 = fmaf(w, r_e1[lt], u1);
      }
      unsafeAtomicAdd(&Up[ba*HH + tid],       u0);
      unsafeAtomicAdd(&Up[ba*HH + tid + 256], u1);
      if (tid == 0){
        float zs = 0.f;
        #pragma unroll
        for (int lt = 0; lt < 16; ++lt) zs += S.scw[lt];
        unsafeAtomicAdd(&Zp[ba], zs);
      }
    }
    e++; gbar_arrive(a.bar, e, bid);   // ---- B2 ARRIVE (U/Z atomics drained) ----

    // B2 window: enc stage + W0e dot + combine
    #pragma unroll
    for (int it = 0; it < 8; ++it){
      const int idx = (it*TPB + tid)*4;
      *(float4*)&S.stg[idx >> 9][idx & 511] = r_en[it];
    }
    __syncthreads();   // enc staged
    dot_part(&S.W0e[0][0][0], S.stg, S.red, wave, lane);  // enc_t part of Wih0
    __syncthreads();
    if (tid < 128){
      const int jj = tid >> 6, l = tid & 63, g = l >> 4, b = l & 15;
      S.pre0[b][g][jj] += S.red[2*jj][l] + S.red[2*jj+1][l];
    }

    gbar_wait(a.bar, e, bid);          // ---- B2 WAIT: U,Z complete ----

    // ================= Phase C: LSTM0 (raw-U dot, post-scale by 1/Z) ========
    {
      float2 r_u[16];
      ldbuf_cc(a.Ug + par*(BB*HH), r_u, tid);
      if (tid < 16) S.zinv[tid] = 1.0f / ldcc(&a.Zg[par*16 + tid]);
      stg_regs(r_u, S.stg, tid);
      __syncthreads();
      dot_part(&S.W0c[0][0][0], S.stg, S.red, wave, lane);  // raw-U part of Wih0
      __syncthreads();
      if (tid < 32){
        const int b = tid & 15, jj = tid >> 4;
        const float zi = S.zinv[b];
        float gv[4];
        #pragma unroll
        for (int g = 0; g < 4; ++g)
          gv[g] = S.pre0[b][g][jj] + (S.red[2*jj][g*16+b] + S.red[2*jj+1][g*16+b]) * zi;
        const float cold = S.cst[0][jj][b];
        const float ii = fsig(gv[0]), ff = fsig(gv[1]);
        const float gg = ftanh(gv[2]), oo = fsig(gv[3]);
        const float cn = ff*cold + ii*gg;
        S.cst[0][jj][b] = cn;
        stcc(&a.H0buf[parn*(BB*HH) + b*HH + j0 + jj], oo * ftanh(cn));
      }
    }
    e++; gbar_arrive(a.bar, e, bid);   // ---- B3 ARRIVE (h0n stores drained) ----
    {
      // B3 window: prefetch next step's enc_t (read-only)
      const int tn = (t + 1 < TT) ? (t + 1) : t;
      #pragma unroll
      for (int it = 0; it < 8; ++it){
        const int idx = (it*TPB + tid)*4;
        r_en[it] = *(const float4*)&a.enc[(size_t)((idx >> 9)*TT + tn)*HH + (idx & 511)];
      }
    }
    gbar_wait(a.bar, e, bid);          // ---- B3 WAIT: h0n complete ----

    // ================= Phase D: LSTM1 =================
    {
      // zero next step's U/Z buffers (visibility rides barrier 4)
      if (tid < 32) stcc(&a.Ug[parn*(BB*HH) + bid*32 + tid], 0.0f);
      if (bid == 0 && tid < 16) stcc(&a.Zg[parn*16 + tid], 0.0f);

      float2 r_x[16];
      ldbuf_cc(a.H0buf + parn*(BB*HH), r_x, tid);
      stg_regs(r_x, S.stg, tid);
      __syncthreads();
      dot_part(&S.W1x[0][0][0], S.stg, S.red, wave, lane);  // h0n @ Wih1^T
      __syncthreads();
      if (tid < 32){
        const int b = tid & 15, jj = tid >> 4;
        float gv[4];
        #pragma unroll
        for (int g = 0; g < 4; ++g)
          gv[g] = S.pre1[b][g][jj] + S.red[2*jj][g*16+b] + S.red[2*jj+1][g*16+b];
        const float cold = S.cst[1][jj][b];
        const float ii = fsig(gv[0]), ff = fsig(gv[1]);
        const float gg = ftanh(gv[2]), oo = fsig(gv[3]);
        const float cn = ff*cold + ii*gg;
        S.cst[1][jj][b] = cn;
        stcc(&a.H1buf[parn*(BB*HH) + b*HH + j0 + jj], oo * ftanh(cn));
      }
    }
    e++; gbar(a.bar, e, bid);   // ---- B4: h1n complete -> next step ----
  }

  // tail: logits for t=255 (final h1 is in H1buf[0] since (255+1)&1==0)
  {
    float2 r_x[16];
    ldbuf_cc(a.H1buf, r_x, tid);
    stg_regs(r_x, S.stg, tid);
    __syncthreads();
    if (wave < 2){
      const int d = bid*2 + wave, bo = d >> 5, vo = d & 31;
      float acc = 0.f;
      #pragma unroll
      for (int k = 0; k < 8; ++k){
        const int h = lane + 64*k;
        acc = fmaf(S.Wor[wave][h], S.stg[bo][h], acc);
      }
      #pragma unroll
      for (int off = 32; off; off >>= 1) acc += __shfl_xor(acc, off);
      if (lane == 0) a.out[(size_t)(bo*TT + 255)*VV + vo] = acc + S.boutv[wave];
    }
  }
}

extern "C" void kernel_launch(void* const* d_in, const int* in_sizes, int n_in,
                              void* d_out, int out_size, void* d_ws, size_t ws_size,
                              hipStream_t stream){
  const float* enc  = (const float*)d_in[0];
  const float* h0in = (const float*)d_in[1];
  const float* c0in = (const float*)d_in[2];
  // d_in[3] audio_lengths: unused by the reference
  const float* Wq   = (const float*)d_in[4];
  const float* bq   = (const float*)d_in[5];
  const float* Wk   = (const float*)d_in[6];
  const float* bk   = (const float*)d_in[7];
  const float* vatt = (const float*)d_in[8];
  const float* vb   = (const float*)d_in[9];
  const float* Wih0 = (const float*)d_in[10];
  const float* bih0 = (const float*)d_in[11];
  const float* Whh0 = (const float*)d_in[12];
  const float* bhh0 = (const float*)d_in[13];
  const float* Wih1 = (const float*)d_in[14];
  const float* bih1 = (const float*)d_in[15];
  const float* Whh1 = (const float*)d_in[16];
  const float* bhh1 = (const float*)d_in[17];
  const float* Wout = (const float*)d_in[18];
  const float* bout = (const float*)d_in[19];

  float* ws    = (float*)d_ws;
  float* Kproj = ws;                               // B*T*H = 2097152
  float* H0buf = Kproj + (size_t)BB*TT*HH;         // 2*B*H
  float* H1buf = H0buf + 2*BB*HH;                  // 2*B*H
  float* qWg   = H1buf + 2*BB*HH;                  // B*H
  float* Ug    = qWg + BB*HH;                      // 2*B*H (parity double-buffer)
  float* Zg    = Ug + 2*BB*HH;                     // 2*16
  int*   bar   = (int*)(Zg + 32);                  // BAR_INTS ints

  hipLaunchKernelGGL(init_kernel, dim3(64), dim3(256), 0, stream,
                     h0in, H0buf, H1buf, Ug, Zg, bar);
  hipLaunchKernelGGL(kproj_kernel, dim3(256), dim3(256), 0, stream, enc, Wk, bk, Kproj);

  KArgs ka;
  ka.enc = enc; ka.c0in = c0in; ka.Wq = Wq; ka.bq = bq; ka.vatt = vatt; ka.vb = vb;
  ka.Wih0 = Wih0; ka.bih0 = bih0; ka.Whh0 = Whh0; ka.bhh0 = bhh0;
  ka.Wih1 = Wih1; ka.bih1 = bih1; ka.Whh1 = Whh1; ka.bhh1 = bhh1;
  ka.Wout = Wout; ka.bout = bout;
  ka.Kproj = Kproj; ka.H0buf = H0buf; ka.H1buf = H1buf;
  ka.qWg = qWg; ka.Ug = Ug; ka.Zg = Zg; ka.bar = bar; ka.out = (float*)d_out;

  void* params[] = { (void*)&ka };
  hipLaunchCooperativeKernel((const void*)decoder_persist, dim3(NBLK), dim3(TPB),
                             params, 0, stream);
}

// Round 12
// 5321.335 us; speedup vs baseline: 3.4664x; 1.1650x over previous
//
#include <hip/hip_runtime.h>

#define HH 512
#define BB 16
#define TT 256
#define VV 32
#define TPB 256
#define NBLK 256
#define PITCH 516   // LDS row pitch (floats)

#define BAR_INTS 512   // 256 global slots + 256 per-group slots

struct KArgs {
  const float* enc; const float* h0in; const float* c0in;
  const float* Wq; const float* bq; const float* vatt; const float* vb;
  const float* Wih0; const float* bih0; const float* Whh0; const float* bhh0;
  const float* Wih1; const float* bih1; const float* Whh1; const float* bhh1;
  const float* Wout; const float* bout;
  const float* Kproj; float* H0buf; float* H1buf; float* qWg; float* Ug; float* Zg;
  int* bar; float* out;
};

struct Smem {
  float W0e[4][2][PITCH];   // Wih0[g*512+j][0:512]    (enc_t part)
  float W0c[4][2][PITCH];   // Wih0[g*512+j][512:1024] (ctx part)
  float W0h[4][2][PITCH];   // Whh0
  float W1x[4][2][PITCH];   // Wih1
  float W1h[4][2][PITCH];   // Whh1
  float Wqr[2][PITCH];
  float Wor[2][PITCH];
  float vv[HH];
  float qrow[HH];
  float stg[BB][PITCH];     // staging: h1 -> enc -> U -> h0n
  float red[4][64];         // per-wave dot partials
  float pre0[BB][4][2];     // bs0 + W0h*h0_prev (B4win of t-1) + W0e*enc (B1win of t)
  float pre1[BB][4][2];     // bs1 + W1h*h1_prev (B1win of t)
  float cst[2][2][BB];      // c state [layer][jj][b]
  float scw[16];            // attention exp-weights
  float zinv[BB];
  float bs0[4][2];
  float bs1[4][2];
  float bqv[2], boutv[2];
};

__device__ __forceinline__ float fsig(float x){ return 1.0f/(1.0f + __expf(-x)); }
__device__ __forceinline__ float ftanh(float x){
  float ee = __expf(2.0f*x);
  return 1.0f - 2.0f/(ee + 1.0f);
}

// relaxed agent-scope (cross-XCD coherent, write-through, no wb/inv) — proven transport
__device__ __forceinline__ void stcc(float* p, float v){
  __hip_atomic_store(p, v, __ATOMIC_RELAXED, __HIP_MEMORY_SCOPE_AGENT);
}
__device__ __forceinline__ float ldcc(const float* p){
  return __hip_atomic_load(p, __ATOMIC_RELAXED, __HIP_MEMORY_SCOPE_AGENT);
}
__device__ __forceinline__ float2 ld2cc(const float* p){
  unsigned long long v = __hip_atomic_load((const unsigned long long*)p,
                                           __ATOMIC_RELAXED, __HIP_MEMORY_SCOPE_AGENT);
  union { unsigned long long u; float2 f; } c; c.u = v;
  return c.f;
}

// contiguous coherent load of a 16x512 buffer + LDS stage
__device__ __forceinline__ void ldbuf_cc(const float* __restrict__ src,
                                         float2* __restrict__ v, int tid){
  #pragma unroll
  for (int it = 0; it < 16; ++it)
    v[it] = ld2cc(&src[(it*TPB + tid)*2]);
}
__device__ __forceinline__ void stg_regs(const float2* __restrict__ v,
                                         float (* __restrict__ stg)[PITCH], int tid){
  #pragma unroll
  for (int it = 0; it < 16; ++it){
    const int i2 = (it*TPB + tid)*2;
    *(float2*)&stg[i2 >> 9][i2 & 511] = v[it];
  }
}

// ---- global split barrier (r8/r10-proven): slot store + decentralized sweep ----
__device__ __forceinline__ void gbar_arrive(int* __restrict__ bar, int e, int bid){
  __syncthreads();   // per-wave vmcnt drain -> all coherent stores/atomics landed
  if (threadIdx.x == 0)
    __hip_atomic_store(&bar[bid], e, __ATOMIC_RELAXED, __HIP_MEMORY_SCOPE_AGENT);
}
__device__ __forceinline__ void gbar_wait(int* __restrict__ bar, int e, int bid){
  if (threadIdx.x < 64){
    const unsigned long long* p = (const unsigned long long*)bar;   // 128 ulls
    const int i0 = threadIdx.x * 2;
    int spins = 0;
    for (;;){
      unsigned long long v0 = __hip_atomic_load(&p[i0],     __ATOMIC_RELAXED, __HIP_MEMORY_SCOPE_AGENT);
      unsigned long long v1 = __hip_atomic_load(&p[i0 + 1], __ATOMIC_RELAXED, __HIP_MEMORY_SCOPE_AGENT);
      const int a0 = (int)v0, a1 = (int)(v0 >> 32), a2 = (int)v1, a3 = (int)(v1 >> 32);
      const int ok = (a0 >= e) & (a1 >= e) & (a2 >= e) & (a3 >= e);
      if (__all(ok)) break;
      __builtin_amdgcn_s_sleep(2);
      if (++spins > (1 << 20)) break;   // safety valve
    }
  }
  __syncthreads();
}
__device__ __forceinline__ void gbar(int* __restrict__ bar, int e, int bid){
  gbar_arrive(bar, e, bid);
  gbar_wait(bar, e, bid);
}

// ---- per-group (16-block) barrier: same primitives, group-ba slots ----
__device__ __forceinline__ void gbar2(int* __restrict__ bar2, int et, int bid, int ba){
  __syncthreads();   // drains this block's U/Z atomics (compiler vmcnt(0) before s_barrier)
  if (threadIdx.x == 0)
    __hip_atomic_store(&bar2[bid], et, __ATOMIC_RELAXED, __HIP_MEMORY_SCOPE_AGENT);
  if (threadIdx.x < 64){
    const unsigned long long* p = (const unsigned long long*)bar2 + ba*8;  // 16 ints
    int spins = 0;
    for (;;){
      int ok = 1;
      if (threadIdx.x < 8){
        unsigned long long v = __hip_atomic_load(&p[threadIdx.x], __ATOMIC_RELAXED, __HIP_MEMORY_SCOPE_AGENT);
        ok = ((int)v >= et) & ((int)(v >> 32) >= et);
      }
      if (__all(ok)) break;
      __builtin_amdgcn_s_sleep(1);
      if (++spins > (1 << 20)) break;   // safety valve
    }
  }
  __syncthreads();
}

// wave w handles (jj = w>>1, h-half = w&1); lane = (g<<4)|b ; writes red[w][lane]
__device__ __forceinline__ void dot_part(const float* __restrict__ W,
                                         const float (* __restrict__ stg)[PITCH],
                                         float (* __restrict__ red)[64],
                                         int wave, int lane){
  const int jj = wave >> 1, off = (wave & 1) << 8;
  const int b = lane & 15, g = lane >> 4;
  const float* wrow = W + (size_t)(g*2 + jj)*PITCH + off;
  const float* xrow = &stg[b][off];
  float acc = 0.f;
  #pragma unroll 8
  for (int h = 0; h < 256; h += 4){
    const float4 w4 = *(const float4*)&wrow[h];
    const float4 x4 = *(const float4*)&xrow[h];
    acc = fmaf(w4.x,x4.x, fmaf(w4.y,x4.y, fmaf(w4.z,x4.z, fmaf(w4.w,x4.w, acc))));
  }
  red[wave][lane] = acc;
}

__global__ void init_kernel(const float* __restrict__ h0in, float* __restrict__ H0buf,
                            float* __restrict__ H1buf, float* __restrict__ Ug,
                            float* __restrict__ Zg, int* __restrict__ bar){
  const int i = blockIdx.x*blockDim.x + threadIdx.x;
  if (i < BB*HH){
    H0buf[i] = h0in[i];            // layer 0
    H1buf[i] = h0in[BB*HH + i];    // layer 1
  }
  if (i < 2*BB*HH) Ug[i] = 0.0f;
  if (i < 32) Zg[i] = 0.0f;
  if (i < BAR_INTS) bar[i] = 0;
}

// Kproj = enc @ Wk^T + bk : 256 blocks x 16 (b,t)-rows, x register-cached
__global__ __launch_bounds__(256, 1) void kproj_kernel(const float* __restrict__ enc,
                                                       const float* __restrict__ Wk,
                                                       const float* __restrict__ bk,
                                                       float* __restrict__ Kproj){
  __shared__ float er[BB][PITCH];
  const int bid = blockIdx.x, tid = threadIdx.x;
  const int wave = tid >> 6, lane = tid & 63;
  const int r = lane & 15, q = lane >> 4;
  const int row0 = bid*16;
  #pragma unroll
  for (int it = 0; it < 8; ++it){
    const int idx = (it*256 + tid)*4;
    const int rr = idx >> 9, h = idx & 511;
    *(float4*)&er[rr][h] = *(const float4*)&enc[(size_t)(row0+rr)*HH + h];
  }
  __syncthreads();
  float4 xr[32];
  #pragma unroll
  for (int i = 0; i < 32; ++i) xr[i] = *(const float4*)&er[r][q*128 + i*4];
  for (int k = 0; k < 128; ++k){
    const int hk = wave*128 + k;
    const float* wrow = Wk + (size_t)hk*HH + q*128;
    float acc = 0.f;
    #pragma unroll
    for (int i = 0; i < 32; ++i){
      const float4 w4 = *(const float4*)&wrow[i*4];
      acc = fmaf(w4.x,xr[i].x, fmaf(w4.y,xr[i].y, fmaf(w4.z,xr[i].z, fmaf(w4.w,xr[i].w, acc))));
    }
    acc += __shfl_xor(acc, 16);
    acc += __shfl_xor(acc, 32);
    if (lane < 16) Kproj[(size_t)(row0 + r)*HH + hk] = acc + bk[hk];
  }
}

__global__ __launch_bounds__(TPB, 1) void decoder_persist(KArgs a){
  __shared__ Smem S;
  const int bid = blockIdx.x, tid = threadIdx.x;
  const int wave = tid >> 6, lane = tid & 63;
  const int lb = lane & 15, lg = lane >> 4;
  const int j0 = bid*2;
  const int ba = bid >> 4, tb = (bid & 15) * 16;   // attention assignment
  int* bar2 = a.bar + 256;

  // ---- one-time: weights to LDS ----
  for (int g = 0; g < 4; ++g){
    for (int jj = 0; jj < 2; ++jj){
      const int row = g*HH + j0 + jj;
      for (int h = tid; h < HH; h += TPB){
        S.W0e[g][jj][h] = a.Wih0[(size_t)row*(2*HH) + h];
        S.W0c[g][jj][h] = a.Wih0[(size_t)row*(2*HH) + HH + h];
        S.W0h[g][jj][h] = a.Whh0[(size_t)row*HH + h];
        S.W1x[g][jj][h] = a.Wih1[(size_t)row*HH + h];
        S.W1h[g][jj][h] = a.Whh1[(size_t)row*HH + h];
      }
    }
  }
  for (int jj = 0; jj < 2; ++jj){
    const int d = bid*2 + jj, vo = d & 31;
    for (int h = tid; h < HH; h += TPB){
      S.Wqr[jj][h] = a.Wq[(size_t)(j0+jj)*HH + h];
      S.Wor[jj][h] = a.Wout[(size_t)vo*HH + h];
    }
  }
  for (int h = tid; h < HH; h += TPB) S.vv[h] = a.vatt[h];
  if (tid < 16){
    S.cst[0][0][tid] = a.c0in[0*BB*HH + tid*HH + j0];
    S.cst[0][1][tid] = a.c0in[0*BB*HH + tid*HH + j0 + 1];
    S.cst[1][0][tid] = a.c0in[1*BB*HH + tid*HH + j0];
    S.cst[1][1][tid] = a.c0in[1*BB*HH + tid*HH + j0 + 1];
  }
  if (tid < 8){
    const int g = tid & 3, jj = tid >> 2;
    const int row = g*HH + j0 + jj;
    S.bs0[g][jj] = a.bih0[row] + a.bhh0[row];
    S.bs1[g][jj] = a.bih1[row] + a.bhh1[row];
  }
  if (tid < 2){
    S.bqv[tid] = a.bq[j0 + tid];
    S.boutv[tid] = a.bout[(bid*2 + tid) & 31];
  }
  const float vb0 = a.vb[0];

  // ---- step-invariant attention operands -> registers ----
  float r_kp[4][8];
  #pragma unroll
  for (int i = 0; i < 4; ++i){
    const float* kp = a.Kproj + (size_t)(ba*TT + tb + wave*4 + i)*HH;
    #pragma unroll
    for (int k = 0; k < 8; ++k) r_kp[i][k] = kp[lane + 64*k];
  }
  float r_e0[16], r_e1[16];
  #pragma unroll
  for (int lt = 0; lt < 16; ++lt){
    const float* er = a.enc + (size_t)(ba*TT + tb + lt)*HH;
    r_e0[lt] = er[tid];
    r_e1[lt] = er[tid + 256];
  }
  // enc_t prefetch for t=0
  float4 r_en[8];
  #pragma unroll
  for (int it = 0; it < 8; ++it){
    const int idx = (it*TPB + tid)*4;
    r_en[it] = *(const float4*)&a.enc[(size_t)((idx >> 9)*TT + 0)*HH + (idx & 511)];
  }
  __syncthreads();

  // ---- prologue: pre0 = bs0 + W0h @ h0_init (h0in layer 0, plain cached loads) ----
  {
    #pragma unroll
    for (int it = 0; it < 8; ++it){
      const int idx = (it*TPB + tid)*4;
      *(float4*)&S.stg[idx >> 9][idx & 511] = *(const float4*)&a.h0in[idx];
    }
    __syncthreads();
    dot_part(&S.W0h[0][0][0], S.stg, S.red, wave, lane);
    __syncthreads();
    if (tid < 128){
      const int jj = tid >> 6, l = tid & 63, g = l >> 4, b = l & 15;
      S.pre0[b][g][jj] = S.red[2*jj][l] + S.red[2*jj+1][l] + S.bs0[g][jj];
    }
    __syncthreads();
  }

  int e = 0;
  for (int t = 0; t < TT; ++t){
    const int par = t & 1, parn = par ^ 1;

    // ========== Phase A: h1 load+stage, logits(t-1), qW ==========
    float2 r_h1[16];
    ldbuf_cc(a.H1buf + par*(BB*HH), r_h1, tid);
    stg_regs(r_h1, S.stg, tid);
    __syncthreads();   // h1 staged

    if (wave < 2){
      if (t > 0){   // logits for step t-1 from staged h1
        const int d = bid*2 + wave, bo = d >> 5, vo = d & 31;
        float acc = 0.f;
        #pragma unroll
        for (int k = 0; k < 8; ++k){
          const int h = lane + 64*k;
          acc = fmaf(S.Wor[wave][h], S.stg[bo][h], acc);
        }
        #pragma unroll
        for (int off = 32; off; off >>= 1) acc += __shfl_xor(acc, off);
        if (lane == 0) a.out[(size_t)(bo*TT + (t-1))*VV + vo] = acc + S.boutv[wave];
      }
    } else {      // qW = h1 @ Wq^T + bq  (2 output rows per block)
      const int jj = wave - 2;
      const int off0 = lg * 128;
      float acc = 0.f;
      #pragma unroll 8
      for (int h = 0; h < 128; h += 4){
        const float4 w4 = *(const float4*)&S.Wqr[jj][off0 + h];
        const float4 x4 = *(const float4*)&S.stg[lb][off0 + h];
        acc = fmaf(w4.x,x4.x, fmaf(w4.y,x4.y, fmaf(w4.z,x4.z, fmaf(w4.w,x4.w, acc))));
      }
      acc += __shfl_xor(acc, 16);
      acc += __shfl_xor(acc, 32);
      if (lane < 16) stcc(&a.qWg[lane*HH + j0 + jj], acc + S.bqv[jj]);
    }

    e++; gbar_arrive(a.bar, e, bid);   // ---- B1 ARRIVE (qW stores drained) ----

    // B1 window: W1h dot + pre1; enc stage + W0e dot + pre0-combine
    dot_part(&S.W1h[0][0][0], S.stg, S.red, wave, lane);  // h1 @ Whh1^T
    __syncthreads();
    if (tid < 128){
      const int jj = tid >> 6, l = tid & 63, g = l >> 4, b = l & 15;
      S.pre1[b][g][jj] = S.red[2*jj][l] + S.red[2*jj+1][l] + S.bs1[g][jj];
    }
    #pragma unroll
    for (int it = 0; it < 8; ++it){               // enc_t stage
      const int idx = (it*TPB + tid)*4;
      *(float4*)&S.stg[idx >> 9][idx & 511] = r_en[it];
    }
    __syncthreads();   // enc staged, pre1 done
    dot_part(&S.W0e[0][0][0], S.stg, S.red, wave, lane);  // enc_t part of Wih0
    __syncthreads();
    if (tid < 128){
      const int jj = tid >> 6, l = tid & 63, g = l >> 4, b = l & 15;
      S.pre0[b][g][jj] += S.red[2*jj][l] + S.red[2*jj+1][l];
    }

    gbar_wait(a.bar, e, bid);   // ---- B1 WAIT: qW visible ----

    // ========== Phase B: attention (critical path) ==========
    {
      float* Up = a.Ug + par*(BB*HH);
      float* Zp = a.Zg + par*16;
      const float2 q2 = ld2cc(&a.qWg[ba*HH + tid*2]);
      *(float2*)&S.qrow[tid*2] = q2;
      __syncthreads();
      #pragma unroll
      for (int i = 0; i < 4; ++i){
        float acc = 0.f;
        #pragma unroll
        for (int k = 0; k < 8; ++k){
          const int h = lane + 64*k;
          acc = fmaf(S.vv[h], ftanh(S.qrow[h] + r_kp[i][k]), acc);
        }
        #pragma unroll
        for (int off = 32; off; off >>= 1) acc += __shfl_xor(acc, off);
        if (lane == 0) S.scw[wave*4 + i] = __expf(acc + vb0);  // |score|<=~18, exp safe
      }
      __syncthreads();
      float u0 = 0.f, u1 = 0.f;
      #pragma unroll
      for (int lt = 0; lt < 16; ++lt){
        const float w = S.scw[lt];
        u0 = fmaf(w, r_e0[lt], u0);
        u1 = fmaf(w, r_e1[lt], u1);
      }
      unsafeAtomicAdd(&Up[ba*HH + tid],       u0);
      unsafeAtomicAdd(&Up[ba*HH + tid + 256], u1);
      if (tid == 0){
        float zs = 0.f;
        #pragma unroll
        for (int lt = 0; lt < 16; ++lt) zs += S.scw[lt];
        unsafeAtomicAdd(&Zp[ba], zs);
      }
    }
    gbar2(bar2, t + 1, bid, ba);   // ---- B2 per-GROUP: group ba's U,Z complete ----

    // ========== Phase C: LSTM0 (raw-U dot, post-scale by 1/Z) ==========
    {
      float2 r_u[16];
      ldbuf_cc(a.Ug + par*(BB*HH), r_u, tid);
      if (tid < 16) S.zinv[tid] = 1.0f / ldcc(&a.Zg[par*16 + tid]);
      stg_regs(r_u, S.stg, tid);
      __syncthreads();
      dot_part(&S.W0c[0][0][0], S.stg, S.red, wave, lane);  // raw-U part of Wih0
      __syncthreads();
      if (tid < 32){
        const int b = tid & 15, jj = tid >> 4;
        const float zi = S.zinv[b];
        float gv[4];
        #pragma unroll
        for (int g = 0; g < 4; ++g)
          gv[g] = S.pre0[b][g][jj] + (S.red[2*jj][g*16+b] + S.red[2*jj+1][g*16+b]) * zi;
        const float cold = S.cst[0][jj][b];
        const float ii = fsig(gv[0]), ff = fsig(gv[1]);
        const float gg = ftanh(gv[2]), oo = fsig(gv[3]);
        const float cn = ff*cold + ii*gg;
        S.cst[0][jj][b] = cn;
        stcc(&a.H0buf[parn*(BB*HH) + b*HH + j0 + jj], oo * ftanh(cn));
      }
    }
    e++; gbar_arrive(a.bar, e, bid);   // ---- B3 ARRIVE (h0n stores drained) ----
    {
      // B3 window: prefetch next step's enc_t (read-only)
      const int tn = (t + 1 < TT) ? (t + 1) : t;
      #pragma unroll
      for (int it = 0; it < 8; ++it){
        const int idx = (it*TPB + tid)*4;
        r_en[it] = *(const float4*)&a.enc[(size_t)((idx >> 9)*TT + tn)*HH + (idx & 511)];
      }
    }
    gbar_wait(a.bar, e, bid);          // ---- B3 WAIT: h0n complete ----

    // ========== Phase D: LSTM1 + (B4 window) W0h dot for t+1 ==========
    {
      // zero next step's U/Z buffers (visibility rides B4; readers of old slot done — gated by B1)
      if (tid < 32) stcc(&a.Ug[parn*(BB*HH) + bid*32 + tid], 0.0f);
      if (bid == 0 && tid < 16) stcc(&a.Zg[parn*16 + tid], 0.0f);

      float2 r_x[16];
      ldbuf_cc(a.H0buf + parn*(BB*HH), r_x, tid);
      stg_regs(r_x, S.stg, tid);
      __syncthreads();
      dot_part(&S.W1x[0][0][0], S.stg, S.red, wave, lane);  // h0n @ Wih1^T
      __syncthreads();
      if (tid < 32){
        const int b = tid & 15, jj = tid >> 4;
        float gv[4];
        #pragma unroll
        for (int g = 0; g < 4; ++g)
          gv[g] = S.pre1[b][g][jj] + S.red[2*jj][g*16+b] + S.red[2*jj+1][g*16+b];
        const float cold = S.cst[1][jj][b];
        const float ii = fsig(gv[0]), ff = fsig(gv[1]);
        const float gg = ftanh(gv[2]), oo = fsig(gv[3]);
        const float cn = ff*cold + ii*gg;
        S.cst[1][jj][b] = cn;
        stcc(&a.H1buf[parn*(BB*HH) + b*HH + j0 + jj], oo * ftanh(cn));
      }
    }
    e++; gbar_arrive(a.bar, e, bid);   // ---- B4 ARRIVE (h1n stores drained) ----
    {
      // B4 window: W0h @ h0n -> pre0 for step t+1 (stg still holds h0n; red free)
      dot_part(&S.W0h[0][0][0], S.stg, S.red, wave, lane);
      __syncthreads();
      if (tid < 128){
        const int jj = tid >> 6, l = tid & 63, g = l >> 4, b = l & 15;
        S.pre0[b][g][jj] = S.red[2*jj][l] + S.red[2*jj+1][l] + S.bs0[g][jj];
      }
    }
    gbar_wait(a.bar, e, bid);          // ---- B4 WAIT: h1n complete -> next step ----
  }

  // tail: logits for t=255 (final h1 is in H1buf[0] since (255+1)&1==0)
  {
    float2 r_x[16];
    ldbuf_cc(a.H1buf, r_x, tid);
    stg_regs(r_x, S.stg, tid);
    __syncthreads();
    if (wave < 2){
      const int d = bid*2 + wave, bo = d >> 5, vo = d & 31;
      float acc = 0.f;
      #pragma unroll
      for (int k = 0; k < 8; ++k){
        const int h = lane + 64*k;
        acc = fmaf(S.Wor[wave][h], S.stg[bo][h], acc);
      }
      #pragma unroll
      for (int off = 32; off; off >>= 1) acc += __shfl_xor(acc, off);
      if (lane == 0) a.out[(size_t)(bo*TT + 255)*VV + vo] = acc + S.boutv[wave];
    }
  }
}

extern "C" void kernel_launch(void* const* d_in, const int* in_sizes, int n_in,
                              void* d_out, int out_size, void* d_ws, size_t ws_size,
                              hipStream_t stream){
  const float* enc  = (const float*)d_in[0];
  const float* h0in = (const float*)d_in[1];
  const float* c0in = (const float*)d_in[2];
  // d_in[3] audio_lengths: unused by the reference
  const float* Wq   = (const float*)d_in[4];
  const float* bq   = (const float*)d_in[5];
  const float* Wk   = (const float*)d_in[6];
  const float* bk   = (const float*)d_in[7];
  const float* vatt = (const float*)d_in[8];
  const float* vb   = (const float*)d_in[9];
  const float* Wih0 = (const float*)d_in[10];
  const float* bih0 = (const float*)d_in[11];
  const float* Whh0 = (const float*)d_in[12];
  const float* bhh0 = (const float*)d_in[13];
  const float* Wih1 = (const float*)d_in[14];
  const float* bih1 = (const float*)d_in[15];
  const float* Whh1 = (const float*)d_in[16];
  const float* bhh1 = (const float*)d_in[17];
  const float* Wout = (const float*)d_in[18];
  const float* bout = (const float*)d_in[19];

  float* ws    = (float*)d_ws;
  float* Kproj = ws;                               // B*T*H = 2097152
  float* H0buf = Kproj + (size_t)BB*TT*HH;         // 2*B*H
  float* H1buf = H0buf + 2*BB*HH;                  // 2*B*H
  float* qWg   = H1buf + 2*BB*HH;                  // B*H
  float* Ug    = qWg + BB*HH;                      // 2*B*H (parity double-buffer)
  float* Zg    = Ug + 2*BB*HH;                     // 2*16
  int*   bar   = (int*)(Zg + 32);                  // BAR_INTS ints (global + group)

  hipLaunchKernelGGL(init_kernel, dim3(64), dim3(256), 0, stream,
                     h0in, H0buf, H1buf, Ug, Zg, bar);
  hipLaunchKernelGGL(kproj_kernel, dim3(256), dim3(256), 0, stream, enc, Wk, bk, Kproj);

  KArgs ka;
  ka.enc = enc; ka.h0in = h0in; ka.c0in = c0in;
  ka.Wq = Wq; ka.bq = bq; ka.vatt = vatt; ka.vb = vb;
  ka.Wih0 = Wih0; ka.bih0 = bih0; ka.Whh0 = Whh0; ka.bhh0 = bhh0;
  ka.Wih1 = Wih1; ka.bih1 = bih1; ka.Whh1 = Whh1; ka.bhh1 = bhh1;
  ka.Wout = Wout; ka.bout = bout;
  ka.Kproj = Kproj; ka.H0buf = H0buf; ka.H1buf = H1buf;
  ka.qWg = qWg; ka.Ug = Ug; ka.Zg = Zg; ka.bar = bar; ka.out = (float*)d_out;

  void* params[] = { (void*)&ka };
  hipLaunchCooperativeKernel((const void*)decoder_persist, dim3(NBLK), dim3(TPB),
                             params, 0, stream);
}

// Round 13
// 4718.548 us; speedup vs baseline: 3.9092x; 1.1277x over previous
//
#include <hip/hip_runtime.h>

#define HH 512
#define BB 16
#define TT 256
#define VV 32
#define TPB 512
#define NBLK 256
#define PITCH 516   // LDS row pitch (floats)

#define BAR_INTS 512   // 256 global slots + 256 per-group slots

struct KArgs {
  const float* enc; const float* h0in; const float* c0in;
  const float* Wq; const float* bq; const float* vatt; const float* vb;
  const float* Wih0; const float* bih0; const float* Whh0; const float* bhh0;
  const float* Wih1; const float* bih1; const float* Whh1; const float* bhh1;
  const float* Wout; const float* bout;
  const float* Kproj; float* H0buf; float* H1buf; float* qWg; float* Ug; float* Zg;
  int* bar; float* out;
};

struct Smem {
  float W0e[4][2][PITCH];   // Wih0[g*512+j][0:512]    (enc_t part)
  float W0c[4][2][PITCH];   // Wih0[g*512+j][512:1024] (ctx part)
  float W0h[4][2][PITCH];   // Whh0
  float W1x[4][2][PITCH];   // Wih1
  float W1h[4][2][PITCH];   // Whh1
  float Wqr[2][PITCH];
  float Wor[2][PITCH];
  float vv[HH];
  union { float qrow[HH]; float red[8][64]; } qr;  // time-disjoint: qrow=phase B, red=dots
  float stg[BB][PITCH];     // staging: h1 -> enc -> U -> h0n
  float pre0[BB][4][2];     // bs0 + W0h*h0_prev (B4win of t-1) + W0e*enc (B1win of t)
  float pre1[BB][4][2];     // bs1 + W1h*h1_prev (B1win of t)
  float cst[2][2][BB];      // c state [layer][jj][b]
  float scw[16];            // attention exp-weights
  float zinv[BB];
  float bs0[4][2];
  float bs1[4][2];
  float bqv[2], boutv[2];
};

__device__ __forceinline__ float fsig(float x){ return 1.0f/(1.0f + __expf(-x)); }
__device__ __forceinline__ float ftanh(float x){
  float ee = __expf(2.0f*x);
  return 1.0f - 2.0f/(ee + 1.0f);
}

// relaxed agent-scope (cross-XCD coherent, write-through, no wb/inv) — proven transport
__device__ __forceinline__ void stcc(float* p, float v){
  __hip_atomic_store(p, v, __ATOMIC_RELAXED, __HIP_MEMORY_SCOPE_AGENT);
}
__device__ __forceinline__ float ldcc(const float* p){
  return __hip_atomic_load(p, __ATOMIC_RELAXED, __HIP_MEMORY_SCOPE_AGENT);
}
__device__ __forceinline__ float2 ld2cc(const float* p){
  unsigned long long v = __hip_atomic_load((const unsigned long long*)p,
                                           __ATOMIC_RELAXED, __HIP_MEMORY_SCOPE_AGENT);
  union { unsigned long long u; float2 f; } c; c.u = v;
  return c.f;
}

// contiguous coherent load of a 16x512 buffer + LDS stage (512 threads: 8 pairs each)
__device__ __forceinline__ void ldbuf_cc(const float* __restrict__ src,
                                         float2* __restrict__ v, int tid){
  #pragma unroll
  for (int it = 0; it < 8; ++it)
    v[it] = ld2cc(&src[(it*TPB + tid)*2]);
}
__device__ __forceinline__ void stg_regs(const float2* __restrict__ v,
                                         float (* __restrict__ stg)[PITCH], int tid){
  #pragma unroll
  for (int it = 0; it < 8; ++it){
    const int i2 = (it*TPB + tid)*2;
    *(float2*)&stg[i2 >> 9][i2 & 511] = v[it];
  }
}

// ---- global split barrier (r8/r10/r12-proven): slot store + decentralized sweep ----
__device__ __forceinline__ void gbar_arrive(int* __restrict__ bar, int e, int bid){
  __syncthreads();   // per-wave vmcnt drain -> all coherent stores/atomics landed
  if (threadIdx.x == 0)
    __hip_atomic_store(&bar[bid], e, __ATOMIC_RELAXED, __HIP_MEMORY_SCOPE_AGENT);
}
__device__ __forceinline__ void gbar_wait(int* __restrict__ bar, int e, int bid){
  if (threadIdx.x < 64){
    const unsigned long long* p = (const unsigned long long*)bar;   // 128 ulls
    const int i0 = threadIdx.x * 2;
    int spins = 0;
    for (;;){
      unsigned long long v0 = __hip_atomic_load(&p[i0],     __ATOMIC_RELAXED, __HIP_MEMORY_SCOPE_AGENT);
      unsigned long long v1 = __hip_atomic_load(&p[i0 + 1], __ATOMIC_RELAXED, __HIP_MEMORY_SCOPE_AGENT);
      const int a0 = (int)v0, a1 = (int)(v0 >> 32), a2 = (int)v1, a3 = (int)(v1 >> 32);
      const int ok = (a0 >= e) & (a1 >= e) & (a2 >= e) & (a3 >= e);
      if (__all(ok)) break;
      __builtin_amdgcn_s_sleep(2);
      if (++spins > (1 << 20)) break;   // safety valve
    }
  }
  __syncthreads();
}

// ---- per-group (16-block) barrier (r12-proven) ----
__device__ __forceinline__ void gbar2(int* __restrict__ bar2, int et, int bid, int ba){
  __syncthreads();   // drains this block's U/Z atomics
  if (threadIdx.x == 0)
    __hip_atomic_store(&bar2[bid], et, __ATOMIC_RELAXED, __HIP_MEMORY_SCOPE_AGENT);
  if (threadIdx.x < 64){
    const unsigned long long* p = (const unsigned long long*)bar2 + ba*8;  // 16 ints
    int spins = 0;
    for (;;){
      int ok = 1;
      if (threadIdx.x < 8){
        unsigned long long v = __hip_atomic_load(&p[threadIdx.x], __ATOMIC_RELAXED, __HIP_MEMORY_SCOPE_AGENT);
        ok = ((int)v >= et) & ((int)(v >> 32) >= et);
      }
      if (__all(ok)) break;
      __builtin_amdgcn_s_sleep(1);
      if (++spins > (1 << 20)) break;   // safety valve
    }
  }
  __syncthreads();
}

// 8-wave dot: wave w -> (jj = w>>2, 128-h segment = w&3); lane = (g<<4)|b
// 4 independent accumulators break the FMA dependency chain (32 -> 8 deep)
__device__ __forceinline__ void dot8(const float* __restrict__ W,
                                     const float (* __restrict__ stg)[PITCH],
                                     float (* __restrict__ red)[64],
                                     int wave, int lane){
  const int jj = wave >> 2, off = (wave & 3) << 7;
  const int b = lane & 15, g = lane >> 4;
  const float* wrow = W + (size_t)(g*2 + jj)*PITCH + off;
  const float* xrow = &stg[b][off];
  float a0 = 0.f, a1 = 0.f, a2 = 0.f, a3 = 0.f;
  #pragma unroll
  for (int h = 0; h < 128; h += 16){
    const float4 w0 = *(const float4*)&wrow[h];      const float4 x0 = *(const float4*)&xrow[h];
    const float4 w1 = *(const float4*)&wrow[h + 4];  const float4 x1 = *(const float4*)&xrow[h + 4];
    const float4 w2 = *(const float4*)&wrow[h + 8];  const float4 x2 = *(const float4*)&xrow[h + 8];
    const float4 w3 = *(const float4*)&wrow[h + 12]; const float4 x3 = *(const float4*)&xrow[h + 12];
    a0 = fmaf(w0.x,x0.x, fmaf(w0.y,x0.y, fmaf(w0.z,x0.z, fmaf(w0.w,x0.w, a0))));
    a1 = fmaf(w1.x,x1.x, fmaf(w1.y,x1.y, fmaf(w1.z,x1.z, fmaf(w1.w,x1.w, a1))));
    a2 = fmaf(w2.x,x2.x, fmaf(w2.y,x2.y, fmaf(w2.z,x2.z, fmaf(w2.w,x2.w, a2))));
    a3 = fmaf(w3.x,x3.x, fmaf(w3.y,x3.y, fmaf(w3.z,x3.z, fmaf(w3.w,x3.w, a3))));
  }
  red[wave][lane] = (a0 + a1) + (a2 + a3);
}

__global__ void init_kernel(const float* __restrict__ h0in, float* __restrict__ H0buf,
                            float* __restrict__ H1buf, float* __restrict__ Ug,
                            float* __restrict__ Zg, int* __restrict__ bar){
  const int i = blockIdx.x*blockDim.x + threadIdx.x;
  if (i < BB*HH){
    H0buf[i] = h0in[i];            // layer 0
    H1buf[i] = h0in[BB*HH + i];    // layer 1
  }
  if (i < 2*BB*HH) Ug[i] = 0.0f;
  if (i < 32) Zg[i] = 0.0f;
  if (i < BAR_INTS) bar[i] = 0;
}

// Kproj = enc @ Wk^T + bk : 256 blocks x 16 (b,t)-rows, x register-cached
__global__ __launch_bounds__(256, 1) void kproj_kernel(const float* __restrict__ enc,
                                                       const float* __restrict__ Wk,
                                                       const float* __restrict__ bk,
                                                       float* __restrict__ Kproj){
  __shared__ float er[BB][PITCH];
  const int bid = blockIdx.x, tid = threadIdx.x;
  const int wave = tid >> 6, lane = tid & 63;
  const int r = lane & 15, q = lane >> 4;
  const int row0 = bid*16;
  #pragma unroll
  for (int it = 0; it < 8; ++it){
    const int idx = (it*256 + tid)*4;
    const int rr = idx >> 9, h = idx & 511;
    *(float4*)&er[rr][h] = *(const float4*)&enc[(size_t)(row0+rr)*HH + h];
  }
  __syncthreads();
  float4 xr[32];
  #pragma unroll
  for (int i = 0; i < 32; ++i) xr[i] = *(const float4*)&er[r][q*128 + i*4];
  for (int k = 0; k < 128; ++k){
    const int hk = wave*128 + k;
    const float* wrow = Wk + (size_t)hk*HH + q*128;
    float acc = 0.f;
    #pragma unroll
    for (int i = 0; i < 32; ++i){
      const float4 w4 = *(const float4*)&wrow[i*4];
      acc = fmaf(w4.x,xr[i].x, fmaf(w4.y,xr[i].y, fmaf(w4.z,xr[i].z, fmaf(w4.w,xr[i].w, acc))));
    }
    acc += __shfl_xor(acc, 16);
    acc += __shfl_xor(acc, 32);
    if (lane < 16) Kproj[(size_t)(row0 + r)*HH + hk] = acc + bk[hk];
  }
}

__global__ __launch_bounds__(TPB, 1) void decoder_persist(KArgs a){
  __shared__ Smem S;
  const int bid = blockIdx.x, tid = threadIdx.x;
  const int wave = tid >> 6, lane = tid & 63;
  const int lb = lane & 15, lg = lane >> 4;
  const int j0 = bid*2;
  const int ba = bid >> 4, tb = (bid & 15) * 16;   // attention assignment
  int* bar2 = a.bar + 256;

  // ---- one-time: weights to LDS ----
  for (int g = 0; g < 4; ++g){
    for (int jj = 0; jj < 2; ++jj){
      const int row = g*HH + j0 + jj;
      for (int h = tid; h < HH; h += TPB){
        S.W0e[g][jj][h] = a.Wih0[(size_t)row*(2*HH) + h];
        S.W0c[g][jj][h] = a.Wih0[(size_t)row*(2*HH) + HH + h];
        S.W0h[g][jj][h] = a.Whh0[(size_t)row*HH + h];
        S.W1x[g][jj][h] = a.Wih1[(size_t)row*HH + h];
        S.W1h[g][jj][h] = a.Whh1[(size_t)row*HH + h];
      }
    }
  }
  for (int jj = 0; jj < 2; ++jj){
    const int d = bid*2 + jj, vo = d & 31;
    for (int h = tid; h < HH; h += TPB){
      S.Wqr[jj][h] = a.Wq[(size_t)(j0+jj)*HH + h];
      S.Wor[jj][h] = a.Wout[(size_t)vo*HH + h];
    }
  }
  for (int h = tid; h < HH; h += TPB) S.vv[h] = a.vatt[h];
  if (tid < 16){
    S.cst[0][0][tid] = a.c0in[0*BB*HH + tid*HH + j0];
    S.cst[0][1][tid] = a.c0in[0*BB*HH + tid*HH + j0 + 1];
    S.cst[1][0][tid] = a.c0in[1*BB*HH + tid*HH + j0];
    S.cst[1][1][tid] = a.c0in[1*BB*HH + tid*HH + j0 + 1];
  }
  if (tid < 8){
    const int g = tid & 3, jj = tid >> 2;
    const int row = g*HH + j0 + jj;
    S.bs0[g][jj] = a.bih0[row] + a.bhh0[row];
    S.bs1[g][jj] = a.bih1[row] + a.bhh1[row];
  }
  if (tid < 2){
    S.bqv[tid] = a.bq[j0 + tid];
    S.boutv[tid] = a.bout[(bid*2 + tid) & 31];
  }
  const float vb0 = a.vb[0];

  // ---- step-invariant attention operands -> registers (8 waves x 2 t each) ----
  float r_kp[2][8];
  #pragma unroll
  for (int i = 0; i < 2; ++i){
    const float* kp = a.Kproj + (size_t)(ba*TT + tb + wave*2 + i)*HH;
    #pragma unroll
    for (int k = 0; k < 8; ++k) r_kp[i][k] = kp[lane + 64*k];
  }
  float r_e[16];
  #pragma unroll
  for (int lt = 0; lt < 16; ++lt)
    r_e[lt] = a.enc[(size_t)(ba*TT + tb + lt)*HH + tid];
  // enc_t prefetch for t=0 (16 floats = 4 float4 per thread)
  float4 r_en[4];
  #pragma unroll
  for (int it = 0; it < 4; ++it){
    const int idx = (it*TPB + tid)*4;
    r_en[it] = *(const float4*)&a.enc[(size_t)((idx >> 9)*TT + 0)*HH + (idx & 511)];
  }
  __syncthreads();

  // ---- prologue: pre0 = bs0 + W0h @ h0_init ----
  {
    #pragma unroll
    for (int it = 0; it < 4; ++it){
      const int idx = (it*TPB + tid)*4;
      *(float4*)&S.stg[idx >> 9][idx & 511] = *(const float4*)&a.h0in[idx];
    }
    __syncthreads();
    dot8(&S.W0h[0][0][0], S.stg, S.qr.red, wave, lane);
    __syncthreads();
    if (tid < 128){
      const int jj = tid >> 6, l = tid & 63, g = l >> 4, b = l & 15;
      S.pre0[b][g][jj] = (S.qr.red[jj*4+0][l] + S.qr.red[jj*4+1][l])
                       + (S.qr.red[jj*4+2][l] + S.qr.red[jj*4+3][l]) + S.bs0[g][jj];
    }
    __syncthreads();
  }

  int e = 0;
  for (int t = 0; t < TT; ++t){
    const int par = t & 1, parn = par ^ 1;

    // ========== Phase A: h1 load+stage, logits(t-1), qW ==========
    float2 r_h1[8];
    ldbuf_cc(a.H1buf + par*(BB*HH), r_h1, tid);
    stg_regs(r_h1, S.stg, tid);
    __syncthreads();   // h1 staged

    if (wave < 2){
      if (t > 0){   // logits for step t-1 from staged h1
        const int d = bid*2 + wave, bo = d >> 5, vo = d & 31;
        float acc = 0.f;
        #pragma unroll
        for (int k = 0; k < 8; ++k){
          const int h = lane + 64*k;
          acc = fmaf(S.Wor[wave][h], S.stg[bo][h], acc);
        }
        #pragma unroll
        for (int off = 32; off; off >>= 1) acc += __shfl_xor(acc, off);
        if (lane == 0) a.out[(size_t)(bo*TT + (t-1))*VV + vo] = acc + S.boutv[wave];
      }
    } else if (wave < 4){  // qW = h1 @ Wq^T + bq (2-accumulator chains)
      const int jj = wave - 2;
      const int off0 = lg * 128;
      float a0 = 0.f, a1 = 0.f;
      #pragma unroll
      for (int h = 0; h < 128; h += 8){
        const float4 w0 = *(const float4*)&S.Wqr[jj][off0 + h];
        const float4 x0 = *(const float4*)&S.stg[lb][off0 + h];
        const float4 w1 = *(const float4*)&S.Wqr[jj][off0 + h + 4];
        const float4 x1 = *(const float4*)&S.stg[lb][off0 + h + 4];
        a0 = fmaf(w0.x,x0.x, fmaf(w0.y,x0.y, fmaf(w0.z,x0.z, fmaf(w0.w,x0.w, a0))));
        a1 = fmaf(w1.x,x1.x, fmaf(w1.y,x1.y, fmaf(w1.z,x1.z, fmaf(w1.w,x1.w, a1))));
      }
      float acc = a0 + a1;
      acc += __shfl_xor(acc, 16);
      acc += __shfl_xor(acc, 32);
      if (lane < 16) stcc(&a.qWg[lane*HH + j0 + jj], acc + S.bqv[jj]);
    }

    e++; gbar_arrive(a.bar, e, bid);   // ---- B1 ARRIVE (qW stores drained) ----

    // B1 window: W1h dot + pre1; enc stage + W0e dot + pre0-combine
    dot8(&S.W1h[0][0][0], S.stg, S.qr.red, wave, lane);   // h1 @ Whh1^T
    __syncthreads();
    if (tid < 128){
      const int jj = tid >> 6, l = tid & 63, g = l >> 4, b = l & 15;
      S.pre1[b][g][jj] = (S.qr.red[jj*4+0][l] + S.qr.red[jj*4+1][l])
                       + (S.qr.red[jj*4+2][l] + S.qr.red[jj*4+3][l]) + S.bs1[g][jj];
    }
    #pragma unroll
    for (int it = 0; it < 4; ++it){               // enc_t stage
      const int idx = (it*TPB + tid)*4;
      *(float4*)&S.stg[idx >> 9][idx & 511] = r_en[it];
    }
    __syncthreads();   // enc staged, pre1 done
    dot8(&S.W0e[0][0][0], S.stg, S.qr.red, wave, lane);   // enc_t part of Wih0
    __syncthreads();
    if (tid < 128){
      const int jj = tid >> 6, l = tid & 63, g = l >> 4, b = l & 15;
      S.pre0[b][g][jj] += (S.qr.red[jj*4+0][l] + S.qr.red[jj*4+1][l])
                        + (S.qr.red[jj*4+2][l] + S.qr.red[jj*4+3][l]);
    }

    gbar_wait(a.bar, e, bid);   // ---- B1 WAIT: qW visible ----

    // ========== Phase B: attention ==========
    {
      float* Up = a.Ug + par*(BB*HH);
      float* Zp = a.Zg + par*16;
      const float qv = ldcc(&a.qWg[ba*HH + tid]);
      S.qr.qrow[tid] = qv;        // qrow aliases red: all red reads completed pre-B1-wait
      __syncthreads();
      #pragma unroll
      for (int i = 0; i < 2; ++i){
        float acc = 0.f;
        #pragma unroll
        for (int k = 0; k < 8; ++k){
          const int h = lane + 64*k;
          acc = fmaf(S.vv[h], ftanh(S.qr.qrow[h] + r_kp[i][k]), acc);
        }
        #pragma unroll
        for (int off = 32; off; off >>= 1) acc += __shfl_xor(acc, off);
        if (lane == 0) S.scw[wave*2 + i] = __expf(acc + vb0);  // |score|<=~18, exp safe
      }
      __syncthreads();
      float u = 0.f;
      #pragma unroll
      for (int lt = 0; lt < 16; ++lt)
        u = fmaf(S.scw[lt], r_e[lt], u);
      unsafeAtomicAdd(&Up[ba*HH + tid], u);
      if (tid == 0){
        float zs = 0.f;
        #pragma unroll
        for (int lt = 0; lt < 16; ++lt) zs += S.scw[lt];
        unsafeAtomicAdd(&Zp[ba], zs);
      }
    }
    gbar2(bar2, t + 1, bid, ba);   // ---- B2 per-GROUP: group ba's U,Z complete ----

    // ========== Phase C: LSTM0 (raw-U dot, post-scale by 1/Z) ==========
    {
      float2 r_u[8];
      ldbuf_cc(a.Ug + par*(BB*HH), r_u, tid);
      if (tid < 16) S.zinv[tid] = 1.0f / ldcc(&a.Zg[par*16 + tid]);
      stg_regs(r_u, S.stg, tid);
      __syncthreads();
      dot8(&S.W0c[0][0][0], S.stg, S.qr.red, wave, lane);  // raw-U part of Wih0
      __syncthreads();
      if (tid < 32){
        const int b = tid & 15, jj = tid >> 4;
        const float zi = S.zinv[b];
        float gv[4];
        #pragma unroll
        for (int g = 0; g < 4; ++g){
          const int l = g*16 + b;
          gv[g] = S.pre0[b][g][jj]
                + ((S.qr.red[jj*4+0][l] + S.qr.red[jj*4+1][l])
                 + (S.qr.red[jj*4+2][l] + S.qr.red[jj*4+3][l])) * zi;
        }
        const float cold = S.cst[0][jj][b];
        const float ii = fsig(gv[0]), ff = fsig(gv[1]);
        const float gg = ftanh(gv[2]), oo = fsig(gv[3]);
        const float cn = ff*cold + ii*gg;
        S.cst[0][jj][b] = cn;
        stcc(&a.H0buf[parn*(BB*HH) + b*HH + j0 + jj], oo * ftanh(cn));
      }
    }
    e++; gbar_arrive(a.bar, e, bid);   // ---- B3 ARRIVE (h0n stores drained) ----
    {
      // B3 window: prefetch next step's enc_t (read-only)
      const int tn = (t + 1 < TT) ? (t + 1) : t;
      #pragma unroll
      for (int it = 0; it < 4; ++it){
        const int idx = (it*TPB + tid)*4;
        r_en[it] = *(const float4*)&a.enc[(size_t)((idx >> 9)*TT + tn)*HH + (idx & 511)];
      }
    }
    gbar_wait(a.bar, e, bid);          // ---- B3 WAIT: h0n complete ----

    // ========== Phase D: LSTM1 + (B4 window) W0h dot for t+1 ==========
    {
      // zero next step's U/Z buffers (visibility rides B4; old-slot readers gated by B1)
      if (tid < 32) stcc(&a.Ug[parn*(BB*HH) + bid*32 + tid], 0.0f);
      if (bid == 0 && tid < 16) stcc(&a.Zg[parn*16 + tid], 0.0f);

      float2 r_x[8];
      ldbuf_cc(a.H0buf + parn*(BB*HH), r_x, tid);
      stg_regs(r_x, S.stg, tid);
      __syncthreads();
      dot8(&S.W1x[0][0][0], S.stg, S.qr.red, wave, lane);  // h0n @ Wih1^T
      __syncthreads();
      if (tid < 32){
        const int b = tid & 15, jj = tid >> 4;
        float gv[4];
        #pragma unroll
        for (int g = 0; g < 4; ++g){
          const int l = g*16 + b;
          gv[g] = S.pre1[b][g][jj]
                + (S.qr.red[jj*4+0][l] + S.qr.red[jj*4+1][l])
                + (S.qr.red[jj*4+2][l] + S.qr.red[jj*4+3][l]);
        }
        const float cold = S.cst[1][jj][b];
        const float ii = fsig(gv[0]), ff = fsig(gv[1]);
        const float gg = ftanh(gv[2]), oo = fsig(gv[3]);
        const float cn = ff*cold + ii*gg;
        S.cst[1][jj][b] = cn;
        stcc(&a.H1buf[parn*(BB*HH) + b*HH + j0 + jj], oo * ftanh(cn));
      }
    }
    e++; gbar_arrive(a.bar, e, bid);   // ---- B4 ARRIVE (h1n stores drained) ----
    {
      // B4 window: W0h @ h0n -> pre0 for step t+1 (stg still holds h0n; red free)
      dot8(&S.W0h[0][0][0], S.stg, S.qr.red, wave, lane);
      __syncthreads();
      if (tid < 128){
        const int jj = tid >> 6, l = tid & 63, g = l >> 4, b = l & 15;
        S.pre0[b][g][jj] = (S.qr.red[jj*4+0][l] + S.qr.red[jj*4+1][l])
                         + (S.qr.red[jj*4+2][l] + S.qr.red[jj*4+3][l]) + S.bs0[g][jj];
      }
    }
    gbar_wait(a.bar, e, bid);          // ---- B4 WAIT: h1n complete -> next step ----
  }

  // tail: logits for t=255 (final h1 is in H1buf[0] since (255+1)&1==0)
  {
    float2 r_x[8];
    ldbuf_cc(a.H1buf, r_x, tid);
    stg_regs(r_x, S.stg, tid);
    __syncthreads();
    if (wave < 2){
      const int d = bid*2 + wave, bo = d >> 5, vo = d & 31;
      float acc = 0.f;
      #pragma unroll
      for (int k = 0; k < 8; ++k){
        const int h = lane + 64*k;
        acc = fmaf(S.Wor[wave][h], S.stg[bo][h], acc);
      }
      #pragma unroll
      for (int off = 32; off; off >>= 1) acc += __shfl_xor(acc, off);
      if (lane == 0) a.out[(size_t)(bo*TT + 255)*VV + vo] = acc + S.boutv[wave];
    }
  }
}

extern "C" void kernel_launch(void* const* d_in, const int* in_sizes, int n_in,
                              void* d_out, int out_size, void* d_ws, size_t ws_size,
                              hipStream_t stream){
  const float* enc  = (const float*)d_in[0];
  const float* h0in = (const float*)d_in[1];
  const float* c0in = (const float*)d_in[2];
  // d_in[3] audio_lengths: unused by the reference
  const float* Wq   = (const float*)d_in[4];
  const float* bq   = (const float*)d_in[5];
  const float* Wk   = (const float*)d_in[6];
  const float* bk   = (const float*)d_in[7];
  const float* vatt = (const float*)d_in[8];
  const float* vb   = (const float*)d_in[9];
  const float* Wih0 = (const float*)d_in[10];
  const float* bih0 = (const float*)d_in[11];
  const float* Whh0 = (const float*)d_in[12];
  const float* bhh0 = (const float*)d_in[13];
  const float* Wih1 = (const float*)d_in[14];
  const float* bih1 = (const float*)d_in[15];
  const float* Whh1 = (const float*)d_in[16];
  const float* bhh1 = (const float*)d_in[17];
  const float* Wout = (const float*)d_in[18];
  const float* bout = (const float*)d_in[19];

  float* ws    = (float*)d_ws;
  float* Kproj = ws;                               // B*T*H = 2097152
  float* H0buf = Kproj + (size_t)BB*TT*HH;         // 2*B*H
  float* H1buf = H0buf + 2*BB*HH;                  // 2*B*H
  float* qWg   = H1buf + 2*BB*HH;                  // B*H
  float* Ug    = qWg + BB*HH;                      // 2*B*H (parity double-buffer)
  float* Zg    = Ug + 2*BB*HH;                     // 2*16
  int*   bar   = (int*)(Zg + 32);                  // BAR_INTS ints (global + group)

  hipLaunchKernelGGL(init_kernel, dim3(64), dim3(256), 0, stream,
                     h0in, H0buf, H1buf, Ug, Zg, bar);
  hipLaunchKernelGGL(kproj_kernel, dim3(256), dim3(256), 0, stream, enc, Wk, bk, Kproj);

  KArgs ka;
  ka.enc = enc; ka.h0in = h0in; ka.c0in = c0in;
  ka.Wq = Wq; ka.bq = bq; ka.vatt = vatt; ka.vb = vb;
  ka.Wih0 = Wih0; ka.bih0 = bih0; ka.Whh0 = Whh0; ka.bhh0 = bhh0;
  ka.Wih1 = Wih1; ka.bih1 = bih1; ka.Whh1 = Whh1; ka.bhh1 = bhh1;
  ka.Wout = Wout; ka.bout = bout;
  ka.Kproj = Kproj; ka.H0buf = H0buf; ka.H1buf = H1buf;
  ka.qWg = qWg; ka.Ug = Ug; ka.Zg = Zg; ka.bar = bar; ka.out = (float*)d_out;

  void* params[] = { (void*)&ka };
  hipLaunchCooperativeKernel((const void*)decoder_persist, dim3(NBLK), dim3(TPB),
                             params, 0, stream);
}